// Round 1
// baseline (3112.769 us; speedup 1.0000x reference)
//
#include <hip/hip_runtime.h>
#include <math.h>

#define DEV static __device__ __forceinline__

DEV float softplusf_(float x){
  return x > 0.f ? x + log1pf(expf(-x)) : log1pf(expf(x));
}

DEV float waveReduceSum(float v){
  #pragma unroll
  for (int o = 32; o > 0; o >>= 1) v += __shfl_xor(v, o, 64);
  return v;
}
DEV float waveReduceMax(float v){
  #pragma unroll
  for (int o = 32; o > 0; o >>= 1) v = fmaxf(v, __shfl_xor(v, o, 64));
  return v;
}
DEV float blockReduceSum(float v, float* sh){
  v = waveReduceSum(v);
  int w = threadIdx.x >> 6;
  int nw = blockDim.x >> 6;
  __syncthreads();
  if ((threadIdx.x & 63) == 0) sh[w] = v;
  __syncthreads();
  float r = sh[0];
  for (int i = 1; i < nw; i++) r += sh[i];
  return r;
}
DEV float blockReduceMax(float v, float* sh){
  v = waveReduceMax(v);
  int w = threadIdx.x >> 6;
  int nw = blockDim.x >> 6;
  __syncthreads();
  if ((threadIdx.x & 63) == 0) sh[w] = v;
  __syncthreads();
  float r = sh[0];
  for (int i = 1; i < nw; i++) r = fmaxf(r, sh[i]);
  return r;
}

// ---------------- LayerNorm (Lorentz): LN over spatial 512 + add_time ----------------
__global__ __launch_bounds__(256) void ln_fwd(
    const float* __restrict__ xin,   // [2048][513]
    const float* __restrict__ g, const float* __restrict__ b,
    float* __restrict__ y)           // [2048][513]
{
  __shared__ float sh[8];
  int row = blockIdx.x;
  const float* xr = xin + (long)row * 513 + 1;
  int t = threadIdx.x;
  float a0 = xr[t], a1 = xr[t + 256];
  float s  = blockReduceSum(a0 + a1, sh);
  float s2 = blockReduceSum(a0 * a0 + a1 * a1, sh);
  float mu = s * (1.f / 512.f);
  float var = s2 * (1.f / 512.f) - mu * mu;
  float inv = rsqrtf(var + 1e-5f);
  float y0 = (a0 - mu) * inv * g[t] + b[t];
  float y1v = (a1 - mu) * inv * g[t + 256] + b[t + 256];
  float q = blockReduceSum(y0 * y0 + y1v * y1v, sh);
  float* yr = y + (long)row * 513;
  yr[1 + t] = y0;
  yr[1 + t + 256] = y1v;
  if (t == 0) yr[0] = sqrtf(q + 1.f);
}

// ------------- residual + LN(out_s) + add_time; also emits out_s -------------
__global__ __launch_bounds__(256) void res_ln(
    const float* __restrict__ wo,    // [2048][512]
    const float* __restrict__ xin,   // [2048][513]
    const float* __restrict__ g, const float* __restrict__ b,
    float* __restrict__ outs,        // [2048][512]
    float* __restrict__ y)           // [2048][513]
{
  __shared__ float sh[8];
  int row = blockIdx.x;
  int t = threadIdx.x;
  float a0 = wo[(long)row * 512 + t]       + xin[(long)row * 513 + 1 + t];
  float a1 = wo[(long)row * 512 + t + 256] + xin[(long)row * 513 + 1 + t + 256];
  outs[(long)row * 512 + t] = a0;
  outs[(long)row * 512 + t + 256] = a1;
  float s  = blockReduceSum(a0 + a1, sh);
  float s2 = blockReduceSum(a0 * a0 + a1 * a1, sh);
  float mu = s * (1.f / 512.f);
  float var = s2 * (1.f / 512.f) - mu * mu;
  float inv = rsqrtf(var + 1e-5f);
  float y0 = (a0 - mu) * inv * g[t] + b[t];
  float y1v = (a1 - mu) * inv * g[t + 256] + b[t + 256];
  float q = blockReduceSum(y0 * y0 + y1v * y1v, sh);
  float* yr = y + (long)row * 513;
  yr[1 + t] = y0;
  yr[1 + t + 256] = y1v;
  if (t == 0) yr[0] = sqrtf(q + 1.f);
}

// ------------- add_time over a [rows][1+n] buffer (writes col 0) -------------
__global__ __launch_bounds__(256) void addtime_row(float* __restrict__ h, int n, int ld)
{
  __shared__ float sh[8];
  int row = blockIdx.x;
  float* hr = h + (long)row * ld;
  float s2 = 0.f;
  for (int c = threadIdx.x; c < n; c += 256) {
    float v = hr[1 + c];
    s2 = fmaf(v, v, s2);
  }
  s2 = blockReduceSum(s2, sh);
  if (threadIdx.x == 0) hr[0] = sqrtf(s2 + 1.f);
}

// ------------- final: out_s = h2 + outs ; write [t, out_s] -------------
__global__ __launch_bounds__(256) void final_k(
    const float* __restrict__ h2, const float* __restrict__ outs,
    float* __restrict__ out)
{
  __shared__ float sh[8];
  int row = blockIdx.x;
  int t = threadIdx.x;
  float o0 = h2[(long)row * 512 + t]       + outs[(long)row * 512 + t];
  float o1 = h2[(long)row * 512 + t + 256] + outs[(long)row * 512 + t + 256];
  float q = blockReduceSum(o0 * o0 + o1 * o1, sh);
  float* yr = out + (long)row * 513;
  yr[1 + t] = o0;
  yr[1 + t + 256] = o1;
  if (t == 0) yr[0] = sqrtf(q + 1.f);
}

// ------------- QKV post: split heads, add_time, build Qa/Ka (65-dim), v_tan -------------
__global__ __launch_bounds__(512) void qkv_post(
    const float* __restrict__ S,     // [2048][1536]  (q|k|v)
    float* __restrict__ Qa,          // [16][1024][65]  [q_s, q_t]
    float* __restrict__ Kaa,         // [16][1024][65]  [k_s, -k_t]
    float* __restrict__ VT,          // [16][1024][64]  v_tan spatial
    float* __restrict__ qt, float* __restrict__ kt, float* __restrict__ Bi,
    const float* __restrict__ beta_p)
{
  int row = blockIdx.x;              // b*1024 + n
  int b = row >> 10, n = row & 1023;
  int h = threadIdx.x >> 6, d = threadIdx.x & 63;
  long base = (long)row * 1536;
  float qv = S[base + h * 64 + d];
  float kv = S[base + 512 + h * 64 + d];
  float vv = S[base + 1024 + h * 64 + d];
  float q2 = waveReduceSum(qv * qv);
  float k2 = waveReduceSum(kv * kv);
  float v2 = waveReduceSum(vv * vv);
  float qT = sqrtf(1.f + q2);
  float kT = sqrtf(1.f + k2);
  float vTt = sqrtf(1.f + v2);
  float sn = fmaxf(sqrtf(v2), 1e-8f);
  float dd = acoshf(fmaxf(vTt, 1.f));
  int z = b * 8 + h;
  long a65 = ((long)z * 1024 + n) * 65;
  Qa[a65 + d] = qv;
  Kaa[a65 + d] = kv;
  VT[((long)z * 1024 + n) * 64 + d] = dd * vv / sn;
  if (d == 0) {
    Qa[a65 + 64] = qT;
    Kaa[a65 + 64] = -kT;
    int ob = z * 1024 + n;
    qt[ob] = qT;
    kt[ob] = kT;
    float beta = softplusf_(beta_p[0]);
    float ct = acoshf(fmaxf(qT, 1.001f));
    float rr = beta / sinhf(ct);
    Bi[ob] = sqrtf(fmaxf(1.f - rr * rr, 0.f) + 1e-8f);
  }
}

// ------------- merge heads: expmap0 + concat + head-time merge -------------
__global__ __launch_bounds__(512) void merge_heads(
    const float* __restrict__ mt, float* __restrict__ attn)
{
  __shared__ float t2s[8];
  int row = blockIdx.x;
  int b = row >> 10, n = row & 1023;
  int h = threadIdx.x >> 6, d = threadIdx.x & 63;
  int z = b * 8 + h;
  float v = mt[((long)z * 1024 + n) * 64 + d];
  float s2 = waveReduceSum(v * v);
  float nn = fmaxf(sqrtf(s2), 1e-8f);
  float coef = sinhf(nn) / nn;
  attn[(long)row * 513 + 1 + h * 64 + d] = coef * v;
  if (d == 0) {
    float th = coshf(nn);
    t2s[h] = th * th;
  }
  __syncthreads();
  if (threadIdx.x == 0) {
    float t2 = t2s[0] + t2s[1] + t2s[2] + t2s[3] + t2s[4] + t2s[5] + t2s[6] + t2s[7] - 7.f;
    attn[(long)row * 513] = sqrtf(fmaxf(t2, 1e-8f));
  }
}

// ------------- row softmax over 1024 (in place), scaled by 1/(1+1e-8) -------------
__global__ __launch_bounds__(256) void softmax_rows(float* __restrict__ S)
{
  __shared__ float sh[8];
  long row = blockIdx.x;
  float* p = S + row * 1024;
  int t = threadIdx.x;
  float4 x = *(const float4*)&p[t * 4];
  float mx = fmaxf(fmaxf(x.x, x.y), fmaxf(x.z, x.w));
  mx = blockReduceMax(mx, sh);
  float4 e;
  e.x = expf(x.x - mx);
  e.y = expf(x.y - mx);
  e.z = expf(x.z - mx);
  e.w = expf(x.w - mx);
  float sum = blockReduceSum(e.x + e.y + e.z + e.w, sh);
  float sc = 1.f / (sum * (1.f + 1e-8f));
  e.x *= sc; e.y *= sc; e.z *= sc; e.w *= sc;
  *(float4*)&p[t * 4] = e;
}

// ------------- generic tiled fp32 GEMM -------------
// C = A @ B^T (BT=true, B is [N][K]) or A @ B (BT=false, B is [K][N])
// ACT: 0 none, 1 exact GELU, 2 hyperbolic attention score logits
template<int BMp, int BNp, int TMp, int TNp, int ACT, bool BT>
__global__ __launch_bounds__(256) void gemm_k(
    const float* __restrict__ A, int lda, long strideA,
    const float* __restrict__ Bm, int ldb, long strideB,
    float* __restrict__ C, int ldc, long strideC,
    int Ka,
    const float* __restrict__ qt, const float* __restrict__ Bi,
    const float* __restrict__ kt,
    const float* __restrict__ lam_p, const float* __restrict__ tau_p,
    const float* __restrict__ temp_p)
{
  constexpr int BK = 16;
  __shared__ float As[BK][BMp];
  __shared__ float Bs[BK][BNp];
  const int z = blockIdx.z;
  const float* Ap = A + (long)z * strideA;
  const float* Bp = Bm + (long)z * strideB;
  float* Cp = C + (long)z * strideC;
  const int bm = blockIdx.x * BMp;
  const int bn = blockIdx.y * BNp;
  const int t = threadIdx.x;
  constexpr int NTX = BNp / TNp;
  const int tx = t % NTX;
  const int ty = t / NTX;
  float acc[TMp][TNp];
  #pragma unroll
  for (int i = 0; i < TMp; i++)
    #pragma unroll
    for (int j = 0; j < TNp; j++) acc[i][j] = 0.f;

  for (int kk = 0; kk < Ka; kk += BK) {
    {
      constexpr int AELT = BMp * BK / 256;
      constexpr int TPR = BK / AELT;
      int r = t / TPR;
      int k0 = (t % TPR) * AELT;
      const float* ap = Ap + (long)(bm + r) * lda + kk + k0;
      #pragma unroll
      for (int i = 0; i < AELT; i++)
        As[k0 + i][r] = (kk + k0 + i < Ka) ? ap[i] : 0.f;
    }
    if (BT) {
      constexpr int BELT = BNp * BK / 256;
      constexpr int TPR = BK / BELT;
      int r = t / TPR;
      int k0 = (t % TPR) * BELT;
      const float* bp = Bp + (long)(bn + r) * ldb + kk + k0;
      #pragma unroll
      for (int i = 0; i < BELT; i++)
        Bs[k0 + i][r] = (kk + k0 + i < Ka) ? bp[i] : 0.f;
    } else {
      constexpr int NE = BK * BNp / 256;
      int n = t % BNp;
      int c0 = (t / BNp) * NE;
      #pragma unroll
      for (int i = 0; i < NE; i++)
        Bs[c0 + i][n] = (kk + c0 + i < Ka) ? Bp[(long)(kk + c0 + i) * ldb + bn + n] : 0.f;
    }
    __syncthreads();
    #pragma unroll
    for (int k = 0; k < BK; k++) {
      float a[TMp], b[TNp];
      #pragma unroll
      for (int i = 0; i < TMp / 4; i++)
        ((float4*)a)[i] = ((const float4*)&As[k][ty * TMp])[i];
      #pragma unroll
      for (int j = 0; j < TNp / 4; j++)
        ((float4*)b)[j] = ((const float4*)&Bs[k][tx * TNp])[j];
      #pragma unroll
      for (int i = 0; i < TMp; i++)
        #pragma unroll
        for (int j = 0; j < TNp; j++)
          acc[i][j] = fmaf(a[i], b[j], acc[i][j]);
    }
    __syncthreads();
  }

  if constexpr (ACT == 2) {
    float lam = softplusf_(lam_p[0]);
    float tau = softplusf_(tau_p[0]);
    float invT = 1.f / temp_p[0];
    float qtv[TMp], Biv[TMp], nOQ[TMp], ktv[TNp];
    #pragma unroll
    for (int i = 0; i < TMp; i++) {
      int gi = z * 1024 + bm + ty * TMp + i;
      qtv[i] = qt[gi];
      Biv[i] = Bi[gi];
      nOQ[i] = fmaxf(qtv[i] * qtv[i] - 1.f, 0.f);
    }
    #pragma unroll
    for (int j = 0; j < TNp; j++) ktv[j] = kt[z * 1024 + bn + tx * TNp + j];
    #pragma unroll
    for (int i = 0; i < TMp; i++) {
      #pragma unroll
      for (int j = 0; j < TNp; j++) {
        float inner = acc[i][j];
        float nQK = fmaxf(inner * inner - 1.f, 0.f);
        float numer = -(ktv[j] + inner * qtv[i]);
        float denom = sqrtf(nQK * nOQ[i] + 2.5e-5f);
        float Zc = fminf(fmaxf(numer / denom, -1.f), 1.f);
        float dist = acoshf(fmaxf(-inner, 1.001f));
        float sd = (40.f / 15.f) * tanhf(dist * 0.025f);
        float H = sd + softplusf_(-2.f * sd) - 0.69314718055994531f;
        float Phi = softplusf_(Biv[i] + Zc - 0.1f) - 0.64439666007357095f;
        acc[i][j] = (-lam * H - tau * Phi) * invT;
      }
    }
  } else if constexpr (ACT == 1) {
    #pragma unroll
    for (int i = 0; i < TMp; i++)
      #pragma unroll
      for (int j = 0; j < TNp; j++) {
        float v = acc[i][j];
        acc[i][j] = 0.5f * v * (1.f + erff(v * 0.70710678118654752f));
      }
  }

  #pragma unroll
  for (int i = 0; i < TMp; i++) {
    float* crow = Cp + (long)(bm + ty * TMp + i) * ldc + bn + tx * TNp;
    #pragma unroll
    for (int j = 0; j < TNp; j++) crow[j] = acc[i][j];
  }
}

extern "C" void kernel_launch(void* const* d_in, const int* in_sizes, int n_in,
                              void* d_out, int out_size, void* d_ws, size_t ws_size,
                              hipStream_t stream) {
  const float* x    = (const float*)d_in[0];
  const float* Wq   = (const float*)d_in[1];
  const float* Wk   = (const float*)d_in[2];
  const float* Wv   = (const float*)d_in[3];
  const float* Wo   = (const float*)d_in[4];
  const float* W1   = (const float*)d_in[5];
  const float* W2   = (const float*)d_in[6];
  const float* g1   = (const float*)d_in[7];
  const float* b1   = (const float*)d_in[8];
  const float* g2   = (const float*)d_in[9];
  const float* b2   = (const float*)d_in[10];
  const float* temp = (const float*)d_in[11];
  const float* beta = (const float*)d_in[12];
  const float* tau  = (const float*)d_in[13];
  const float* lam  = (const float*)d_in[14];

  float* ws = (float*)d_ws;
  float* y1   = ws;                    // 1050624   (2048x513)
  float* qkvs = ws + 1050624;          // 3145728   (2048x1536)
  float* Qa   = ws + 4196352;          // 1064960   (16x1024x65)
  float* Kaa  = ws + 5261312;          // 1064960
  float* VT   = ws + 6326272;          // 1048576   (16x1024x64)
  float* qt   = ws + 7374848;          // 16384
  float* kt   = ws + 7391232;          // 16384
  float* Bi   = ws + 7407616;          // 16384
  float* mt   = ws + 7424000;          // 1048576   (16x1024x64)
  float* S    = ws + 8472576;          // 16777216  (16x1024x1024)
  // aliases (S dead after PV GEMM; y1/qkvs dead after qkv_post)
  float* attn = S;                     // 1050624   (2048x513)
  float* outs = S + 1050624;           // 1048576   (2048x512)
  float* y2   = S + 2099200;           // 1050624   (2048x513)
  float* tmp  = S + 3149824;           // 1048576   (2048x512)
  float* h    = ws;                    // 4196352   (2048x2049) aliases y1+qkvs

  // 1. LN1
  ln_fwd<<<2048, 256, 0, stream>>>(x, g1, b1, y1);

  // 2. QKV projections: qkvs[:, 0:512|512:1024|1024:1536] = y1 @ W{q,k,v}^T
  gemm_k<128,128,8,8,0,true><<<dim3(16,4,1),256,0,stream>>>(
      y1,513,0, Wq,513,0, qkvs,1536,0, 513,
      nullptr,nullptr,nullptr,nullptr,nullptr,nullptr);
  gemm_k<128,128,8,8,0,true><<<dim3(16,4,1),256,0,stream>>>(
      y1,513,0, Wk,513,0, qkvs+512,1536,0, 513,
      nullptr,nullptr,nullptr,nullptr,nullptr,nullptr);
  gemm_k<128,128,8,8,0,true><<<dim3(16,4,1),256,0,stream>>>(
      y1,513,0, Wv,513,0, qkvs+1024,1536,0, 513,
      nullptr,nullptr,nullptr,nullptr,nullptr,nullptr);

  // 3. split heads, add_time, v_tan, per-row attention constants
  qkv_post<<<2048, 512, 0, stream>>>(qkvs, Qa, Kaa, VT, qt, kt, Bi, beta);

  // 4. batched QK^T (65-dim) + fused score-logit epilogue
  gemm_k<128,128,8,8,2,true><<<dim3(8,8,16),256,0,stream>>>(
      Qa,65,(long)1024*65, Kaa,65,(long)1024*65, S,1024,(long)1024*1024, 65,
      qt,Bi,kt, lam,tau,temp);

  // 5. row softmax (in place, normalized incl. the +1e-8 denom)
  softmax_rows<<<16384, 256, 0, stream>>>(S);

  // 6. batched PV: mt = S @ VT   (B not transposed)
  gemm_k<128,64,8,4,0,false><<<dim3(8,1,16),256,0,stream>>>(
      S,1024,(long)1024*1024, VT,64,(long)1024*64, mt,64,(long)1024*64, 1024,
      nullptr,nullptr,nullptr,nullptr,nullptr,nullptr);

  // 7. expmap0 + merge heads -> attn (2048x513)
  merge_heads<<<2048, 512, 0, stream>>>(mt, attn);

  // 8. Wo projection
  gemm_k<128,128,8,8,0,true><<<dim3(16,4,1),256,0,stream>>>(
      attn,513,0, Wo,513,0, tmp,512,0, 513,
      nullptr,nullptr,nullptr,nullptr,nullptr,nullptr);

  // 9. residual + LN2 (+ keep out_s)
  res_ln<<<2048, 256, 0, stream>>>(tmp, x, g2, b2, outs, y2);

  // 10. FFN up + exact GELU (writes spatial part of h at col 1)
  gemm_k<128,128,8,8,1,true><<<dim3(16,16,1),256,0,stream>>>(
      y2,513,0, W1,513,0, h+1,2049,0, 513,
      nullptr,nullptr,nullptr,nullptr,nullptr,nullptr);

  // 11. add_time over 2048 dims -> h col 0
  addtime_row<<<2048, 256, 0, stream>>>(h, 2048, 2049);

  // 12. FFN down
  gemm_k<128,128,8,8,0,true><<<dim3(16,4,1),256,0,stream>>>(
      h,2049,0, W2,2049,0, tmp,512,0, 2049,
      nullptr,nullptr,nullptr,nullptr,nullptr,nullptr);

  // 13. final residual + add_time -> d_out
  final_k<<<2048, 256, 0, stream>>>(tmp, outs, (float*)d_out);
}

// Round 2
// 494.426 us; speedup vs baseline: 6.2957x; 6.2957x over previous
//
#include <hip/hip_runtime.h>
#include <math.h>

#define DEV static __device__ __forceinline__

typedef __bf16 bf16_t;
typedef __bf16 bf16x8 __attribute__((ext_vector_type(8)));
typedef __bf16 bf16x4v __attribute__((ext_vector_type(4)));
typedef float f32x4 __attribute__((ext_vector_type(4)));

DEV float softplusf_(float x){
  return x > 0.f ? x + log1pf(expf(-x)) : log1pf(expf(x));
}

DEV void gl_lds16(const void* g, void* l) {
  __builtin_amdgcn_global_load_lds((const __attribute__((address_space(1))) void*)g,
                                   (__attribute__((address_space(3))) void*)l, 16, 0, 0);
}

DEV float waveReduceSum(float v){
  #pragma unroll
  for (int o = 32; o > 0; o >>= 1) v += __shfl_xor(v, o, 64);
  return v;
}
DEV float waveReduceMax(float v){
  #pragma unroll
  for (int o = 32; o > 0; o >>= 1) v = fmaxf(v, __shfl_xor(v, o, 64));
  return v;
}
DEV float blockReduceSum(float v, float* sh){
  v = waveReduceSum(v);
  int w = threadIdx.x >> 6;
  int nw = blockDim.x >> 6;
  __syncthreads();
  if ((threadIdx.x & 63) == 0) sh[w] = v;
  __syncthreads();
  float r = sh[0];
  for (int i = 1; i < nw; i++) r += sh[i];
  return r;
}
DEV float blockReduceMax(float v, float* sh){
  v = waveReduceMax(v);
  int w = threadIdx.x >> 6;
  int nw = blockDim.x >> 6;
  __syncthreads();
  if ((threadIdx.x & 63) == 0) sh[w] = v;
  __syncthreads();
  float r = sh[0];
  for (int i = 1; i < nw; i++) r = fmaxf(r, sh[i]);
  return r;
}

// ---------------- fp32 [N][K] -> bf16 [N][Kp] zero-padded ----------------
__global__ __launch_bounds__(256) void conv_pad(
    const float* __restrict__ in, bf16_t* __restrict__ out, int K, int Kp, long total)
{
  long i = (long)blockIdx.x * 256 + threadIdx.x;
  if (i >= total) return;
  long r = i / Kp;
  int c = (int)(i - r * Kp);
  out[i] = (c < K) ? (bf16_t)in[r * K + c] : (bf16_t)0.f;
}

// ---------------- LN1: fp32 x [2048][513] -> bf16 y1b [2048][544] ----------------
__global__ __launch_bounds__(256) void ln_fwd(
    const float* __restrict__ xin,
    const float* __restrict__ g, const float* __restrict__ b,
    bf16_t* __restrict__ y)
{
  __shared__ float sh[8];
  int row = blockIdx.x;
  const float* xr = xin + (long)row * 513 + 1;
  int t = threadIdx.x;
  float a0 = xr[t], a1 = xr[t + 256];
  float s  = blockReduceSum(a0 + a1, sh);
  float s2 = blockReduceSum(a0 * a0 + a1 * a1, sh);
  float mu = s * (1.f / 512.f);
  float var = s2 * (1.f / 512.f) - mu * mu;
  float inv = rsqrtf(var + 1e-5f);
  float y0 = (a0 - mu) * inv * g[t] + b[t];
  float y1v = (a1 - mu) * inv * g[t + 256] + b[t + 256];
  float q = blockReduceSum(y0 * y0 + y1v * y1v, sh);
  bf16_t* yr = y + (long)row * 544;
  yr[1 + t] = (bf16_t)y0;
  yr[1 + t + 256] = (bf16_t)y1v;
  if (t == 0) yr[0] = (bf16_t)sqrtf(q + 1.f);
  if (t < 31) yr[513 + t] = (bf16_t)0.f;
}

// ------------- residual + LN2 + add_time; outs fp32, y2b bf16 padded -------------
__global__ __launch_bounds__(256) void res_ln(
    const float* __restrict__ wo,
    const float* __restrict__ xin,
    const float* __restrict__ g, const float* __restrict__ b,
    float* __restrict__ outs,
    bf16_t* __restrict__ y)
{
  __shared__ float sh[8];
  int row = blockIdx.x;
  int t = threadIdx.x;
  float a0 = wo[(long)row * 512 + t]       + xin[(long)row * 513 + 1 + t];
  float a1 = wo[(long)row * 512 + t + 256] + xin[(long)row * 513 + 1 + t + 256];
  outs[(long)row * 512 + t] = a0;
  outs[(long)row * 512 + t + 256] = a1;
  float s  = blockReduceSum(a0 + a1, sh);
  float s2 = blockReduceSum(a0 * a0 + a1 * a1, sh);
  float mu = s * (1.f / 512.f);
  float var = s2 * (1.f / 512.f) - mu * mu;
  float inv = rsqrtf(var + 1e-5f);
  float y0 = (a0 - mu) * inv * g[t] + b[t];
  float y1v = (a1 - mu) * inv * g[t + 256] + b[t + 256];
  float q = blockReduceSum(y0 * y0 + y1v * y1v, sh);
  bf16_t* yr = y + (long)row * 544;
  yr[1 + t] = (bf16_t)y0;
  yr[1 + t + 256] = (bf16_t)y1v;
  if (t == 0) yr[0] = (bf16_t)sqrtf(q + 1.f);
  if (t < 31) yr[513 + t] = (bf16_t)0.f;
}

// ------------- add_time over bf16 h [2048][2080] (col0 = time, pad cols zeroed) -------------
__global__ __launch_bounds__(256) void addtime_row(bf16_t* __restrict__ h)
{
  __shared__ float sh[8];
  int row = blockIdx.x;
  bf16_t* hr = h + (long)row * 2080;
  float s2 = 0.f;
  for (int c = threadIdx.x; c < 2048; c += 256) {
    float v = (float)hr[1 + c];
    s2 = fmaf(v, v, s2);
  }
  s2 = blockReduceSum(s2, sh);
  if (threadIdx.x == 0) hr[0] = (bf16_t)sqrtf(s2 + 1.f);
  if (threadIdx.x < 31) hr[2049 + threadIdx.x] = (bf16_t)0.f;
}

// ------------- final: out_s = h2 + outs ; write [t, out_s] fp32 -------------
__global__ __launch_bounds__(256) void final_k(
    const float* __restrict__ h2, const float* __restrict__ outs,
    float* __restrict__ out)
{
  __shared__ float sh[8];
  int row = blockIdx.x;
  int t = threadIdx.x;
  float o0 = h2[(long)row * 512 + t]       + outs[(long)row * 512 + t];
  float o1 = h2[(long)row * 512 + t + 256] + outs[(long)row * 512 + t + 256];
  float q = blockReduceSum(o0 * o0 + o1 * o1, sh);
  float* yr = out + (long)row * 513;
  yr[1 + t] = o0;
  yr[1 + t + 256] = o1;
  if (t == 0) yr[0] = sqrtf(q + 1.f);
}

// ------------- QKV post: heads, add_time, Qa/Ka bf16 (K=96 padded), v_tan bf16 -------------
__global__ __launch_bounds__(512) void qkv_post(
    const float* __restrict__ S,      // [2048][1536]
    bf16_t* __restrict__ Qab,         // [16][1024][96]
    bf16_t* __restrict__ Kab,         // [16][1024][96]
    bf16_t* __restrict__ VTb,         // [16][1024][64]
    float* __restrict__ qt, float* __restrict__ kt, float* __restrict__ Bi,
    const float* __restrict__ beta_p)
{
  int row = blockIdx.x;
  int b = row >> 10, n = row & 1023;
  int h = threadIdx.x >> 6, d = threadIdx.x & 63;
  long base = (long)row * 1536;
  float qv = S[base + h * 64 + d];
  float kv = S[base + 512 + h * 64 + d];
  float vv = S[base + 1024 + h * 64 + d];
  float q2 = waveReduceSum(qv * qv);
  float k2 = waveReduceSum(kv * kv);
  float v2 = waveReduceSum(vv * vv);
  float qT = sqrtf(1.f + q2);
  float kT = sqrtf(1.f + k2);
  float vTt = sqrtf(1.f + v2);
  float sn = fmaxf(sqrtf(v2), 1e-8f);
  float dd = acoshf(fmaxf(vTt, 1.f));
  int z = b * 8 + h;
  long a96 = ((long)z * 1024 + n) * 96;
  Qab[a96 + d] = (bf16_t)qv;
  Kab[a96 + d] = (bf16_t)kv;
  VTb[((long)z * 1024 + n) * 64 + d] = (bf16_t)(dd * vv / sn);
  if (d == 0) {
    Qab[a96 + 64] = (bf16_t)qT;
    Kab[a96 + 64] = (bf16_t)(-kT);
    int ob = z * 1024 + n;
    qt[ob] = qT;
    kt[ob] = kT;
    float beta = softplusf_(beta_p[0]);
    float ct = acoshf(fmaxf(qT, 1.001f));
    float rr = beta / sinhf(ct);
    Bi[ob] = sqrtf(fmaxf(1.f - rr * rr, 0.f) + 1e-8f);
  }
  if (d < 31) {
    Qab[a96 + 65 + d] = (bf16_t)0.f;
    Kab[a96 + 65 + d] = (bf16_t)0.f;
  }
}

// ------------- merge heads: expmap0 + concat -> attnb bf16 [2048][544] -------------
__global__ __launch_bounds__(512) void merge_heads(
    const float* __restrict__ mt, bf16_t* __restrict__ attn)
{
  __shared__ float t2s[8];
  int row = blockIdx.x;
  int b = row >> 10, n = row & 1023;
  int h = threadIdx.x >> 6, d = threadIdx.x & 63;
  int z = b * 8 + h;
  float v = mt[((long)z * 1024 + n) * 64 + d];
  float s2 = waveReduceSum(v * v);
  float nn = fmaxf(sqrtf(s2), 1e-8f);
  float coef = sinhf(nn) / nn;
  attn[(long)row * 544 + 1 + h * 64 + d] = (bf16_t)(coef * v);
  if (d == 0) {
    float th = coshf(nn);
    t2s[h] = th * th;
  }
  __syncthreads();
  if (threadIdx.x == 0) {
    float t2 = t2s[0] + t2s[1] + t2s[2] + t2s[3] + t2s[4] + t2s[5] + t2s[6] + t2s[7] - 7.f;
    attn[(long)row * 544] = (bf16_t)sqrtf(fmaxf(t2, 1e-8f));
  }
  if (threadIdx.x < 31) attn[(long)row * 544 + 513 + threadIdx.x] = (bf16_t)0.f;
}

// ------------- row softmax over 1024: fp32 S in -> bf16 P out (P aliases S) -------------
__global__ __launch_bounds__(256) void softmax_rows(
    const float* __restrict__ S, bf16_t* __restrict__ P)
{
  __shared__ float sh[8];
  long row = blockIdx.x;
  const float* p = S + row * 1024;
  int t = threadIdx.x;
  float4 x = *(const float4*)&p[t * 4];
  float mx = fmaxf(fmaxf(x.x, x.y), fmaxf(x.z, x.w));
  mx = blockReduceMax(mx, sh);
  float4 e;
  e.x = expf(x.x - mx);
  e.y = expf(x.y - mx);
  e.z = expf(x.z - mx);
  e.w = expf(x.w - mx);
  float sum = blockReduceSum(e.x + e.y + e.z + e.w, sh);
  float sc = 1.f / (sum * (1.f + 1e-8f));
  bf16x4v o;
  o[0] = (bf16_t)(e.x * sc); o[1] = (bf16_t)(e.y * sc);
  o[2] = (bf16_t)(e.z * sc); o[3] = (bf16_t)(e.w * sc);
  *(bf16x4v*)&P[row * 1024 + t * 4] = o;
}

// ------------- bf16 MFMA GEMM: C = A @ B^T (BKN=false, B=[N][K]) or A @ B (BKN=true, B=[K][N]) -------------
// ACT: 0 fp32 write, 1 GELU->bf16 write, 2 score-logit epilogue -> fp32
template<int BM, int BN, int WM, int WN, int ACT, bool BKN>
__global__ __launch_bounds__(256) void gemm_mfma(
    const bf16_t* __restrict__ Ag, int lda, long sA,
    const bf16_t* __restrict__ Bg, int ldb, long sB,
    void* __restrict__ Cg, int ldc, long sC,
    int K,
    const float* __restrict__ qt, const float* __restrict__ Bi,
    const float* __restrict__ kt,
    const float* __restrict__ lam_p, const float* __restrict__ tau_p,
    const float* __restrict__ temp_p)
{
  constexpr int MI = WM / 16, NJ = WN / 16;
  constexpr int NWN = BN / WN;
  __shared__ bf16_t As[BM][32];
  __shared__ bf16_t Bs[BN][32];
  const int t = threadIdx.x;
  const int wid = t >> 6, lane = t & 63;
  const int lm = lane & 15, lh = lane >> 4;
  const int z = blockIdx.z;
  const bf16_t* A = Ag + (long)z * sA;
  const bf16_t* B = Bg + (long)z * sB;
  const int bm = blockIdx.x * BM;
  const int bn = blockIdx.y * BN;
  const int wm = (wid / NWN) * WM;
  const int wn = (wid % NWN) * WN;
  f32x4 acc[MI][NJ] = {};

  for (int kk = 0; kk < K; kk += 32) {
    __syncthreads();
    #pragma unroll
    for (int r = 0; r < BM / 64; r++) {
      int chunk = r * 4 + wid;
      const char* src = (const char*)(A + (long)(bm + chunk * 16 + (lane >> 2)) * lda + kk)
                        + (lane & 3) * 16;
      gl_lds16(src, (char*)&As[0][0] + chunk * 1024);
    }
    if constexpr (!BKN) {
      #pragma unroll
      for (int r = 0; r < BN / 64; r++) {
        int chunk = r * 4 + wid;
        const char* src = (const char*)(B + (long)(bn + chunk * 16 + (lane >> 2)) * ldb + kk)
                          + (lane & 3) * 16;
        gl_lds16(src, (char*)&Bs[0][0] + chunk * 1024);
      }
    } else {
      // B is [K][N], BN == 64: transpose-stage via registers
      int k = t & 31, n0 = (t >> 5) * 8;
      bf16x8 v = *(const bf16x8*)(B + (long)(kk + k) * ldb + bn + n0);
      #pragma unroll
      for (int i = 0; i < 8; i++) Bs[n0 + i][k] = v[i];
    }
    __syncthreads();
    bf16x8 af[MI], bfr[NJ];
    #pragma unroll
    for (int i = 0; i < MI; i++) af[i] = *(const bf16x8*)&As[wm + i * 16 + lm][lh * 8];
    #pragma unroll
    for (int j = 0; j < NJ; j++) bfr[j] = *(const bf16x8*)&Bs[wn + j * 16 + lm][lh * 8];
    #pragma unroll
    for (int i = 0; i < MI; i++)
      #pragma unroll
      for (int j = 0; j < NJ; j++)
        acc[i][j] = __builtin_amdgcn_mfma_f32_16x16x32_bf16(af[i], bfr[j], acc[i][j], 0, 0, 0);
  }

  if constexpr (ACT == 2) {
    float lam = softplusf_(lam_p[0]);
    float tau = softplusf_(tau_p[0]);
    float invT = 1.f / temp_p[0];
    float* C = (float*)Cg + (long)z * sC;
    #pragma unroll
    for (int i = 0; i < MI; i++) {
      #pragma unroll
      for (int q = 0; q < 4; q++) {
        int row = bm + wm + i * 16 + lh * 4 + q;
        int gi = z * 1024 + row;
        float qtv = qt[gi], Biv = Bi[gi];
        float nOQ = fmaxf(qtv * qtv - 1.f, 0.f);
        #pragma unroll
        for (int j = 0; j < NJ; j++) {
          int col = bn + wn + j * 16 + lm;
          float ktv = kt[z * 1024 + col];
          float inner = acc[i][j][q];
          float nQK = fmaxf(inner * inner - 1.f, 0.f);
          float numer = -(ktv + inner * qtv);
          float denom = sqrtf(nQK * nOQ + 2.5e-5f);
          float Zc = fminf(fmaxf(numer / denom, -1.f), 1.f);
          float dist = acoshf(fmaxf(-inner, 1.001f));
          float sd = (40.f / 15.f) * tanhf(dist * 0.025f);
          float H = sd + softplusf_(-2.f * sd) - 0.69314718055994531f;
          float Phi = softplusf_(Biv + Zc - 0.1f) - 0.64439666007357095f;
          C[(long)row * ldc + col] = (-lam * H - tau * Phi) * invT;
        }
      }
    }
  } else if constexpr (ACT == 1) {
    bf16_t* C = (bf16_t*)Cg;
    #pragma unroll
    for (int i = 0; i < MI; i++) {
      #pragma unroll
      for (int q = 0; q < 4; q++) {
        long row = bm + wm + i * 16 + lh * 4 + q;
        #pragma unroll
        for (int j = 0; j < NJ; j++) {
          int col = bn + wn + j * 16 + lm;
          float v = acc[i][j][q];
          C[row * ldc + col] = (bf16_t)(0.5f * v * (1.f + erff(v * 0.70710678118654752f)));
        }
      }
    }
  } else {
    float* C = (float*)Cg + (long)z * sC;
    #pragma unroll
    for (int i = 0; i < MI; i++) {
      #pragma unroll
      for (int q = 0; q < 4; q++) {
        long row = bm + wm + i * 16 + lh * 4 + q;
        #pragma unroll
        for (int j = 0; j < NJ; j++) {
          int col = bn + wn + j * 16 + lm;
          C[row * ldc + col] = acc[i][j][q];
        }
      }
    }
  }
}

extern "C" void kernel_launch(void* const* d_in, const int* in_sizes, int n_in,
                              void* d_out, int out_size, void* d_ws, size_t ws_size,
                              hipStream_t stream) {
  const float* x    = (const float*)d_in[0];
  const float* Wq   = (const float*)d_in[1];
  const float* Wk   = (const float*)d_in[2];
  const float* Wv   = (const float*)d_in[3];
  const float* Wo   = (const float*)d_in[4];
  const float* W1   = (const float*)d_in[5];
  const float* W2   = (const float*)d_in[6];
  const float* g1   = (const float*)d_in[7];
  const float* b1   = (const float*)d_in[8];
  const float* g2   = (const float*)d_in[9];
  const float* b2   = (const float*)d_in[10];
  const float* temp = (const float*)d_in[11];
  const float* beta = (const float*)d_in[12];
  const float* tau  = (const float*)d_in[13];
  const float* lam  = (const float*)d_in[14];

  char* W = (char*)d_ws;
  bf16_t* Wqkvb = (bf16_t*)(W + 0);          // [1536][544]
  bf16_t* Wob   = (bf16_t*)(W + 1671168);    // [512][544]
  bf16_t* W1b   = (bf16_t*)(W + 2228224);    // [2048][544]
  bf16_t* W2b   = (bf16_t*)(W + 4456448);    // [512][2080]
  bf16_t* y1b   = (bf16_t*)(W + 6586368);    // [2048][544]
  float*  qkvs  = (float*) (W + 8814592);    // [2048][1536]
  float*  mt    = (float*) (W + 8814592);    // [16][1024][64]  (aliases qkvs, used after)
  bf16_t* Qab   = (bf16_t*)(W + 21397504);   // [16][1024][96]
  bf16_t* Kab   = (bf16_t*)(W + 24543232);   // [16][1024][96]
  bf16_t* VTb   = (bf16_t*)(W + 27688960);   // [16][1024][64]
  float*  qt    = (float*) (W + 29786112);
  float*  kt    = (float*) (W + 29851648);
  float*  Bi    = (float*) (W + 29917184);
  float*  S     = (float*) (W + 29982720);   // [16][1024][1024] fp32
  bf16_t* Pb    = (bf16_t*)S;                // bf16 alias (in-place after softmax)
  float*  outs  = (float*) (W + 63537152);   // [2048][512]   (inside dead upper half of S)
  bf16_t* y2b   = (bf16_t*)(W + 67731456);   // [2048][544]
  bf16_t* hb    = (bf16_t*)(W + 69959680);   // [2048][2080]
  float*  tmp   = (float*) (W + 78479360);   // [2048][512]
  bf16_t* attnb = y1b;                       // alias (y1b dead after QKV GEMM)

  // 0. weight conversions (bf16, K zero-padded)
  conv_pad<<<1088, 256, 0, stream>>>(Wq, Wqkvb,               513, 544, (long)512*544);
  conv_pad<<<1088, 256, 0, stream>>>(Wk, Wqkvb + 512*544,     513, 544, (long)512*544);
  conv_pad<<<1088, 256, 0, stream>>>(Wv, Wqkvb + 1024*544,    513, 544, (long)512*544);
  conv_pad<<<1088, 256, 0, stream>>>(Wo, Wob,                 513, 544, (long)512*544);
  conv_pad<<<4352, 256, 0, stream>>>(W1, W1b,                 513, 544, (long)2048*544);
  conv_pad<<<4160, 256, 0, stream>>>(W2, W2b,                2049, 2080, (long)512*2080);

  // 1. LN1 -> bf16
  ln_fwd<<<2048, 256, 0, stream>>>(x, g1, b1, y1b);

  // 2. fused QKV projection: qkvs = y1 @ [Wq|Wk|Wv]^T
  gemm_mfma<128,128,64,64,0,false><<<dim3(16,12,1),256,0,stream>>>(
      y1b,544,0, Wqkvb,544,0, qkvs,1536,0, 544,
      nullptr,nullptr,nullptr,nullptr,nullptr,nullptr);

  // 3. heads + add_time + v_tan + per-row constants
  qkv_post<<<2048, 512, 0, stream>>>(qkvs, Qab, Kab, VTb, qt, kt, Bi, beta);

  // 4. batched QK^T (K=96) + fused score-logit epilogue -> fp32 S
  gemm_mfma<128,128,64,64,2,false><<<dim3(8,8,16),256,0,stream>>>(
      Qab,96,(long)1024*96, Kab,96,(long)1024*96, S,1024,(long)1024*1024, 96,
      qt,Bi,kt, lam,tau,temp);

  // 5. row softmax -> bf16 P (in place)
  softmax_rows<<<16384, 256, 0, stream>>>(S, Pb);

  // 6. batched PV: mt = P @ VT  (B=[K][N], transpose-staged)
  gemm_mfma<64,64,32,32,0,true><<<dim3(16,1,16),256,0,stream>>>(
      Pb,1024,(long)1024*1024, VTb,64,(long)1024*64, mt,64,(long)1024*64, 1024,
      nullptr,nullptr,nullptr,nullptr,nullptr,nullptr);

  // 7. expmap0 + merge heads -> attnb bf16
  merge_heads<<<2048, 512, 0, stream>>>(mt, attnb);

  // 8. Wo projection -> fp32 tmp
  gemm_mfma<128,128,64,64,0,false><<<dim3(16,4,1),256,0,stream>>>(
      attnb,544,0, Wob,544,0, tmp,512,0, 544,
      nullptr,nullptr,nullptr,nullptr,nullptr,nullptr);

  // 9. residual + LN2
  res_ln<<<2048, 256, 0, stream>>>(tmp, x, g2, b2, outs, y2b);

  // 10. FFN up + exact GELU -> bf16 hb (cols 1..2048)
  gemm_mfma<128,128,64,64,1,false><<<dim3(16,16,1),256,0,stream>>>(
      y2b,544,0, W1b,544,0, hb+1,2080,0, 544,
      nullptr,nullptr,nullptr,nullptr,nullptr,nullptr);

  // 11. time coordinate for h
  addtime_row<<<2048, 256, 0, stream>>>(hb);

  // 12. FFN down -> fp32 tmp
  gemm_mfma<128,128,64,64,0,false><<<dim3(16,4,1),256,0,stream>>>(
      hb,2080,0, W2b,2080,0, tmp,512,0, 2080,
      nullptr,nullptr,nullptr,nullptr,nullptr,nullptr);

  // 13. final residual + add_time -> d_out
  final_k<<<2048, 256, 0, stream>>>(tmp, outs, (float*)d_out);
}

// Round 3
// 260.394 us; speedup vs baseline: 11.9541x; 1.8988x over previous
//
#include <hip/hip_runtime.h>
#include <math.h>

#define DEV static __device__ __forceinline__

typedef __bf16 bf16_t;
typedef __bf16 bf16x8 __attribute__((ext_vector_type(8)));
typedef float f32x4 __attribute__((ext_vector_type(4)));

// ---------- fast transcendentals (v_exp_f32 / v_log_f32 / v_rcp_f32) ----------
DEV float frcp(float x){ return __builtin_amdgcn_rcpf(x); }
DEV float tanh_fast(float z){           // |z| modest; e^{2z} finite for |z|<40
  float e2 = __expf(2.f * z);
  return (e2 - 1.f) * frcp(e2 + 1.f);
}
DEV float softplus_fast(float x){       // branchless, any x
  return fmaxf(x, 0.f) + __logf(1.f + __expf(-fabsf(x)));
}
DEV float softplus_exact(float x){      // for scalar params (lam/tau/beta)
  return x > 0.f ? x + log1pf(expf(-x)) : log1pf(expf(x));
}
DEV float gelu_fast(float v){
  float u = 0.7978845608028654f * fmaf(0.044715f * v, v * v, v);
  u = fminf(fmaxf(u, -15.f), 15.f);
  return 0.5f * v * (1.f + tanh_fast(u));
}

DEV void gl_lds16(const void* g, void* l) {
  __builtin_amdgcn_global_load_lds((const __attribute__((address_space(1))) void*)g,
                                   (__attribute__((address_space(3))) void*)l, 16, 0, 0);
}

DEV float waveReduceSum(float v){
  #pragma unroll
  for (int o = 32; o > 0; o >>= 1) v += __shfl_xor(v, o, 64);
  return v;
}
DEV float waveReduceMax(float v){
  #pragma unroll
  for (int o = 32; o > 0; o >>= 1) v = fmaxf(v, __shfl_xor(v, o, 64));
  return v;
}
DEV float blockReduceSum(float v, float* sh){
  v = waveReduceSum(v);
  int w = threadIdx.x >> 6;
  int nw = blockDim.x >> 6;
  __syncthreads();
  if ((threadIdx.x & 63) == 0) sh[w] = v;
  __syncthreads();
  float r = sh[0];
  for (int i = 1; i < nw; i++) r += sh[i];
  return r;
}
DEV float blockReduceMax(float v, float* sh){
  v = waveReduceMax(v);
  int w = threadIdx.x >> 6;
  int nw = blockDim.x >> 6;
  __syncthreads();
  if ((threadIdx.x & 63) == 0) sh[w] = v;
  __syncthreads();
  float r = sh[0];
  for (int i = 1; i < nw; i++) r = fmaxf(r, sh[i]);
  return r;
}

// ---------------- weight conversions ----------------
__global__ __launch_bounds__(256) void conv_pad(
    const float* __restrict__ in, bf16_t* __restrict__ out, int K, int Kp, long total)
{
  long i = (long)blockIdx.x * 256 + threadIdx.x;
  if (i >= total) return;
  long r = i / Kp;
  int c = (int)(i - r * Kp);
  out[i] = (c < K) ? (bf16_t)in[r * K + c] : (bf16_t)0.f;
}
// fused Wq|Wk|Wv|Wo (each [512][513] -> [512][544])
__global__ __launch_bounds__(256) void conv_qkvo(
    const float* __restrict__ Wq, const float* __restrict__ Wk,
    const float* __restrict__ Wv, const float* __restrict__ Wo,
    bf16_t* __restrict__ outQKV, bf16_t* __restrict__ outO)
{
  long i = (long)blockIdx.x * 256 + threadIdx.x;
  if (i >= (long)4 * 512 * 544) return;
  int w = (int)(i / (512 * 544));
  long rem = i - (long)w * 512 * 544;
  long r = rem / 544;
  int c = (int)(rem - r * 544);
  const float* src = (w == 0) ? Wq : (w == 1) ? Wk : (w == 2) ? Wv : Wo;
  float v = (c < 513) ? src[r * 513 + c] : 0.f;
  if (w < 3) outQKV[(long)w * 512 * 544 + rem] = (bf16_t)v;
  else       outO[rem] = (bf16_t)v;
}

// ---------------- LN1 ----------------
__global__ __launch_bounds__(256) void ln_fwd(
    const float* __restrict__ xin,
    const float* __restrict__ g, const float* __restrict__ b,
    bf16_t* __restrict__ y)
{
  __shared__ float sh[8];
  int row = blockIdx.x;
  const float* xr = xin + (long)row * 513 + 1;
  int t = threadIdx.x;
  float a0 = xr[t], a1 = xr[t + 256];
  float s  = blockReduceSum(a0 + a1, sh);
  float s2 = blockReduceSum(a0 * a0 + a1 * a1, sh);
  float mu = s * (1.f / 512.f);
  float var = s2 * (1.f / 512.f) - mu * mu;
  float inv = rsqrtf(var + 1e-5f);
  float y0 = (a0 - mu) * inv * g[t] + b[t];
  float y1v = (a1 - mu) * inv * g[t + 256] + b[t + 256];
  float q = blockReduceSum(y0 * y0 + y1v * y1v, sh);
  bf16_t* yr = y + (long)row * 544;
  yr[1 + t] = (bf16_t)y0;
  yr[1 + t + 256] = (bf16_t)y1v;
  if (t == 0) yr[0] = (bf16_t)sqrtf(q + 1.f);
  if (t < 31) yr[513 + t] = (bf16_t)0.f;
}

// ---------------- residual + LN2 ----------------
__global__ __launch_bounds__(256) void res_ln(
    const float* __restrict__ wo,
    const float* __restrict__ xin,
    const float* __restrict__ g, const float* __restrict__ b,
    float* __restrict__ outs,
    bf16_t* __restrict__ y)
{
  __shared__ float sh[8];
  int row = blockIdx.x;
  int t = threadIdx.x;
  float a0 = wo[(long)row * 512 + t]       + xin[(long)row * 513 + 1 + t];
  float a1 = wo[(long)row * 512 + t + 256] + xin[(long)row * 513 + 1 + t + 256];
  outs[(long)row * 512 + t] = a0;
  outs[(long)row * 512 + t + 256] = a1;
  float s  = blockReduceSum(a0 + a1, sh);
  float s2 = blockReduceSum(a0 * a0 + a1 * a1, sh);
  float mu = s * (1.f / 512.f);
  float var = s2 * (1.f / 512.f) - mu * mu;
  float inv = rsqrtf(var + 1e-5f);
  float y0 = (a0 - mu) * inv * g[t] + b[t];
  float y1v = (a1 - mu) * inv * g[t + 256] + b[t + 256];
  float q = blockReduceSum(y0 * y0 + y1v * y1v, sh);
  bf16_t* yr = y + (long)row * 544;
  yr[1 + t] = (bf16_t)y0;
  yr[1 + t + 256] = (bf16_t)y1v;
  if (t == 0) yr[0] = (bf16_t)sqrtf(q + 1.f);
  if (t < 31) yr[513 + t] = (bf16_t)0.f;
}

// ---------------- add_time over bf16 h [2048][2080], vectorized ----------------
__global__ __launch_bounds__(256) void addtime_row(bf16_t* __restrict__ h)
{
  __shared__ float sh[8];
  int row = blockIdx.x;
  bf16_t* hr = h + (long)row * 2080;
  int t = threadIdx.x;
  float s2 = 0.f;
  // chunks 0..255 cover cols 0..2047 (col 0 is time slot: skip j==0 in chunk 0)
  bf16x8 v = *(const bf16x8*)&hr[t * 8];
  #pragma unroll
  for (int j = 0; j < 8; j++) {
    if (t == 0 && j == 0) continue;
    float f = (float)v[j];
    s2 = fmaf(f, f, s2);
  }
  if (t == 0) { float f = (float)hr[2048]; s2 = fmaf(f, f, s2); }
  s2 = blockReduceSum(s2, sh);
  if (t == 0) hr[0] = (bf16_t)sqrtf(s2 + 1.f);
  if (t < 31) hr[2049 + t] = (bf16_t)0.f;
}

// ---------------- final residual + add_time ----------------
__global__ __launch_bounds__(256) void final_k(
    const float* __restrict__ h2, const float* __restrict__ outs,
    float* __restrict__ out)
{
  __shared__ float sh[8];
  int row = blockIdx.x;
  int t = threadIdx.x;
  float o0 = h2[(long)row * 512 + t]       + outs[(long)row * 512 + t];
  float o1 = h2[(long)row * 512 + t + 256] + outs[(long)row * 512 + t + 256];
  float q = blockReduceSum(o0 * o0 + o1 * o1, sh);
  float* yr = out + (long)row * 513;
  yr[1 + t] = o0;
  yr[1 + t + 256] = o1;
  if (t == 0) yr[0] = sqrtf(q + 1.f);
}

// ---------------- QKV post ----------------
__global__ __launch_bounds__(512) void qkv_post(
    const float* __restrict__ S,      // [2048][1536]
    bf16_t* __restrict__ Qab,         // [16][1024][96]
    bf16_t* __restrict__ Kab,         // [16][1024][96]
    bf16_t* __restrict__ VTt,         // [16][64][1024]  (transposed v_tan)
    float* __restrict__ qt, float* __restrict__ kt, float* __restrict__ Bi,
    const float* __restrict__ beta_p)
{
  int row = blockIdx.x;
  int b = row >> 10, n = row & 1023;
  int h = threadIdx.x >> 6, d = threadIdx.x & 63;
  long base = (long)row * 1536;
  float qv = S[base + h * 64 + d];
  float kv = S[base + 512 + h * 64 + d];
  float vv = S[base + 1024 + h * 64 + d];
  float q2 = waveReduceSum(qv * qv);
  float k2 = waveReduceSum(kv * kv);
  float v2 = waveReduceSum(vv * vv);
  float qT = sqrtf(1.f + q2);
  float kT = sqrtf(1.f + k2);
  float vTt_ = sqrtf(1.f + v2);
  float sn0 = sqrtf(v2);
  float dd = __logf(vTt_ + sn0);          // acosh(vTt_)
  float coef = dd * frcp(fmaxf(sn0, 1e-8f));
  int z = b * 8 + h;
  long a96 = ((long)z * 1024 + n) * 96;
  Qab[a96 + d] = (bf16_t)qv;
  Kab[a96 + d] = (bf16_t)kv;
  VTt[((long)z * 64 + d) * 1024 + n] = (bf16_t)(coef * vv);
  if (d == 0) {
    Qab[a96 + 64] = (bf16_t)qT;
    Kab[a96 + 64] = (bf16_t)(-kT);
    int ob = z * 1024 + n;
    qt[ob] = qT;
    kt[ob] = kT;
    float beta = softplus_exact(beta_p[0]);
    float xq = fmaxf(qT, 1.001f);
    float sh_ = sqrtf(fmaxf(xq * xq - 1.f, 0.f));   // sinh(acosh(xq))
    float rr = beta * frcp(sh_);
    Bi[ob] = sqrtf(fmaxf(1.f - rr * rr, 0.f) + 1e-8f);
  }
  if (d < 31) {
    Qab[a96 + 65 + d] = (bf16_t)0.f;
    Kab[a96 + 65 + d] = (bf16_t)0.f;
  }
}

// ---------------- merge heads: expmap0 + concat ----------------
__global__ __launch_bounds__(512) void merge_heads(
    const float* __restrict__ mt, bf16_t* __restrict__ attn)
{
  __shared__ float t2s[8];
  int row = blockIdx.x;
  int b = row >> 10, n = row & 1023;
  int h = threadIdx.x >> 6, d = threadIdx.x & 63;
  int z = b * 8 + h;
  float v = mt[((long)z * 1024 + n) * 64 + d];
  float s2 = waveReduceSum(v * v);
  float nn = fmaxf(sqrtf(s2), 1e-8f);
  float e = __expf(nn), ei = frcp(e);
  float coef = 0.5f * (e - ei) * frcp(nn);        // sinh(nn)/nn
  attn[(long)row * 544 + 1 + h * 64 + d] = (bf16_t)(coef * v);
  if (d == 0) {
    float th = 0.5f * (e + ei);                   // cosh(nn)
    t2s[h] = th * th;
  }
  __syncthreads();
  if (threadIdx.x == 0) {
    float t2 = t2s[0] + t2s[1] + t2s[2] + t2s[3] + t2s[4] + t2s[5] + t2s[6] + t2s[7] - 7.f;
    attn[(long)row * 544] = (bf16_t)sqrtf(fmaxf(t2, 1e-8f));
  }
  if (threadIdx.x < 31) attn[(long)row * 544 + 513 + threadIdx.x] = (bf16_t)0.f;
}

// ---------------- row softmax: fp32 S -> bf16 P (in place) ----------------
__global__ __launch_bounds__(256) void softmax_rows(
    const float* __restrict__ S, bf16_t* __restrict__ P)
{
  __shared__ float sh[8];
  long row = blockIdx.x;
  const float* p = S + row * 1024;
  int t = threadIdx.x;
  float4 x = *(const float4*)&p[t * 4];
  float mx = fmaxf(fmaxf(x.x, x.y), fmaxf(x.z, x.w));
  mx = blockReduceMax(mx, sh);
  float4 e;
  e.x = __expf(x.x - mx);
  e.y = __expf(x.y - mx);
  e.z = __expf(x.z - mx);
  e.w = __expf(x.w - mx);
  float sum = blockReduceSum(e.x + e.y + e.z + e.w, sh);
  float sc = frcp(sum * (1.f + 1e-8f));
  typedef __bf16 bf16x4v __attribute__((ext_vector_type(4)));
  bf16x4v o;
  o[0] = (bf16_t)(e.x * sc); o[1] = (bf16_t)(e.y * sc);
  o[2] = (bf16_t)(e.z * sc); o[3] = (bf16_t)(e.w * sc);
  *(bf16x4v*)&P[row * 1024 + t * 4] = o;
}

// ---------------- bf16 MFMA GEMM body: C = A @ B^T  (B is [N][K]) ----------------
// ACT: 0 fp32 write, 1 GELU->bf16 write, 2 score-logit epilogue -> fp32
template<int BM, int BN, int WM, int WN, int ACT>
DEV void gemm_body(
    const bf16_t* __restrict__ Ag, int lda, long sA,
    const bf16_t* __restrict__ Bg, int ldb, long sB,
    void* __restrict__ Cg, int ldc, long sC,
    int K,
    const float* __restrict__ qt, const float* __restrict__ Bi,
    const float* __restrict__ kt,
    const float* __restrict__ lam_p, const float* __restrict__ tau_p,
    const float* __restrict__ temp_p)
{
  constexpr int MI = WM / 16, NJ = WN / 16;
  constexpr int NWN = BN / WN;
  __shared__ bf16_t As[BM][32];
  __shared__ bf16_t Bs[BN][32];
  const int t = threadIdx.x;
  const int wid = t >> 6, lane = t & 63;
  const int lm = lane & 15, lh = lane >> 4;
  const int z = blockIdx.z;
  const bf16_t* A = Ag + (long)z * sA;
  const bf16_t* B = Bg + (long)z * sB;
  const int bm = blockIdx.x * BM;
  const int bn = blockIdx.y * BN;
  const int wm = (wid / NWN) * WM;
  const int wn = (wid % NWN) * WN;
  f32x4 acc[MI][NJ] = {};

  for (int kk = 0; kk < K; kk += 32) {
    __syncthreads();
    #pragma unroll
    for (int r = 0; r < BM / 64; r++) {
      int chunk = r * 4 + wid;
      const char* src = (const char*)(A + (long)(bm + chunk * 16 + (lane >> 2)) * lda + kk)
                        + (lane & 3) * 16;
      gl_lds16(src, (char*)&As[0][0] + chunk * 1024);
    }
    #pragma unroll
    for (int r = 0; r < BN / 64; r++) {
      int chunk = r * 4 + wid;
      const char* src = (const char*)(B + (long)(bn + chunk * 16 + (lane >> 2)) * ldb + kk)
                        + (lane & 3) * 16;
      gl_lds16(src, (char*)&Bs[0][0] + chunk * 1024);
    }
    __syncthreads();
    bf16x8 af[MI], bfr[NJ];
    #pragma unroll
    for (int i = 0; i < MI; i++) af[i] = *(const bf16x8*)&As[wm + i * 16 + lm][lh * 8];
    #pragma unroll
    for (int j = 0; j < NJ; j++) bfr[j] = *(const bf16x8*)&Bs[wn + j * 16 + lm][lh * 8];
    #pragma unroll
    for (int i = 0; i < MI; i++)
      #pragma unroll
      for (int j = 0; j < NJ; j++)
        acc[i][j] = __builtin_amdgcn_mfma_f32_16x16x32_bf16(af[i], bfr[j], acc[i][j], 0, 0, 0);
  }

  if constexpr (ACT == 2) {
    float lam = softplus_exact(lam_p[0]);
    float tau = softplus_exact(tau_p[0]);
    float invT = frcp(temp_p[0]);
    float* C = (float*)Cg + (long)z * sC;
    float ktv[NJ];
    #pragma unroll
    for (int j = 0; j < NJ; j++) ktv[j] = kt[z * 1024 + bn + wn + j * 16 + lm];
    #pragma unroll
    for (int i = 0; i < MI; i++) {
      #pragma unroll
      for (int q = 0; q < 4; q++) {
        int row = bm + wm + i * 16 + lh * 4 + q;
        int gi = z * 1024 + row;
        float qtv = qt[gi], Biv = Bi[gi];
        float nOQ = fmaxf(qtv * qtv - 1.f, 0.f);
        #pragma unroll
        for (int j = 0; j < NJ; j++) {
          int col = bn + wn + j * 16 + lm;
          float inner = acc[i][j][q];
          float nQK = fmaxf(inner * inner - 1.f, 0.f);
          float numer = -(ktv[j] + inner * qtv);
          float denom = sqrtf(fmaf(nQK, nOQ, 2.5e-5f));
          float Zc = fminf(fmaxf(numer * frcp(denom), -1.f), 1.f);
          float xx = fmaxf(-inner, 1.001f);
          float dist = __logf(xx + sqrtf(xx * xx - 1.f));     // acosh
          float sd = 2.66666667f * tanh_fast(dist * 0.025f);  // 40*tanh(d/40)/15
          float H = sd + __logf(1.f + __expf(-2.f * sd)) - 0.69314718056f;
          float Phi = softplus_fast(Biv + Zc - 0.1f) - 0.64439666007f;
          C[(long)row * ldc + col] = (-lam * H - tau * Phi) * invT;
        }
      }
    }
  } else if constexpr (ACT == 1) {
    bf16_t* C = (bf16_t*)Cg;
    #pragma unroll
    for (int i = 0; i < MI; i++) {
      #pragma unroll
      for (int q = 0; q < 4; q++) {
        long row = bm + wm + i * 16 + lh * 4 + q;
        #pragma unroll
        for (int j = 0; j < NJ; j++) {
          int col = bn + wn + j * 16 + lm;
          C[row * ldc + col] = (bf16_t)gelu_fast(acc[i][j][q]);
        }
      }
    }
  } else {
    float* C = (float*)Cg + (long)z * sC;
    #pragma unroll
    for (int i = 0; i < MI; i++) {
      #pragma unroll
      for (int q = 0; q < 4; q++) {
        long row = bm + wm + i * 16 + lh * 4 + q;
        #pragma unroll
        for (int j = 0; j < NJ; j++) {
          int col = bn + wn + j * 16 + lm;
          C[row * ldc + col] = acc[i][j][q];
        }
      }
    }
  }
}

// ---- named wrappers (one per pipeline stage, for profiler attribution) ----
#define GEMM_ARGS const bf16_t* A, int lda, long sA, const bf16_t* B, int ldb, long sB, \
                  void* C, int ldc, long sC, int K, \
                  const float* qt, const float* Bi, const float* kt, \
                  const float* lam, const float* tau, const float* temp
#define GEMM_PASS A,lda,sA,B,ldb,sB,C,ldc,sC,K,qt,Bi,kt,lam,tau,temp

__global__ __launch_bounds__(256) void gemm_qkv(GEMM_ARGS){ gemm_body<128,128,64,64,0>(GEMM_PASS); }
__global__ __launch_bounds__(256) void gemm_qk (GEMM_ARGS){ gemm_body<128,128,64,64,2>(GEMM_PASS); }
__global__ __launch_bounds__(256) void gemm_pv (GEMM_ARGS){ gemm_body< 64, 64,32,32,0>(GEMM_PASS); }
__global__ __launch_bounds__(256) void gemm_wo (GEMM_ARGS){ gemm_body<128,128,64,64,0>(GEMM_PASS); }
__global__ __launch_bounds__(256) void gemm_f1 (GEMM_ARGS){ gemm_body<128,128,64,64,1>(GEMM_PASS); }
__global__ __launch_bounds__(256) void gemm_f2 (GEMM_ARGS){ gemm_body<128,128,64,64,0>(GEMM_PASS); }

extern "C" void kernel_launch(void* const* d_in, const int* in_sizes, int n_in,
                              void* d_out, int out_size, void* d_ws, size_t ws_size,
                              hipStream_t stream) {
  const float* x    = (const float*)d_in[0];
  const float* Wq   = (const float*)d_in[1];
  const float* Wk   = (const float*)d_in[2];
  const float* Wv   = (const float*)d_in[3];
  const float* Wo   = (const float*)d_in[4];
  const float* W1   = (const float*)d_in[5];
  const float* W2   = (const float*)d_in[6];
  const float* g1   = (const float*)d_in[7];
  const float* b1   = (const float*)d_in[8];
  const float* g2   = (const float*)d_in[9];
  const float* b2   = (const float*)d_in[10];
  const float* temp = (const float*)d_in[11];
  const float* beta = (const float*)d_in[12];
  const float* tau  = (const float*)d_in[13];
  const float* lam  = (const float*)d_in[14];

  char* W = (char*)d_ws;
  bf16_t* Wqkvb = (bf16_t*)(W + 0);          // [1536][544]
  bf16_t* Wob   = (bf16_t*)(W + 1671168);    // [512][544]
  bf16_t* W1b   = (bf16_t*)(W + 2228224);    // [2048][544]
  bf16_t* W2b   = (bf16_t*)(W + 4456448);    // [512][2080]
  bf16_t* y1b   = (bf16_t*)(W + 6586368);    // [2048][544]
  float*  qkvs  = (float*) (W + 8814592);    // [2048][1536]
  float*  mt    = (float*) (W + 8814592);    // [16][1024][64]  (aliases qkvs)
  bf16_t* Qab   = (bf16_t*)(W + 21397504);   // [16][1024][96]
  bf16_t* Kab   = (bf16_t*)(W + 24543232);   // [16][1024][96]
  bf16_t* VTt   = (bf16_t*)(W + 27688960);   // [16][64][1024]
  float*  qt    = (float*) (W + 29786112);
  float*  kt    = (float*) (W + 29851648);
  float*  Bi    = (float*) (W + 29917184);
  float*  S     = (float*) (W + 29982720);   // [16][1024][1024] fp32
  bf16_t* Pb    = (bf16_t*)S;                // bf16 alias (in-place after softmax)
  float*  outs  = (float*) (W + 63537152);   // [2048][512] (upper half of dead S)
  bf16_t* y2b   = (bf16_t*)(W + 67731456);   // [2048][544]
  bf16_t* hb    = (bf16_t*)(W + 69959680);   // [2048][2080]
  float*  tmp   = (float*) (W + 78479360);   // [2048][512]
  bf16_t* attnb = y1b;                       // alias (y1b dead after QKV GEMM)

  // 0. weight conversions
  conv_qkvo<<<4352, 256, 0, stream>>>(Wq, Wk, Wv, Wo, Wqkvb, Wob);
  conv_pad<<<4352, 256, 0, stream>>>(W1, W1b,  513,  544, (long)2048 * 544);
  conv_pad<<<4160, 256, 0, stream>>>(W2, W2b, 2049, 2080, (long)512 * 2080);

  // 1. LN1 -> bf16
  ln_fwd<<<2048, 256, 0, stream>>>(x, g1, b1, y1b);

  // 2. fused QKV projection
  gemm_qkv<<<dim3(16,12,1),256,0,stream>>>(
      y1b,544,0, Wqkvb,544,0, qkvs,1536,0, 544,
      nullptr,nullptr,nullptr,nullptr,nullptr,nullptr);

  // 3. heads + add_time + v_tan(transposed) + per-row constants
  qkv_post<<<2048, 512, 0, stream>>>(qkvs, Qab, Kab, VTt, qt, kt, Bi, beta);

  // 4. batched QK^T (K=96) + fast score-logit epilogue -> fp32 S
  gemm_qk<<<dim3(8,8,16),256,0,stream>>>(
      Qab,96,(long)1024*96, Kab,96,(long)1024*96, S,1024,(long)1024*1024, 96,
      qt,Bi,kt, lam,tau,temp);

  // 5. row softmax -> bf16 P (in place)
  softmax_rows<<<16384, 256, 0, stream>>>(S, Pb);

  // 6. batched PV: mt = P @ VTt^T
  gemm_pv<<<dim3(16,1,16),256,0,stream>>>(
      Pb,1024,(long)1024*1024, VTt,1024,(long)64*1024, mt,64,(long)1024*64, 1024,
      nullptr,nullptr,nullptr,nullptr,nullptr,nullptr);

  // 7. expmap0 + merge heads -> attnb bf16
  merge_heads<<<2048, 512, 0, stream>>>(mt, attnb);

  // 8. Wo projection -> fp32 tmp
  gemm_wo<<<dim3(16,4,1),256,0,stream>>>(
      attnb,544,0, Wob,544,0, tmp,512,0, 544,
      nullptr,nullptr,nullptr,nullptr,nullptr,nullptr);

  // 9. residual + LN2
  res_ln<<<2048, 256, 0, stream>>>(tmp, x, g2, b2, outs, y2b);

  // 10. FFN up + fast GELU -> bf16 hb (cols 1..2048)
  gemm_f1<<<dim3(16,16,1),256,0,stream>>>(
      y2b,544,0, W1b,544,0, hb+1,2080,0, 544,
      nullptr,nullptr,nullptr,nullptr,nullptr,nullptr);

  // 11. time coordinate for h
  addtime_row<<<2048, 256, 0, stream>>>(hb);

  // 12. FFN down -> fp32 tmp
  gemm_f2<<<dim3(16,4,1),256,0,stream>>>(
      hb,2080,0, W2b,2080,0, tmp,512,0, 2080,
      nullptr,nullptr,nullptr,nullptr,nullptr,nullptr);

  // 13. final residual + add_time -> d_out
  final_k<<<2048, 256, 0, stream>>>(tmp, outs, (float*)d_out);
}

// Round 4
// 193.054 us; speedup vs baseline: 16.1238x; 1.3488x over previous
//
#include <hip/hip_runtime.h>
#include <math.h>

#define DEV static __device__ __forceinline__

typedef __bf16 bf16_t;
typedef __bf16 bf16x8 __attribute__((ext_vector_type(8)));
typedef float f32x4 __attribute__((ext_vector_type(4)));

// ---------- fast transcendentals ----------
DEV float frcp(float x){ return __builtin_amdgcn_rcpf(x); }
DEV float softplus_exact(float x){
  return x > 0.f ? x + log1pf(expf(-x)) : log1pf(expf(x));
}
DEV float tanh_fast(float z){
  float e2 = __expf(2.f * z);
  return (e2 - 1.f) * frcp(e2 + 1.f);
}
DEV float gelu_fast(float v){
  float u = 0.7978845608028654f * fmaf(0.044715f * v, v * v, v);
  u = fminf(fmaxf(u, -15.f), 15.f);
  return 0.5f * v * (1.f + tanh_fast(u));
}

DEV void gl_lds16(const void* g, void* l) {
  __builtin_amdgcn_global_load_lds((const __attribute__((address_space(1))) void*)g,
                                   (__attribute__((address_space(3))) void*)l, 16, 0, 0);
}

DEV float waveReduceSum(float v){
  #pragma unroll
  for (int o = 32; o > 0; o >>= 1) v += __shfl_xor(v, o, 64);
  return v;
}
DEV float blockReduceSum(float v, float* sh){
  v = waveReduceSum(v);
  int w = threadIdx.x >> 6;
  int nw = blockDim.x >> 6;
  __syncthreads();
  if ((threadIdx.x & 63) == 0) sh[w] = v;
  __syncthreads();
  float r = sh[0];
  for (int i = 1; i < nw; i++) r += sh[i];
  return r;
}

// ---------------- all weight conversions in one kernel ----------------
__global__ __launch_bounds__(256) void conv_all(
    const float* __restrict__ Wq, const float* __restrict__ Wk,
    const float* __restrict__ Wv, const float* __restrict__ Wo,
    const float* __restrict__ W1, const float* __restrict__ W2,
    bf16_t* __restrict__ Wqkvb, bf16_t* __restrict__ Wob,
    bf16_t* __restrict__ W1b, bf16_t* __restrict__ W2b)
{
  long i = (long)blockIdx.x * 256 + threadIdx.x;
  if (i < 1114112) {                       // Wq|Wk|Wv|Wo : [512][513] -> [512][544]
    int w = (int)(i / (512 * 544));
    long rem = i - (long)w * (512 * 544);
    long r = rem / 544;
    int c = (int)(rem - r * 544);
    const float* src = (w == 0) ? Wq : (w == 1) ? Wk : (w == 2) ? Wv : Wo;
    float v = (c < 513) ? src[r * 513 + c] : 0.f;
    if (w < 3) Wqkvb[(long)w * 512 * 544 + rem] = (bf16_t)v;
    else       Wob[rem] = (bf16_t)v;
  } else if (i < 2228224) {                // W1 : [2048][513] -> [2048][544]
    long j = i - 1114112;
    long r = j / 544;
    int c = (int)(j - r * 544);
    W1b[j] = (c < 513) ? (bf16_t)W1[r * 513 + c] : (bf16_t)0.f;
  } else if (i < 3293184) {                // W2 : [512][2049] -> [512][2080]
    long j = i - 2228224;
    long r = j / 2080;
    int c = (int)(j - r * 2080);
    W2b[j] = (c < 2049) ? (bf16_t)W2[r * 2049 + c] : (bf16_t)0.f;
  }
}

// ---------------- LN1 ----------------
__global__ __launch_bounds__(256) void ln_fwd(
    const float* __restrict__ xin,
    const float* __restrict__ g, const float* __restrict__ b,
    bf16_t* __restrict__ y)
{
  __shared__ float sh[8];
  int row = blockIdx.x;
  const float* xr = xin + (long)row * 513 + 1;
  int t = threadIdx.x;
  float a0 = xr[t], a1 = xr[t + 256];
  float s  = blockReduceSum(a0 + a1, sh);
  float s2 = blockReduceSum(a0 * a0 + a1 * a1, sh);
  float mu = s * (1.f / 512.f);
  float var = s2 * (1.f / 512.f) - mu * mu;
  float inv = rsqrtf(var + 1e-5f);
  float y0 = (a0 - mu) * inv * g[t] + b[t];
  float y1v = (a1 - mu) * inv * g[t + 256] + b[t + 256];
  float q = blockReduceSum(y0 * y0 + y1v * y1v, sh);
  bf16_t* yr = y + (long)row * 544;
  yr[1 + t] = (bf16_t)y0;
  yr[1 + t + 256] = (bf16_t)y1v;
  if (t == 0) yr[0] = (bf16_t)sqrtf(q + 1.f);
  if (t < 31) yr[513 + t] = (bf16_t)0.f;
}

// ---------------- residual + LN2 ----------------
__global__ __launch_bounds__(256) void res_ln(
    const float* __restrict__ wo,
    const float* __restrict__ xin,
    const float* __restrict__ g, const float* __restrict__ b,
    float* __restrict__ outs,
    bf16_t* __restrict__ y)
{
  __shared__ float sh[8];
  int row = blockIdx.x;
  int t = threadIdx.x;
  float a0 = wo[(long)row * 512 + t]       + xin[(long)row * 513 + 1 + t];
  float a1 = wo[(long)row * 512 + t + 256] + xin[(long)row * 513 + 1 + t + 256];
  outs[(long)row * 512 + t] = a0;
  outs[(long)row * 512 + t + 256] = a1;
  float s  = blockReduceSum(a0 + a1, sh);
  float s2 = blockReduceSum(a0 * a0 + a1 * a1, sh);
  float mu = s * (1.f / 512.f);
  float var = s2 * (1.f / 512.f) - mu * mu;
  float inv = rsqrtf(var + 1e-5f);
  float y0 = (a0 - mu) * inv * g[t] + b[t];
  float y1v = (a1 - mu) * inv * g[t + 256] + b[t + 256];
  float q = blockReduceSum(y0 * y0 + y1v * y1v, sh);
  bf16_t* yr = y + (long)row * 544;
  yr[1 + t] = (bf16_t)y0;
  yr[1 + t + 256] = (bf16_t)y1v;
  if (t == 0) yr[0] = (bf16_t)sqrtf(q + 1.f);
  if (t < 31) yr[513 + t] = (bf16_t)0.f;
}

// ---------------- add_time over bf16 h [2048][2080] ----------------
__global__ __launch_bounds__(256) void addtime_row(bf16_t* __restrict__ h)
{
  __shared__ float sh[8];
  int row = blockIdx.x;
  bf16_t* hr = h + (long)row * 2080;
  int t = threadIdx.x;
  float s2 = 0.f;
  bf16x8 v = *(const bf16x8*)&hr[t * 8];
  #pragma unroll
  for (int j = 0; j < 8; j++) {
    if (t == 0 && j == 0) continue;
    float f = (float)v[j];
    s2 = fmaf(f, f, s2);
  }
  if (t == 0) { float f = (float)hr[2048]; s2 = fmaf(f, f, s2); }
  s2 = blockReduceSum(s2, sh);
  if (t == 0) hr[0] = (bf16_t)sqrtf(s2 + 1.f);
  if (t < 31) hr[2049 + t] = (bf16_t)0.f;
}

// ---------------- final residual + add_time ----------------
__global__ __launch_bounds__(256) void final_k(
    const float* __restrict__ h2, const float* __restrict__ outs,
    float* __restrict__ out)
{
  __shared__ float sh[8];
  int row = blockIdx.x;
  int t = threadIdx.x;
  float o0 = h2[(long)row * 512 + t]       + outs[(long)row * 512 + t];
  float o1 = h2[(long)row * 512 + t + 256] + outs[(long)row * 512 + t + 256];
  float q = blockReduceSum(o0 * o0 + o1 * o1, sh);
  float* yr = out + (long)row * 513;
  yr[1 + t] = o0;
  yr[1 + t + 256] = o1;
  if (t == 0) yr[0] = sqrtf(q + 1.f);
}

// ---------------- QKV post (VT written coalesced [z][n][d]) ----------------
__global__ __launch_bounds__(512) void qkv_post(
    const float* __restrict__ S,      // [2048][1536]
    bf16_t* __restrict__ Qab,         // [16][1024][96]
    bf16_t* __restrict__ Kab,         // [16][1024][96]
    bf16_t* __restrict__ VT,          // [16][1024][64]
    float* __restrict__ qt, float* __restrict__ kt, float* __restrict__ Bi,
    const float* __restrict__ beta_p)
{
  int row = blockIdx.x;
  int b = row >> 10, n = row & 1023;
  int h = threadIdx.x >> 6, d = threadIdx.x & 63;
  long base = (long)row * 1536;
  float qv = S[base + h * 64 + d];
  float kv = S[base + 512 + h * 64 + d];
  float vv = S[base + 1024 + h * 64 + d];
  float q2 = waveReduceSum(qv * qv);
  float k2 = waveReduceSum(kv * kv);
  float v2 = waveReduceSum(vv * vv);
  float qT = sqrtf(1.f + q2);
  float kT = sqrtf(1.f + k2);
  float vTt_ = sqrtf(1.f + v2);
  float sn0 = sqrtf(v2);
  float dd = __logf(vTt_ + sn0);          // acosh
  float coef = dd * frcp(fmaxf(sn0, 1e-8f));
  int z = b * 8 + h;
  long a96 = ((long)z * 1024 + n) * 96;
  Qab[a96 + d] = (bf16_t)qv;
  Kab[a96 + d] = (bf16_t)kv;
  VT[((long)z * 1024 + n) * 64 + d] = (bf16_t)(coef * vv);
  if (d == 0) {
    Qab[a96 + 64] = (bf16_t)qT;
    Kab[a96 + 64] = (bf16_t)(-kT);
    int ob = z * 1024 + n;
    qt[ob] = qT;
    kt[ob] = kT;
    float beta = softplus_exact(beta_p[0]);
    float xq = fmaxf(qT, 1.001f);
    float sh_ = sqrtf(fmaxf(xq * xq - 1.f, 0.f));
    float rr = beta * frcp(sh_);
    Bi[ob] = sqrtf(fmaxf(1.f - rr * rr, 0.f) + 1e-8f);
  }
  if (d < 31) {
    Qab[a96 + 65 + d] = (bf16_t)0.f;
    Kab[a96 + 65 + d] = (bf16_t)0.f;
  }
}

// ---------------- VT [z][n][d] -> VTt [z][d][n] (32x32 LDS tiles) ----------------
__global__ __launch_bounds__(256) void vt_tr(
    const bf16_t* __restrict__ VT, bf16_t* __restrict__ VTt)
{
  __shared__ bf16_t tile[32][33];
  int z = blockIdx.z, n0 = blockIdx.x * 32, d0 = blockIdx.y * 32;
  int tx = threadIdx.x & 31, ty = threadIdx.x >> 5;   // 8 rows per pass
  const bf16_t* src = VT + (long)z * 1024 * 64;
  #pragma unroll
  for (int r = 0; r < 32; r += 8)
    tile[ty + r][tx] = src[(long)(n0 + ty + r) * 64 + d0 + tx];
  __syncthreads();
  bf16_t* dst = VTt + (long)z * 64 * 1024;
  #pragma unroll
  for (int r = 0; r < 32; r += 8)
    dst[(long)(d0 + ty + r) * 1024 + n0 + tx] = tile[tx][ty + r];
}

// ---------------- merge heads: expmap0 + concat ----------------
__global__ __launch_bounds__(512) void merge_heads(
    const float* __restrict__ mt, bf16_t* __restrict__ attn)
{
  __shared__ float t2s[8];
  int row = blockIdx.x;
  int b = row >> 10, n = row & 1023;
  int h = threadIdx.x >> 6, d = threadIdx.x & 63;
  int z = b * 8 + h;
  float v = mt[((long)z * 1024 + n) * 64 + d];
  float s2 = waveReduceSum(v * v);
  float nn = fmaxf(sqrtf(s2), 1e-8f);
  float e = __expf(nn), ei = frcp(e);
  float coef = 0.5f * (e - ei) * frcp(nn);
  attn[(long)row * 544 + 1 + h * 64 + d] = (bf16_t)(coef * v);
  if (d == 0) {
    float th = 0.5f * (e + ei);
    t2s[h] = th * th;
  }
  __syncthreads();
  if (threadIdx.x == 0) {
    float t2 = t2s[0] + t2s[1] + t2s[2] + t2s[3] + t2s[4] + t2s[5] + t2s[6] + t2s[7] - 7.f;
    attn[(long)row * 544] = (bf16_t)sqrtf(fmaxf(t2, 1e-8f));
  }
  if (threadIdx.x < 31) attn[(long)row * 544 + 513 + threadIdx.x] = (bf16_t)0.f;
}

// ---------------- bf16 MFMA GEMM body: C = A @ B^T ----------------
// ACT: 0 fp32 write | 1 GELU->bf16 | 3 score+exp->bf16 P + row partials | 4 normalize-by-partials
template<int BM, int BN, int WM, int WN, int ACT>
DEV void gemm_body(
    const bf16_t* __restrict__ Ag, int lda, long sA,
    const bf16_t* __restrict__ Bg, int ldb, long sB,
    void* __restrict__ Cg, int ldc, long sC,
    int K, float* __restrict__ aux,
    const float* __restrict__ qt, const float* __restrict__ Bi,
    const float* __restrict__ kt,
    const float* __restrict__ lam_p, const float* __restrict__ tau_p,
    const float* __restrict__ temp_p)
{
  constexpr int MI = WM / 16, NJ = WN / 16;
  constexpr int NWN = BN / WN;
  __shared__ bf16_t As[BM][32];
  __shared__ bf16_t Bs[BN][32];
  const int t = threadIdx.x;
  const int wid = t >> 6, lane = t & 63;
  const int lm = lane & 15, lh = lane >> 4;
  const int z = blockIdx.z;
  const bf16_t* A = Ag + (long)z * sA;
  const bf16_t* B = Bg + (long)z * sB;
  const int bm = blockIdx.x * BM;
  const int bn = blockIdx.y * BN;
  const int wm = (wid / NWN) * WM;
  const int wn = (wid % NWN) * WN;
  f32x4 acc[MI][NJ] = {};

  for (int kk = 0; kk < K; kk += 32) {
    __syncthreads();
    #pragma unroll
    for (int r = 0; r < BM / 64; r++) {
      int chunk = r * 4 + wid;
      const char* src = (const char*)(A + (long)(bm + chunk * 16 + (lane >> 2)) * lda + kk)
                        + (lane & 3) * 16;
      gl_lds16(src, (char*)&As[0][0] + chunk * 1024);
    }
    #pragma unroll
    for (int r = 0; r < BN / 64; r++) {
      int chunk = r * 4 + wid;
      const char* src = (const char*)(B + (long)(bn + chunk * 16 + (lane >> 2)) * ldb + kk)
                        + (lane & 3) * 16;
      gl_lds16(src, (char*)&Bs[0][0] + chunk * 1024);
    }
    __syncthreads();
    bf16x8 af[MI], bfr[NJ];
    #pragma unroll
    for (int i = 0; i < MI; i++) af[i] = *(const bf16x8*)&As[wm + i * 16 + lm][lh * 8];
    #pragma unroll
    for (int j = 0; j < NJ; j++) bfr[j] = *(const bf16x8*)&Bs[wn + j * 16 + lm][lh * 8];
    #pragma unroll
    for (int i = 0; i < MI; i++)
      #pragma unroll
      for (int j = 0; j < NJ; j++)
        acc[i][j] = __builtin_amdgcn_mfma_f32_16x16x32_bf16(af[i], bfr[j], acc[i][j], 0, 0, 0);
  }

  if constexpr (ACT == 3) {
    // score logits -> exp (no-max softmax numerator), bf16 P + per-block row sums
    __shared__ float sh_rs[BM];
    for (int r = t; r < BM; r += 256) sh_rs[r] = 0.f;
    __syncthreads();
    float lam = softplus_exact(lam_p[0]);
    float tau = softplus_exact(tau_p[0]);
    float invT = frcp(temp_p[0]);
    bf16_t* C = (bf16_t*)Cg + (long)z * sC;
    float ktv[NJ];
    #pragma unroll
    for (int j = 0; j < NJ; j++) ktv[j] = kt[z * 1024 + bn + wn + j * 16 + lm];
    #pragma unroll
    for (int i = 0; i < MI; i++) {
      #pragma unroll
      for (int q = 0; q < 4; q++) {
        int lrow = wm + i * 16 + lh * 4 + q;
        int gi = z * 1024 + bm + lrow;
        float qtv = qt[gi], Biv = Bi[gi];
        float nOQ = fmaxf(qtv * qtv - 1.f, 0.f);
        float rp = 0.f;
        #pragma unroll
        for (int j = 0; j < NJ; j++) {
          int col = bn + wn + j * 16 + lm;
          float inner = acc[i][j][q];
          float nQK = fmaxf(inner * inner - 1.f, 0.f);
          float numer = -(ktv[j] + inner * qtv);
          float Zc = fminf(fmaxf(numer * __builtin_amdgcn_rsqf(fmaf(nQK, nOQ, 2.5e-5f)), -1.f), 1.f);
          float xx = fmaxf(-inner, 1.001f);
          float dist = __logf(xx + sqrtf(fmaf(xx, xx, -1.f)));        // acosh
          float u = fminf(dist * 0.025f, 0.5f);
          float u2 = u * u;
          float sd = 2.66666667f * u * fmaf(u2, fmaf(u2, 0.13333333f, -0.33333333f), 1.f);
          float s2 = sd * sd;                                          // H = ln cosh(sd)
          float H = s2 * fmaf(s2, fmaf(s2, 0.02222222f, -0.08333333f), 0.5f);
          float a = Biv + Zc - 0.1f;
          float Phi = fmaxf(a, 0.f) + __logf(1.f + __expf(-fabsf(a))) - 0.64439666007f;
          float e = __expf((-lam * H - tau * Phi) * invT);
          C[(long)(bm + lrow) * ldc + col] = (bf16_t)e;
          rp += e;
        }
        rp += __shfl_xor(rp, 1, 64);
        rp += __shfl_xor(rp, 2, 64);
        rp += __shfl_xor(rp, 4, 64);
        rp += __shfl_xor(rp, 8, 64);
        if (lm == 0) atomicAdd(&sh_rs[lrow], rp);
      }
    }
    __syncthreads();
    for (int r = t; r < BM; r += 256)
      aux[((long)z * 1024 + bm + r) * 8 + blockIdx.y] = sh_rs[r];
  } else if constexpr (ACT == 4) {
    // normalize by sum of 8 partials per row
    float* C = (float*)Cg + (long)z * sC;
    const float* part = aux + (long)z * 1024 * 8;
    #pragma unroll
    for (int i = 0; i < MI; i++) {
      #pragma unroll
      for (int q = 0; q < 4; q++) {
        int row = bm + wm + i * 16 + lh * 4 + q;
        const float* pr = part + (long)row * 8;
        float su = ((pr[0] + pr[1]) + (pr[2] + pr[3])) + ((pr[4] + pr[5]) + (pr[6] + pr[7]));
        float sc = frcp(su * (1.f + 1e-8f));
        #pragma unroll
        for (int j = 0; j < NJ; j++) {
          int col = bn + wn + j * 16 + lm;
          C[(long)row * ldc + col] = acc[i][j][q] * sc;
        }
      }
    }
  } else if constexpr (ACT == 1) {
    bf16_t* C = (bf16_t*)Cg;
    #pragma unroll
    for (int i = 0; i < MI; i++) {
      #pragma unroll
      for (int q = 0; q < 4; q++) {
        long row = bm + wm + i * 16 + lh * 4 + q;
        #pragma unroll
        for (int j = 0; j < NJ; j++) {
          int col = bn + wn + j * 16 + lm;
          C[row * ldc + col] = (bf16_t)gelu_fast(acc[i][j][q]);
        }
      }
    }
  } else {
    float* C = (float*)Cg + (long)z * sC;
    #pragma unroll
    for (int i = 0; i < MI; i++) {
      #pragma unroll
      for (int q = 0; q < 4; q++) {
        long row = bm + wm + i * 16 + lh * 4 + q;
        #pragma unroll
        for (int j = 0; j < NJ; j++) {
          int col = bn + wn + j * 16 + lm;
          C[row * ldc + col] = acc[i][j][q];
        }
      }
    }
  }
}

#define GEMM_ARGS const bf16_t* A, int lda, long sA, const bf16_t* B, int ldb, long sB, \
                  void* C, int ldc, long sC, int K, float* aux, \
                  const float* qt, const float* Bi, const float* kt, \
                  const float* lam, const float* tau, const float* temp
#define GEMM_PASS A,lda,sA,B,ldb,sB,C,ldc,sC,K,aux,qt,Bi,kt,lam,tau,temp

__global__ __launch_bounds__(256) void gemm_qkv(GEMM_ARGS){ gemm_body<128,128,64,64,0>(GEMM_PASS); }
__global__ __launch_bounds__(256) void gemm_qk (GEMM_ARGS){ gemm_body<128,128,64,64,3>(GEMM_PASS); }
__global__ __launch_bounds__(256) void gemm_pv (GEMM_ARGS){ gemm_body< 64, 64,32,32,4>(GEMM_PASS); }
__global__ __launch_bounds__(256) void gemm_wo (GEMM_ARGS){ gemm_body< 64, 64,32,32,0>(GEMM_PASS); }
__global__ __launch_bounds__(256) void gemm_f1 (GEMM_ARGS){ gemm_body<128,128,64,64,1>(GEMM_PASS); }
__global__ __launch_bounds__(256) void gemm_f2 (GEMM_ARGS){ gemm_body< 64, 64,32,32,0>(GEMM_PASS); }

extern "C" void kernel_launch(void* const* d_in, const int* in_sizes, int n_in,
                              void* d_out, int out_size, void* d_ws, size_t ws_size,
                              hipStream_t stream) {
  const float* x    = (const float*)d_in[0];
  const float* Wq   = (const float*)d_in[1];
  const float* Wk   = (const float*)d_in[2];
  const float* Wv   = (const float*)d_in[3];
  const float* Wo   = (const float*)d_in[4];
  const float* W1   = (const float*)d_in[5];
  const float* W2   = (const float*)d_in[6];
  const float* g1   = (const float*)d_in[7];
  const float* b1   = (const float*)d_in[8];
  const float* g2   = (const float*)d_in[9];
  const float* b2   = (const float*)d_in[10];
  const float* temp = (const float*)d_in[11];
  const float* beta = (const float*)d_in[12];
  const float* tau  = (const float*)d_in[13];
  const float* lam  = (const float*)d_in[14];

  char* W = (char*)d_ws;
  bf16_t* Wqkvb = (bf16_t*)(W + 0);          // [1536][544]
  bf16_t* Wob   = (bf16_t*)(W + 1671168);    // [512][544]
  bf16_t* W1b   = (bf16_t*)(W + 2228224);    // [2048][544]
  bf16_t* W2b   = (bf16_t*)(W + 4456448);    // [512][2080]
  bf16_t* y1b   = (bf16_t*)(W + 6586368);    // [2048][544]
  float*  qkvs  = (float*) (W + 8814592);    // [2048][1536] fp32 (12.58 MB)
  float*  mt    = (float*) (W + 8814592);    // [16][1024][64] fp32 (alias, after qkv_post)
  float*  tmp   = (float*) (W + 13008896);   // [2048][512] fp32 (alias)
  float*  outs  = (float*) (W + 17203200);   // [2048][512] fp32 (alias)
  bf16_t* Qab   = (bf16_t*)(W + 21397504);   // [16][1024][96]
  bf16_t* Kab   = (bf16_t*)(W + 24543232);   // [16][1024][96]
  bf16_t* VTt   = (bf16_t*)(W + 27688960);   // [16][64][1024]
  float*  qt    = (float*) (W + 29786112);
  float*  kt    = (float*) (W + 29851648);
  float*  Bi    = (float*) (W + 29917184);
  bf16_t* Pb    = (bf16_t*)(W + 29982720);   // [16][1024][1024] bf16 (33.55 MB)
  float*  part  = (float*) (W + 63537152);   // [16][1024][8]
  bf16_t* VT    = (bf16_t*)(W + 64061440);   // [16][1024][64]
  bf16_t* y2b   = (bf16_t*)(W + 66158592);   // [2048][544]
  bf16_t* hb    = (bf16_t*)(W + 68386816);   // [2048][2080]  (end 76.9 MB)
  bf16_t* attnb = y1b;                       // alias (y1b dead after QKV GEMM)

  // 0. weight conversions (single kernel)
  conv_all<<<12864, 256, 0, stream>>>(Wq, Wk, Wv, Wo, W1, W2, Wqkvb, Wob, W1b, W2b);

  // 1. LN1 -> bf16
  ln_fwd<<<2048, 256, 0, stream>>>(x, g1, b1, y1b);

  // 2. fused QKV projection
  gemm_qkv<<<dim3(16,12,1),256,0,stream>>>(
      y1b,544,0, Wqkvb,544,0, qkvs,1536,0, 544, nullptr,
      nullptr,nullptr,nullptr,nullptr,nullptr,nullptr);

  // 3. heads + add_time + v_tan + per-row constants (VT coalesced)
  qkv_post<<<2048, 512, 0, stream>>>(qkvs, Qab, Kab, VT, qt, kt, Bi, beta);

  // 4. VT -> VTt transpose
  vt_tr<<<dim3(32,2,16),256,0,stream>>>(VT, VTt);

  // 5. batched QK^T + score + exp (fused no-max softmax numerator) -> bf16 P + partials
  gemm_qk<<<dim3(8,8,16),256,0,stream>>>(
      Qab,96,(long)1024*96, Kab,96,(long)1024*96, Pb,1024,(long)1024*1024, 96, part,
      qt,Bi,kt, lam,tau,temp);

  // 6. batched PV with normalization epilogue: mt = (P @ VTt^T) / rowsum
  gemm_pv<<<dim3(16,1,16),256,0,stream>>>(
      Pb,1024,(long)1024*1024, VTt,1024,(long)64*1024, mt,64,(long)1024*64, 1024, part,
      nullptr,nullptr,nullptr,nullptr,nullptr,nullptr);

  // 7. expmap0 + merge heads -> attnb bf16
  merge_heads<<<2048, 512, 0, stream>>>(mt, attnb);

  // 8. Wo projection -> fp32 tmp  (64x64 tiles: 256 blocks)
  gemm_wo<<<dim3(32,8,1),256,0,stream>>>(
      attnb,544,0, Wob,544,0, tmp,512,0, 544, nullptr,
      nullptr,nullptr,nullptr,nullptr,nullptr,nullptr);

  // 9. residual + LN2
  res_ln<<<2048, 256, 0, stream>>>(tmp, x, g2, b2, outs, y2b);

  // 10. FFN up + fast GELU -> bf16 hb (cols 1..2048)
  gemm_f1<<<dim3(16,16,1),256,0,stream>>>(
      y2b,544,0, W1b,544,0, hb+1,2080,0, 544, nullptr,
      nullptr,nullptr,nullptr,nullptr,nullptr,nullptr);

  // 11. time coordinate for h
  addtime_row<<<2048, 256, 0, stream>>>(hb);

  // 12. FFN down -> fp32 tmp  (64x64 tiles: 256 blocks)
  gemm_f2<<<dim3(32,8,1),256,0,stream>>>(
      hb,2080,0, W2b,2080,0, tmp,512,0, 2080, nullptr,
      nullptr,nullptr,nullptr,nullptr,nullptr,nullptr);

  // 13. final residual + add_time -> d_out
  final_k<<<2048, 256, 0, stream>>>(tmp, outs, (float*)d_out);
}

// Round 5
// 184.193 us; speedup vs baseline: 16.8995x; 1.0481x over previous
//
#include <hip/hip_runtime.h>
#include <math.h>

#define DEV static __device__ __forceinline__

typedef __bf16 bf16_t;
typedef __bf16 bf16x8 __attribute__((ext_vector_type(8)));
typedef float f32x4 __attribute__((ext_vector_type(4)));

// ---------- fast transcendentals ----------
DEV float frcp(float x){ return __builtin_amdgcn_rcpf(x); }
DEV float softplus_exact(float x){
  return x > 0.f ? x + log1pf(expf(-x)) : log1pf(expf(x));
}
DEV float tanh_fast(float z){
  float e2 = __expf(2.f * z);
  return (e2 - 1.f) * frcp(e2 + 1.f);
}
DEV float gelu_fast(float v){
  float u = 0.7978845608028654f * fmaf(0.044715f * v, v * v, v);
  u = fminf(fmaxf(u, -15.f), 15.f);
  return 0.5f * v * (1.f + tanh_fast(u));
}

DEV void gl_lds16(const void* g, void* l) {
  __builtin_amdgcn_global_load_lds((const __attribute__((address_space(1))) void*)g,
                                   (__attribute__((address_space(3))) void*)l, 16, 0, 0);
}

DEV float waveReduceSum(float v){
  #pragma unroll
  for (int o = 32; o > 0; o >>= 1) v += __shfl_xor(v, o, 64);
  return v;
}
DEV float blockReduceSum(float v, float* sh){
  v = waveReduceSum(v);
  int w = threadIdx.x >> 6;
  int nw = blockDim.x >> 6;
  __syncthreads();
  if ((threadIdx.x & 63) == 0) sh[w] = v;
  __syncthreads();
  float r = sh[0];
  for (int i = 1; i < nw; i++) r += sh[i];
  return r;
}

// ---------------- weight conversions (TIME MOVED TO LAST K-SLOT) ----------------
// Wb[n][c] = W[n][c+1] for c<Ks, Wb[n][Ks] = W[n][0], 0 beyond.
__global__ __launch_bounds__(256) void conv_all(
    const float* __restrict__ Wq, const float* __restrict__ Wk,
    const float* __restrict__ Wv, const float* __restrict__ Wo,
    const float* __restrict__ W1, const float* __restrict__ W2,
    bf16_t* __restrict__ Wqkvb, bf16_t* __restrict__ Wob,
    bf16_t* __restrict__ W1b, bf16_t* __restrict__ W2b)
{
  long i = (long)blockIdx.x * 256 + threadIdx.x;
  if (i < 1114112) {                       // Wq|Wk|Wv|Wo : [512][513] -> [512][544]
    int w = (int)(i / (512 * 544));
    long rem = i - (long)w * (512 * 544);
    long r = rem / 544;
    int c = (int)(rem - r * 544);
    const float* src = (w == 0) ? Wq : (w == 1) ? Wk : (w == 2) ? Wv : Wo;
    float v = (c < 512) ? src[r * 513 + c + 1] : (c == 512 ? src[r * 513] : 0.f);
    if (w < 3) Wqkvb[(long)w * 512 * 544 + rem] = (bf16_t)v;
    else       Wob[rem] = (bf16_t)v;
  } else if (i < 2228224) {                // W1 : [2048][513] -> [2048][544]
    long j = i - 1114112;
    long r = j / 544;
    int c = (int)(j - r * 544);
    W1b[j] = (c < 512) ? (bf16_t)W1[r * 513 + c + 1]
           : (c == 512 ? (bf16_t)W1[r * 513] : (bf16_t)0.f);
  } else if (i < 3293184) {                // W2 : [512][2049] -> [512][2080]
    long j = i - 2228224;
    long r = j / 2080;
    int c = (int)(j - r * 2080);
    W2b[j] = (c < 2048) ? (bf16_t)W2[r * 2049 + c + 1]
           : (c == 2048 ? (bf16_t)W2[r * 2049] : (bf16_t)0.f);
  }
}

// ---------------- LN1: y[0..511]=spatial, y[512]=time, 513..543=0 ----------------
__global__ __launch_bounds__(256) void ln_fwd(
    const float* __restrict__ xin,
    const float* __restrict__ g, const float* __restrict__ b,
    bf16_t* __restrict__ y)
{
  __shared__ float sh[8];
  int row = blockIdx.x;
  const float* xr = xin + (long)row * 513 + 1;
  int t = threadIdx.x;
  float a0 = xr[t], a1 = xr[t + 256];
  float s  = blockReduceSum(a0 + a1, sh);
  float s2 = blockReduceSum(a0 * a0 + a1 * a1, sh);
  float mu = s * (1.f / 512.f);
  float var = s2 * (1.f / 512.f) - mu * mu;
  float inv = rsqrtf(var + 1e-5f);
  float y0 = (a0 - mu) * inv * g[t] + b[t];
  float y1v = (a1 - mu) * inv * g[t + 256] + b[t + 256];
  float q = blockReduceSum(y0 * y0 + y1v * y1v, sh);
  bf16_t* yr = y + (long)row * 544;
  yr[t] = (bf16_t)y0;
  yr[t + 256] = (bf16_t)y1v;
  if (t == 0) yr[512] = (bf16_t)sqrtf(q + 1.f);
  if (t < 31) yr[513 + t] = (bf16_t)0.f;
}

// ---------------- residual + LN2 ----------------
__global__ __launch_bounds__(256) void res_ln(
    const float* __restrict__ wo,
    const float* __restrict__ xin,
    const float* __restrict__ g, const float* __restrict__ b,
    float* __restrict__ outs,
    bf16_t* __restrict__ y)
{
  __shared__ float sh[8];
  int row = blockIdx.x;
  int t = threadIdx.x;
  float a0 = wo[(long)row * 512 + t]       + xin[(long)row * 513 + 1 + t];
  float a1 = wo[(long)row * 512 + t + 256] + xin[(long)row * 513 + 1 + t + 256];
  outs[(long)row * 512 + t] = a0;
  outs[(long)row * 512 + t + 256] = a1;
  float s  = blockReduceSum(a0 + a1, sh);
  float s2 = blockReduceSum(a0 * a0 + a1 * a1, sh);
  float mu = s * (1.f / 512.f);
  float var = s2 * (1.f / 512.f) - mu * mu;
  float inv = rsqrtf(var + 1e-5f);
  float y0 = (a0 - mu) * inv * g[t] + b[t];
  float y1v = (a1 - mu) * inv * g[t + 256] + b[t + 256];
  float q = blockReduceSum(y0 * y0 + y1v * y1v, sh);
  bf16_t* yr = y + (long)row * 544;
  yr[t] = (bf16_t)y0;
  yr[t + 256] = (bf16_t)y1v;
  if (t == 0) yr[512] = (bf16_t)sqrtf(q + 1.f);
  if (t < 31) yr[513 + t] = (bf16_t)0.f;
}

// ---------------- add_time over bf16 h [2048][2080]: spatial 0..2047, time at 2048 ----------------
__global__ __launch_bounds__(256) void addtime_row(bf16_t* __restrict__ h)
{
  __shared__ float sh[8];
  int row = blockIdx.x;
  bf16_t* hr = h + (long)row * 2080;
  int t = threadIdx.x;
  float s2 = 0.f;
  bf16x8 v = *(const bf16x8*)&hr[t * 8];
  #pragma unroll
  for (int j = 0; j < 8; j++) {
    float f = (float)v[j];
    s2 = fmaf(f, f, s2);
  }
  s2 = blockReduceSum(s2, sh);
  if (t == 0) hr[2048] = (bf16_t)sqrtf(s2 + 1.f);
  if (t < 31) hr[2049 + t] = (bf16_t)0.f;
}

// ---------------- final residual + add_time -> d_out [t, s] ----------------
__global__ __launch_bounds__(256) void final_k(
    const float* __restrict__ h2, const float* __restrict__ outs,
    float* __restrict__ out)
{
  __shared__ float sh[8];
  int row = blockIdx.x;
  int t = threadIdx.x;
  float o0 = h2[(long)row * 512 + t]       + outs[(long)row * 512 + t];
  float o1 = h2[(long)row * 512 + t + 256] + outs[(long)row * 512 + t + 256];
  float q = blockReduceSum(o0 * o0 + o1 * o1, sh);
  float* yr = out + (long)row * 513;
  yr[1 + t] = o0;
  yr[1 + t + 256] = o1;
  if (t == 0) yr[0] = sqrtf(q + 1.f);
}

// ---------------- QKV post ----------------
__global__ __launch_bounds__(512) void qkv_post(
    const float* __restrict__ S,      // [2048][1536]
    bf16_t* __restrict__ Qab,         // [16][1024][96]
    bf16_t* __restrict__ Kab,         // [16][1024][96]
    bf16_t* __restrict__ VT,          // [16][1024][64]
    float* __restrict__ qt, float* __restrict__ kt, float* __restrict__ Bi,
    const float* __restrict__ beta_p)
{
  int row = blockIdx.x;
  int b = row >> 10, n = row & 1023;
  int h = threadIdx.x >> 6, d = threadIdx.x & 63;
  long base = (long)row * 1536;
  float qv = S[base + h * 64 + d];
  float kv = S[base + 512 + h * 64 + d];
  float vv = S[base + 1024 + h * 64 + d];
  float q2 = waveReduceSum(qv * qv);
  float k2 = waveReduceSum(kv * kv);
  float v2 = waveReduceSum(vv * vv);
  float qT = sqrtf(1.f + q2);
  float kT = sqrtf(1.f + k2);
  float vTt_ = sqrtf(1.f + v2);
  float sn0 = sqrtf(v2);
  float dd = __logf(vTt_ + sn0);          // acosh
  float coef = dd * frcp(fmaxf(sn0, 1e-8f));
  int z = b * 8 + h;
  long a96 = ((long)z * 1024 + n) * 96;
  Qab[a96 + d] = (bf16_t)qv;
  Kab[a96 + d] = (bf16_t)kv;
  VT[((long)z * 1024 + n) * 64 + d] = (bf16_t)(coef * vv);
  if (d == 0) {
    Qab[a96 + 64] = (bf16_t)qT;
    Kab[a96 + 64] = (bf16_t)(-kT);
    int ob = z * 1024 + n;
    qt[ob] = qT;
    kt[ob] = kT;
    float beta = softplus_exact(beta_p[0]);
    float xq = fmaxf(qT, 1.001f);
    float sh_ = sqrtf(fmaxf(xq * xq - 1.f, 0.f));
    float rr = beta * frcp(sh_);
    Bi[ob] = sqrtf(fmaxf(1.f - rr * rr, 0.f) + 1e-8f);
  }
  if (d < 31) {
    Qab[a96 + 65 + d] = (bf16_t)0.f;
    Kab[a96 + 65 + d] = (bf16_t)0.f;
  }
}

// ---------------- VT [z][n][d] -> VTt [z][d][n] ----------------
__global__ __launch_bounds__(256) void vt_tr(
    const bf16_t* __restrict__ VT, bf16_t* __restrict__ VTt)
{
  __shared__ bf16_t tile[32][33];
  int z = blockIdx.z, n0 = blockIdx.x * 32, d0 = blockIdx.y * 32;
  int tx = threadIdx.x & 31, ty = threadIdx.x >> 5;
  const bf16_t* src = VT + (long)z * 1024 * 64;
  #pragma unroll
  for (int r = 0; r < 32; r += 8)
    tile[ty + r][tx] = src[(long)(n0 + ty + r) * 64 + d0 + tx];
  __syncthreads();
  bf16_t* dst = VTt + (long)z * 64 * 1024;
  #pragma unroll
  for (int r = 0; r < 32; r += 8)
    dst[(long)(d0 + ty + r) * 1024 + n0 + tx] = tile[tx][ty + r];
}

// ---------------- merge heads: spatial at 0..511, time at 512 ----------------
__global__ __launch_bounds__(512) void merge_heads(
    const float* __restrict__ mt, bf16_t* __restrict__ attn)
{
  __shared__ float t2s[8];
  int row = blockIdx.x;
  int b = row >> 10, n = row & 1023;
  int h = threadIdx.x >> 6, d = threadIdx.x & 63;
  int z = b * 8 + h;
  float v = mt[((long)z * 1024 + n) * 64 + d];
  float s2 = waveReduceSum(v * v);
  float nn = fmaxf(sqrtf(s2), 1e-8f);
  float e = __expf(nn), ei = frcp(e);
  float coef = 0.5f * (e - ei) * frcp(nn);
  attn[(long)row * 544 + h * 64 + d] = (bf16_t)(coef * v);
  if (d == 0) {
    float th = 0.5f * (e + ei);
    t2s[h] = th * th;
  }
  __syncthreads();
  if (threadIdx.x == 0) {
    float t2 = t2s[0] + t2s[1] + t2s[2] + t2s[3] + t2s[4] + t2s[5] + t2s[6] + t2s[7] - 7.f;
    attn[(long)row * 544 + 512] = (bf16_t)sqrtf(fmaxf(t2, 1e-8f));
  }
  if (threadIdx.x < 31) attn[(long)row * 544 + 513 + threadIdx.x] = (bf16_t)0.f;
}

// ============ bf16-output GEMM with LDS repack (BM=128, BN=64, 4 waves) ============
// ACTF: 0 = GELU (FFN up), 1 = score+exp (QK) with per-block row sums -> aux
template<int ACTF>
DEV void gemm_rep_body(
    const bf16_t* __restrict__ Ag, int lda, long sA,
    const bf16_t* __restrict__ Bg, int ldb, long sB,
    bf16_t* __restrict__ Cg, int ldc, long sC,
    int K, float* __restrict__ aux,
    const float* __restrict__ qt, const float* __restrict__ Bi,
    const float* __restrict__ kt,
    const float* __restrict__ lam_p, const float* __restrict__ tau_p,
    const float* __restrict__ temp_p)
{
  __shared__ char smem[16384];          // k-loop: As 8K | Bs 4K ; epilogue: rep 16K
  __shared__ float sh_qt[128], sh_Bi[128];
  bf16_t* As = (bf16_t*)smem;           // [128][32]
  bf16_t* Bs = (bf16_t*)(smem + 8192);  // [64][32]
  const int t = threadIdx.x;
  const int wid = t >> 6, lane = t & 63;
  const int lm = lane & 15, lh = lane >> 4;
  const int z = blockIdx.z;
  const bf16_t* A = Ag + (long)z * sA;
  const bf16_t* B = Bg + (long)z * sB;
  const int bm = blockIdx.x * 128;
  const int bn = blockIdx.y * 64;
  const int wm = (wid >> 1) * 64;
  const int wn = (wid & 1) * 32;
  f32x4 acc[4][2] = {};

  if constexpr (ACTF == 1) {
    if (t < 128) {
      sh_qt[t] = qt[z * 1024 + bm + t];
      sh_Bi[t] = Bi[z * 1024 + bm + t];
    }
  }

  for (int kk = 0; kk < K; kk += 32) {
    __syncthreads();
    #pragma unroll
    for (int r = 0; r < 2; r++) {
      int chunk = r * 4 + wid;
      const char* src = (const char*)(A + (long)(bm + chunk * 16 + (lane >> 2)) * lda + kk)
                        + (lane & 3) * 16;
      gl_lds16(src, smem + chunk * 1024);
    }
    {
      const char* src = (const char*)(B + (long)(bn + wid * 16 + (lane >> 2)) * ldb + kk)
                        + (lane & 3) * 16;
      gl_lds16(src, smem + 8192 + wid * 1024);
    }
    __syncthreads();
    bf16x8 af[4], bfr[2];
    #pragma unroll
    for (int i = 0; i < 4; i++) af[i] = *(const bf16x8*)&As[(wm + i * 16 + lm) * 32 + lh * 8];
    #pragma unroll
    for (int j = 0; j < 2; j++) bfr[j] = *(const bf16x8*)&Bs[(wn + j * 16 + lm) * 32 + lh * 8];
    #pragma unroll
    for (int i = 0; i < 4; i++)
      #pragma unroll
      for (int j = 0; j < 2; j++)
        acc[i][j] = __builtin_amdgcn_mfma_f32_16x16x32_bf16(af[i], bfr[j], acc[i][j], 0, 0, 0);
  }

  __syncthreads();                       // As/Bs dead; reuse as rep[128][64]
  bf16_t* rep = (bf16_t*)smem;

  if constexpr (ACTF == 1) {
    float lam = softplus_exact(lam_p[0]);
    float tau = softplus_exact(tau_p[0]);
    float invT = frcp(temp_p[0]);
    float ktv[2];
    #pragma unroll
    for (int j = 0; j < 2; j++) ktv[j] = kt[z * 1024 + bn + wn + j * 16 + lm];
    #pragma unroll
    for (int i = 0; i < 4; i++) {
      #pragma unroll
      for (int q = 0; q < 4; q++) {
        int r = wm + i * 16 + lh * 4 + q;
        float qtv = sh_qt[r], Biv = sh_Bi[r];
        float nOQ = fmaxf(qtv * qtv - 1.f, 0.f);
        #pragma unroll
        for (int j = 0; j < 2; j++) {
          float inner = acc[i][j][q];
          float nQK = fmaxf(inner * inner - 1.f, 0.f);
          float numer = -(ktv[j] + inner * qtv);
          float Zc = fminf(fmaxf(numer * __builtin_amdgcn_rsqf(fmaf(nQK, nOQ, 2.5e-5f)), -1.f), 1.f);
          float xx = fmaxf(-inner, 1.001f);
          float dist = __logf(xx + sqrtf(fmaf(xx, xx, -1.f)));        // acosh
          float u = fminf(dist * 0.025f, 0.5f);
          float u2 = u * u;
          float sd = 2.66666667f * u * fmaf(u2, fmaf(u2, 0.13333333f, -0.33333333f), 1.f);
          float s2 = sd * sd;                                          // H = ln cosh(sd)
          float H = s2 * fmaf(s2, fmaf(s2, 0.02222222f, -0.08333333f), 0.5f);
          // Phi = softplus(a) - c  via  sp(a) = a/2 + ln2 + lncosh(a/2), a in [-1.1,1.9]
          float a = Biv + Zc - 0.1f;
          float w = 0.5f * a;
          float w2 = w * w;
          float lc = w2 * fmaf(w2, fmaf(w2, fmaf(w2, -0.0067460317f, 0.0222222222f), -0.0833333333f), 0.5f);
          float Phi = w + 0.69314718056f + lc - 0.64439666007f;
          float e = __expf((-lam * H - tau * Phi) * invT);
          rep[r * 64 + wn + j * 16 + lm] = (bf16_t)e;
        }
      }
    }
  } else {
    #pragma unroll
    for (int i = 0; i < 4; i++) {
      #pragma unroll
      for (int q = 0; q < 4; q++) {
        int r = wm + i * 16 + lh * 4 + q;
        #pragma unroll
        for (int j = 0; j < 2; j++)
          rep[r * 64 + wn + j * 16 + lm] = (bf16_t)gelu_fast(acc[i][j][q]);
      }
    }
  }
  __syncthreads();

  // 4 rounds: coalesced 16B LDS read -> coalesced 16B global store (+ rowsum for score)
  bf16_t* C = Cg + (long)z * sC;
  #pragma unroll
  for (int rd = 0; rd < 4; rd++) {
    int off = rd * 4096 + t * 16;       // byte offset in rep
    int lr = off >> 7;                  // local row (128 B/row)
    int lc = (off & 127) >> 1;          // local col
    bf16x8 vv = *(const bf16x8*)(smem + off);
    *(bf16x8*)(C + (long)(bm + lr) * ldc + bn + lc) = vv;
    if constexpr (ACTF == 1) {
      float s = 0.f;
      #pragma unroll
      for (int e = 0; e < 8; e++) s += (float)vv[e];
      s += __shfl_xor(s, 1, 64);
      s += __shfl_xor(s, 2, 64);
      s += __shfl_xor(s, 4, 64);
      if ((t & 7) == 0)
        aux[((long)z * 1024 + bm + lr) * 16 + blockIdx.y] = s;
    }
  }
}

// ---------------- generic MFMA GEMM (fp32 out / PV-normalize) ----------------
// ACT: 0 fp32 write | 4 normalize-by-16-partials (PV)
template<int BM, int BN, int WM, int WN, int ACT>
DEV void gemm_body(
    const bf16_t* __restrict__ Ag, int lda, long sA,
    const bf16_t* __restrict__ Bg, int ldb, long sB,
    float* __restrict__ Cg, int ldc, long sC,
    int K, const float* __restrict__ aux)
{
  constexpr int MI = WM / 16, NJ = WN / 16;
  constexpr int NWN = BN / WN;
  __shared__ bf16_t As[BM][32];
  __shared__ bf16_t Bs[BN][32];
  __shared__ float sh_inv[BM];
  const int t = threadIdx.x;
  const int wid = t >> 6, lane = t & 63;
  const int lm = lane & 15, lh = lane >> 4;
  const int z = blockIdx.z;
  const bf16_t* A = Ag + (long)z * sA;
  const bf16_t* B = Bg + (long)z * sB;
  const int bm = blockIdx.x * BM;
  const int bn = blockIdx.y * BN;
  const int wm = (wid / NWN) * WM;
  const int wn = (wid % NWN) * WN;
  f32x4 acc[MI][NJ] = {};

  for (int kk = 0; kk < K; kk += 32) {
    __syncthreads();
    #pragma unroll
    for (int r = 0; r < BM / 64; r++) {
      int chunk = r * 4 + wid;
      const char* src = (const char*)(A + (long)(bm + chunk * 16 + (lane >> 2)) * lda + kk)
                        + (lane & 3) * 16;
      gl_lds16(src, (char*)&As[0][0] + chunk * 1024);
    }
    #pragma unroll
    for (int r = 0; r < BN / 64; r++) {
      int chunk = r * 4 + wid;
      const char* src = (const char*)(B + (long)(bn + chunk * 16 + (lane >> 2)) * ldb + kk)
                        + (lane & 3) * 16;
      gl_lds16(src, (char*)&Bs[0][0] + chunk * 1024);
    }
    __syncthreads();
    bf16x8 af[MI], bfr[NJ];
    #pragma unroll
    for (int i = 0; i < MI; i++) af[i] = *(const bf16x8*)&As[wm + i * 16 + lm][lh * 8];
    #pragma unroll
    for (int j = 0; j < NJ; j++) bfr[j] = *(const bf16x8*)&Bs[wn + j * 16 + lm][lh * 8];
    #pragma unroll
    for (int i = 0; i < MI; i++)
      #pragma unroll
      for (int j = 0; j < NJ; j++)
        acc[i][j] = __builtin_amdgcn_mfma_f32_16x16x32_bf16(af[i], bfr[j], acc[i][j], 0, 0, 0);
  }

  float* C = Cg + (long)z * sC;
  if constexpr (ACT == 4) {
    if (t < BM) {
      const float* pr = aux + ((long)z * 1024 + bm + t) * 16;
      float su = 0.f;
      #pragma unroll
      for (int p = 0; p < 16; p++) su += pr[p];
      sh_inv[t] = frcp(su * (1.f + 1e-8f));
    }
    __syncthreads();
    #pragma unroll
    for (int i = 0; i < MI; i++) {
      #pragma unroll
      for (int q = 0; q < 4; q++) {
        int r = wm + i * 16 + lh * 4 + q;
        float sc = sh_inv[r];
        #pragma unroll
        for (int j = 0; j < NJ; j++)
          C[(long)(bm + r) * ldc + bn + wn + j * 16 + lm] = acc[i][j][q] * sc;
      }
    }
  } else {
    #pragma unroll
    for (int i = 0; i < MI; i++) {
      #pragma unroll
      for (int q = 0; q < 4; q++) {
        long row = bm + wm + i * 16 + lh * 4 + q;
        #pragma unroll
        for (int j = 0; j < NJ; j++)
          C[row * ldc + bn + wn + j * 16 + lm] = acc[i][j][q];
      }
    }
  }
}

// ---- named wrappers ----
#define GEMMR_ARGS const bf16_t* A, int lda, long sA, const bf16_t* B, int ldb, long sB, \
                   bf16_t* C, int ldc, long sC, int K, float* aux, \
                   const float* qt, const float* Bi, const float* kt, \
                   const float* lam, const float* tau, const float* temp
#define GEMMR_PASS A,lda,sA,B,ldb,sB,C,ldc,sC,K,aux,qt,Bi,kt,lam,tau,temp
#define GEMMF_ARGS const bf16_t* A, int lda, long sA, const bf16_t* B, int ldb, long sB, \
                   float* C, int ldc, long sC, int K, const float* aux
#define GEMMF_PASS A,lda,sA,B,ldb,sB,C,ldc,sC,K,aux

__global__ __launch_bounds__(256) void gemm_qk (GEMMR_ARGS){ gemm_rep_body<1>(GEMMR_PASS); }
__global__ __launch_bounds__(256) void gemm_f1 (GEMMR_ARGS){ gemm_rep_body<0>(GEMMR_PASS); }
__global__ __launch_bounds__(256) void gemm_qkv(GEMMF_ARGS){ gemm_body<128,128,64,64,0>(GEMMF_PASS); }
__global__ __launch_bounds__(256) void gemm_pv (GEMMF_ARGS){ gemm_body< 64, 64,32,32,4>(GEMMF_PASS); }
__global__ __launch_bounds__(256) void gemm_wo (GEMMF_ARGS){ gemm_body< 64, 64,32,32,0>(GEMMF_PASS); }
__global__ __launch_bounds__(256) void gemm_f2 (GEMMF_ARGS){ gemm_body< 64, 64,32,32,0>(GEMMF_PASS); }

extern "C" void kernel_launch(void* const* d_in, const int* in_sizes, int n_in,
                              void* d_out, int out_size, void* d_ws, size_t ws_size,
                              hipStream_t stream) {
  const float* x    = (const float*)d_in[0];
  const float* Wq   = (const float*)d_in[1];
  const float* Wk   = (const float*)d_in[2];
  const float* Wv   = (const float*)d_in[3];
  const float* Wo   = (const float*)d_in[4];
  const float* W1   = (const float*)d_in[5];
  const float* W2   = (const float*)d_in[6];
  const float* g1   = (const float*)d_in[7];
  const float* b1   = (const float*)d_in[8];
  const float* g2   = (const float*)d_in[9];
  const float* b2   = (const float*)d_in[10];
  const float* temp = (const float*)d_in[11];
  const float* beta = (const float*)d_in[12];
  const float* tau  = (const float*)d_in[13];
  const float* lam  = (const float*)d_in[14];

  char* W = (char*)d_ws;
  bf16_t* Wqkvb = (bf16_t*)(W + 0);          // [1536][544]
  bf16_t* Wob   = (bf16_t*)(W + 1671168);    // [512][544]
  bf16_t* W1b   = (bf16_t*)(W + 2228224);    // [2048][544]
  bf16_t* W2b   = (bf16_t*)(W + 4456448);    // [512][2080]
  bf16_t* y1b   = (bf16_t*)(W + 6586368);    // [2048][544]
  float*  qkvs  = (float*) (W + 8814592);    // [2048][1536] fp32
  float*  mt    = (float*) (W + 8814592);    // [16][1024][64] fp32 (alias after qkv_post)
  float*  tmp   = (float*) (W + 13008896);   // [2048][512] fp32 (alias)
  float*  outs  = (float*) (W + 17203200);   // [2048][512] fp32 (alias)
  bf16_t* Qab   = (bf16_t*)(W + 21397504);   // [16][1024][96]
  bf16_t* Kab   = (bf16_t*)(W + 24543232);   // [16][1024][96]
  bf16_t* VTt   = (bf16_t*)(W + 27688960);   // [16][64][1024]
  float*  qt    = (float*) (W + 29786112);
  float*  kt    = (float*) (W + 29851648);
  float*  Bi    = (float*) (W + 29917184);
  bf16_t* Pb    = (bf16_t*)(W + 29982720);   // [16][1024][1024] bf16
  float*  part  = (float*) (W + 63537152);   // [16][1024][16] fp32 (1 MB)
  bf16_t* VT    = (bf16_t*)(W + 64585728);   // [16][1024][64]
  bf16_t* y2b   = (bf16_t*)(W + 66682880);   // [2048][544]
  bf16_t* hb    = (bf16_t*)(W + 68911104);   // [2048][2080]  (end 77.4 MB)
  bf16_t* attnb = y1b;                       // alias (y1b dead after QKV GEMM)

  // 0. weight conversions (time moved to last k-slot)
  conv_all<<<12864, 256, 0, stream>>>(Wq, Wk, Wv, Wo, W1, W2, Wqkvb, Wob, W1b, W2b);

  // 1. LN1 -> bf16
  ln_fwd<<<2048, 256, 0, stream>>>(x, g1, b1, y1b);

  // 2. fused QKV projection
  gemm_qkv<<<dim3(16,12,1),256,0,stream>>>(
      y1b,544,0, Wqkvb,544,0, qkvs,1536,0, 544, nullptr);

  // 3. heads + add_time + v_tan + per-row constants
  qkv_post<<<2048, 512, 0, stream>>>(qkvs, Qab, Kab, VT, qt, kt, Bi, beta);

  // 4. VT -> VTt transpose
  vt_tr<<<dim3(32,2,16),256,0,stream>>>(VT, VTt);

  // 5. batched QK^T + score + exp -> bf16 P (LDS repack, coalesced) + 16 partials/row
  gemm_qk<<<dim3(8,16,16),256,0,stream>>>(
      Qab,96,(long)1024*96, Kab,96,(long)1024*96, Pb,1024,(long)1024*1024, 96, part,
      qt,Bi,kt, lam,tau,temp);

  // 6. batched PV with normalization epilogue
  gemm_pv<<<dim3(16,1,16),256,0,stream>>>(
      Pb,1024,(long)1024*1024, VTt,1024,(long)64*1024, mt,64,(long)1024*64, 1024, part);

  // 7. expmap0 + merge heads -> attnb
  merge_heads<<<2048, 512, 0, stream>>>(mt, attnb);

  // 8. Wo projection -> fp32 tmp
  gemm_wo<<<dim3(32,8,1),256,0,stream>>>(
      attnb,544,0, Wob,544,0, tmp,512,0, 544, nullptr);

  // 9. residual + LN2
  res_ln<<<2048, 256, 0, stream>>>(tmp, x, g2, b2, outs, y2b);

  // 10. FFN up + GELU -> bf16 hb cols 0..2047 (LDS repack, coalesced)
  gemm_f1<<<dim3(16,32,1),256,0,stream>>>(
      y2b,544,0, W1b,544,0, hb,2080,0, 544, nullptr,
      nullptr,nullptr,nullptr,nullptr,nullptr,nullptr);

  // 11. time coordinate for h (col 2048)
  addtime_row<<<2048, 256, 0, stream>>>(hb);

  // 12. FFN down -> fp32 tmp
  gemm_f2<<<dim3(32,8,1),256,0,stream>>>(
      hb,2080,0, W2b,2080,0, tmp,512,0, 2080, nullptr);

  // 13. final residual + add_time -> d_out
  final_k<<<2048, 256, 0, stream>>>(tmp, outs, (float*)d_out);
}

// Round 6
// 158.446 us; speedup vs baseline: 19.6457x; 1.1625x over previous
//
#include <hip/hip_runtime.h>
#include <math.h>

#define DEV static __device__ __forceinline__

typedef __bf16 bf16_t;
typedef __bf16 bf16x8 __attribute__((ext_vector_type(8)));
typedef float f32x4 __attribute__((ext_vector_type(4)));

// ---------- fast transcendentals ----------
DEV float frcp(float x){ return __builtin_amdgcn_rcpf(x); }
DEV float softplus_fast(float x){
  return fmaxf(x, 0.f) + __logf(1.f + __expf(-fabsf(x)));
}
DEV float tanh_fast(float z){
  float e2 = __expf(2.f * z);
  return (e2 - 1.f) * frcp(e2 + 1.f);
}
DEV float gelu_fast(float v){
  float u = 0.7978845608028654f * fmaf(0.044715f * v, v * v, v);
  u = fminf(fmaxf(u, -15.f), 15.f);
  return 0.5f * v * (1.f + tanh_fast(u));
}

DEV void gl_lds16(const void* g, void* l) {
  __builtin_amdgcn_global_load_lds((const __attribute__((address_space(1))) void*)g,
                                   (__attribute__((address_space(3))) void*)l, 16, 0, 0);
}

DEV float waveReduceSum(float v){
  #pragma unroll
  for (int o = 32; o > 0; o >>= 1) v += __shfl_xor(v, o, 64);
  return v;
}
DEV float blockReduceSum(float v, float* sh){
  v = waveReduceSum(v);
  int w = threadIdx.x >> 6;
  int nw = blockDim.x >> 6;
  __syncthreads();
  if ((threadIdx.x & 63) == 0) sh[w] = v;
  __syncthreads();
  float r = sh[0];
  for (int i = 1; i < nw; i++) r += sh[i];
  return r;
}

// ---------------- weight conversions (time moved to LAST k-slot) ----------------
__global__ __launch_bounds__(256) void conv_all(
    const float* __restrict__ Wq, const float* __restrict__ Wk,
    const float* __restrict__ Wv, const float* __restrict__ Wo,
    const float* __restrict__ W1, const float* __restrict__ W2,
    bf16_t* __restrict__ Wqkvb, bf16_t* __restrict__ Wob,
    bf16_t* __restrict__ W1b, bf16_t* __restrict__ W2b)
{
  long i = (long)blockIdx.x * 256 + threadIdx.x;
  if (i < 1114112) {                       // Wq|Wk|Wv|Wo : [512][513] -> [512][544]
    int w = (int)(i / (512 * 544));
    long rem = i - (long)w * (512 * 544);
    long r = rem / 544;
    int c = (int)(rem - r * 544);
    const float* src = (w == 0) ? Wq : (w == 1) ? Wk : (w == 2) ? Wv : Wo;
    float v = (c < 512) ? src[r * 513 + c + 1] : (c == 512 ? src[r * 513] : 0.f);
    if (w < 3) Wqkvb[(long)w * 512 * 544 + rem] = (bf16_t)v;
    else       Wob[rem] = (bf16_t)v;
  } else if (i < 2228224) {                // W1 : [2048][513] -> [2048][544]
    long j = i - 1114112;
    long r = j / 544;
    int c = (int)(j - r * 544);
    W1b[j] = (c < 512) ? (bf16_t)W1[r * 513 + c + 1]
           : (c == 512 ? (bf16_t)W1[r * 513] : (bf16_t)0.f);
  } else if (i < 3293184) {                // W2 : [512][2049] -> [512][2080]
    long j = i - 2228224;
    long r = j / 2080;
    int c = (int)(j - r * 2080);
    W2b[j] = (c < 2048) ? (bf16_t)W2[r * 2049 + c + 1]
           : (c == 2048 ? (bf16_t)W2[r * 2049] : (bf16_t)0.f);
  }
}

// ---------------- LN1: y[0..511]=spatial, y[512]=time, 513..543=0 ----------------
__global__ __launch_bounds__(256) void ln_fwd(
    const float* __restrict__ xin,
    const float* __restrict__ g, const float* __restrict__ b,
    bf16_t* __restrict__ y)
{
  __shared__ float sh[8];
  int row = blockIdx.x;
  const float* xr = xin + (long)row * 513 + 1;
  int t = threadIdx.x;
  float a0 = xr[t], a1 = xr[t + 256];
  float s  = blockReduceSum(a0 + a1, sh);
  float s2 = blockReduceSum(a0 * a0 + a1 * a1, sh);
  float mu = s * (1.f / 512.f);
  float var = s2 * (1.f / 512.f) - mu * mu;
  float inv = rsqrtf(var + 1e-5f);
  float y0 = (a0 - mu) * inv * g[t] + b[t];
  float y1v = (a1 - mu) * inv * g[t + 256] + b[t + 256];
  float q = blockReduceSum(y0 * y0 + y1v * y1v, sh);
  bf16_t* yr = y + (long)row * 544;
  yr[t] = (bf16_t)y0;
  yr[t + 256] = (bf16_t)y1v;
  if (t == 0) yr[512] = (bf16_t)sqrtf(q + 1.f);
  if (t < 31) yr[513 + t] = (bf16_t)0.f;
}

// ---------------- residual + LN2 ----------------
__global__ __launch_bounds__(256) void res_ln(
    const float* __restrict__ wo,
    const float* __restrict__ xin,
    const float* __restrict__ g, const float* __restrict__ b,
    float* __restrict__ outs,
    bf16_t* __restrict__ y)
{
  __shared__ float sh[8];
  int row = blockIdx.x;
  int t = threadIdx.x;
  float a0 = wo[(long)row * 512 + t]       + xin[(long)row * 513 + 1 + t];
  float a1 = wo[(long)row * 512 + t + 256] + xin[(long)row * 513 + 1 + t + 256];
  outs[(long)row * 512 + t] = a0;
  outs[(long)row * 512 + t + 256] = a1;
  float s  = blockReduceSum(a0 + a1, sh);
  float s2 = blockReduceSum(a0 * a0 + a1 * a1, sh);
  float mu = s * (1.f / 512.f);
  float var = s2 * (1.f / 512.f) - mu * mu;
  float inv = rsqrtf(var + 1e-5f);
  float y0 = (a0 - mu) * inv * g[t] + b[t];
  float y1v = (a1 - mu) * inv * g[t + 256] + b[t + 256];
  float q = blockReduceSum(y0 * y0 + y1v * y1v, sh);
  bf16_t* yr = y + (long)row * 544;
  yr[t] = (bf16_t)y0;
  yr[t + 256] = (bf16_t)y1v;
  if (t == 0) yr[512] = (bf16_t)sqrtf(q + 1.f);
  if (t < 31) yr[513 + t] = (bf16_t)0.f;
}

// ---------------- add_time over bf16 h [2048][2080] ----------------
__global__ __launch_bounds__(256) void addtime_row(bf16_t* __restrict__ h)
{
  __shared__ float sh[8];
  int row = blockIdx.x;
  bf16_t* hr = h + (long)row * 2080;
  int t = threadIdx.x;
  float s2 = 0.f;
  bf16x8 v = *(const bf16x8*)&hr[t * 8];
  #pragma unroll
  for (int j = 0; j < 8; j++) {
    float f = (float)v[j];
    s2 = fmaf(f, f, s2);
  }
  s2 = blockReduceSum(s2, sh);
  if (t == 0) hr[2048] = (bf16_t)sqrtf(s2 + 1.f);
  if (t < 31) hr[2049 + t] = (bf16_t)0.f;
}

// ---------------- final residual + add_time -> d_out [t, s] ----------------
__global__ __launch_bounds__(256) void final_k(
    const float* __restrict__ h2, const float* __restrict__ outs,
    float* __restrict__ out)
{
  __shared__ float sh[8];
  int row = blockIdx.x;
  int t = threadIdx.x;
  float o0 = h2[(long)row * 512 + t]       + outs[(long)row * 512 + t];
  float o1 = h2[(long)row * 512 + t + 256] + outs[(long)row * 512 + t + 256];
  float q = blockReduceSum(o0 * o0 + o1 * o1, sh);
  float* yr = out + (long)row * 513;
  yr[1 + t] = o0;
  yr[1 + t + 256] = o1;
  if (t == 0) yr[0] = sqrtf(q + 1.f);
}

// ---------------- QKV post (bf16 in, K=64 Q/K out, coalesced VT) ----------------
__global__ __launch_bounds__(512) void qkv_post(
    const bf16_t* __restrict__ S,     // [2048][1536] bf16
    bf16_t* __restrict__ Qab,         // [16][1024][64]
    bf16_t* __restrict__ Kab,         // [16][1024][64]
    bf16_t* __restrict__ VT,          // [16][1024][64]
    float* __restrict__ qt, float* __restrict__ kt, float* __restrict__ Bi,
    const float* __restrict__ beta_p)
{
  int row = blockIdx.x;
  int b = row >> 10, n = row & 1023;
  int h = threadIdx.x >> 6, d = threadIdx.x & 63;
  long base = (long)row * 1536;
  bf16_t qraw = S[base + h * 64 + d];
  bf16_t kraw = S[base + 512 + h * 64 + d];
  float qv = (float)qraw;
  float kv = (float)kraw;
  float vv = (float)S[base + 1024 + h * 64 + d];
  float q2 = waveReduceSum(qv * qv);
  float k2 = waveReduceSum(kv * kv);
  float v2 = waveReduceSum(vv * vv);
  float qT = sqrtf(1.f + q2);
  float kT = sqrtf(1.f + k2);
  float vTt_ = sqrtf(1.f + v2);
  float sn0 = sqrtf(v2);
  float dd = __logf(vTt_ + sn0);          // acosh
  float coef = dd * frcp(fmaxf(sn0, 1e-8f));
  int z = b * 8 + h;
  long a64 = ((long)z * 1024 + n) * 64;
  Qab[a64 + d] = qraw;
  Kab[a64 + d] = kraw;
  VT[a64 + d] = (bf16_t)(coef * vv);
  if (d == 0) {
    int ob = z * 1024 + n;
    qt[ob] = qT;
    kt[ob] = kT;
    float beta = softplus_fast(beta_p[0]);
    float xq = fmaxf(qT, 1.001f);
    float sh_ = sqrtf(fmaxf(xq * xq - 1.f, 0.f));
    float rr = beta * frcp(sh_);
    Bi[ob] = sqrtf(fmaxf(1.f - rr * rr, 0.f) + 1e-8f);
  }
}

// ---------------- VT [z][n][d] -> VTt [z][d][n] ----------------
__global__ __launch_bounds__(256) void vt_tr(
    const bf16_t* __restrict__ VT, bf16_t* __restrict__ VTt)
{
  __shared__ bf16_t tile[32][33];
  int z = blockIdx.z, n0 = blockIdx.x * 32, d0 = blockIdx.y * 32;
  int tx = threadIdx.x & 31, ty = threadIdx.x >> 5;
  const bf16_t* src = VT + (long)z * 1024 * 64;
  #pragma unroll
  for (int r = 0; r < 32; r += 8)
    tile[ty + r][tx] = src[(long)(n0 + ty + r) * 64 + d0 + tx];
  __syncthreads();
  bf16_t* dst = VTt + (long)z * 64 * 1024;
  #pragma unroll
  for (int r = 0; r < 32; r += 8)
    dst[(long)(d0 + ty + r) * 1024 + n0 + tx] = tile[tx][ty + r];
}

// ---------------- merge heads: spatial at 0..511, time at 512 ----------------
__global__ __launch_bounds__(512) void merge_heads(
    const float* __restrict__ mt, bf16_t* __restrict__ attn)
{
  __shared__ float t2s[8];
  int row = blockIdx.x;
  int b = row >> 10, n = row & 1023;
  int h = threadIdx.x >> 6, d = threadIdx.x & 63;
  int z = b * 8 + h;
  float v = mt[((long)z * 1024 + n) * 64 + d];
  float s2 = waveReduceSum(v * v);
  float nn = fmaxf(sqrtf(s2), 1e-8f);
  float e = __expf(nn), ei = frcp(e);
  float coef = 0.5f * (e - ei) * frcp(nn);
  attn[(long)row * 544 + h * 64 + d] = (bf16_t)(coef * v);
  if (d == 0) {
    float th = 0.5f * (e + ei);
    t2s[h] = th * th;
  }
  __syncthreads();
  if (threadIdx.x == 0) {
    float t2 = t2s[0] + t2s[1] + t2s[2] + t2s[3] + t2s[4] + t2s[5] + t2s[6] + t2s[7] - 7.f;
    attn[(long)row * 544 + 512] = (bf16_t)sqrtf(fmaxf(t2, 1e-8f));
  }
  if (threadIdx.x < 31) attn[(long)row * 544 + 513 + threadIdx.x] = (bf16_t)0.f;
}

// ============ bf16-output GEMM with LDS repack (BM=128, BN=64, 4 waves) ============
// ACTF: 0 = GELU | 1 = score+exp (QK, K=64, time folded in epilogue) | 2 = plain bf16
template<int ACTF>
DEV void gemm_rep_body(
    const bf16_t* __restrict__ Ag, int lda, long sA,
    const bf16_t* __restrict__ Bg, int ldb, long sB,
    bf16_t* __restrict__ Cg, int ldc, long sC,
    int K, float* __restrict__ aux,
    const float* __restrict__ qt, const float* __restrict__ Bi,
    const float* __restrict__ kt,
    const float* __restrict__ lam_p, const float* __restrict__ tau_p,
    const float* __restrict__ temp_p)
{
  __shared__ char smem[16384];          // k-loop: As 8K | Bs 4K ; epilogue: rep 16K
  __shared__ float sh_qt[128], sh_Bc[128];
  bf16_t* As = (bf16_t*)smem;           // [128][32]
  bf16_t* Bs = (bf16_t*)(smem + 8192);  // [64][32]
  const int t = threadIdx.x;
  const int wid = t >> 6, lane = t & 63;
  const int lm = lane & 15, lh = lane >> 4;
  const int z = blockIdx.z;
  const bf16_t* A = Ag + (long)z * sA;
  const bf16_t* B = Bg + (long)z * sB;
  const int bm = blockIdx.x * 128;
  const int bn = blockIdx.y * 64;
  const int wm = (wid >> 1) * 64;
  const int wn = (wid & 1) * 32;
  f32x4 acc[4][2] = {};

  if constexpr (ACTF == 1) {
    if (t < 128) {
      sh_qt[t] = qt[z * 1024 + bm + t];
      sh_Bc[t] = Bi[z * 1024 + bm + t] - 0.1f;
    }
  }

  for (int kk = 0; kk < K; kk += 32) {
    __syncthreads();
    #pragma unroll
    for (int r = 0; r < 2; r++) {
      int chunk = r * 4 + wid;
      const char* src = (const char*)(A + (long)(bm + chunk * 16 + (lane >> 2)) * lda + kk)
                        + (lane & 3) * 16;
      gl_lds16(src, smem + chunk * 1024);
    }
    {
      const char* src = (const char*)(B + (long)(bn + wid * 16 + (lane >> 2)) * ldb + kk)
                        + (lane & 3) * 16;
      gl_lds16(src, smem + 8192 + wid * 1024);
    }
    __syncthreads();
    bf16x8 af[4], bfr[2];
    #pragma unroll
    for (int i = 0; i < 4; i++) af[i] = *(const bf16x8*)&As[(wm + i * 16 + lm) * 32 + lh * 8];
    #pragma unroll
    for (int j = 0; j < 2; j++) bfr[j] = *(const bf16x8*)&Bs[(wn + j * 16 + lm) * 32 + lh * 8];
    #pragma unroll
    for (int i = 0; i < 4; i++)
      #pragma unroll
      for (int j = 0; j < 2; j++)
        acc[i][j] = __builtin_amdgcn_mfma_f32_16x16x32_bf16(af[i], bfr[j], acc[i][j], 0, 0, 0);
  }

  __syncthreads();                       // As/Bs dead; reuse as rep[128][64]
  bf16_t* rep = (bf16_t*)smem;

  if constexpr (ACTF == 1) {
    // constants: fold lam/tau/T
    float lam = softplus_fast(lam_p[0]);
    float tau = softplus_fast(tau_p[0]);
    float invT = frcp(temp_p[0]);
    float A1 = -lam * invT;
    float A2 = -tau * invT;
    float A2h = 0.5f * A2;
    float K0 = A2 * 0.048750465f;        // ln2 - ln(1+e^-0.1)
    float ktv[2];
    #pragma unroll
    for (int j = 0; j < 2; j++) ktv[j] = kt[z * 1024 + bn + wn + j * 16 + lm];
    #pragma unroll
    for (int i = 0; i < 4; i++) {
      #pragma unroll
      for (int q = 0; q < 4; q++) {
        int r = wm + i * 16 + lh * 4 + q;
        float qtv = sh_qt[r], Bc = sh_Bc[r];
        float nOQ = fmaf(qtv, qtv, -1.f);
        #pragma unroll
        for (int j = 0; j < 2; j++) {
          float inner = fmaf(-qtv, ktv[j], acc[i][j][q]);   // time term folded here
          float nQK = fmaxf(fmaf(inner, inner, -1.f), 0.f);
          float ri = __builtin_amdgcn_rsqf(fmaf(nQK, nOQ, 2.5e-5f));
          float zr = fmaf(inner, qtv, ktv[j]) * ri;
          float Zc = fminf(fmaxf(-zr, -1.f), 1.f);
          float xx = fmaxf(-inner, 1.001f);
          // dist = acosh(xx) ~= ln(2xx); u = dist/40; H = lncosh((8/3)tanh(u)) poly in p=u^2
          float u = fmaf(__log2f(xx), 0.01732868f, 0.01732868f);
          float p = fminf(u * u, 0.09f);
          float H = p * fmaf(p, -6.584f, 3.5556f);
          // Phi = 0.5a + lncosh(a/2) + 0.0487505 ; lncosh poly in a^2
          float a = Zc + Bc;
          float a2 = a * a;
          float lc = a2 * fmaf(a2, fmaf(a2, 0.00034722f, -0.0052083f), 0.125f);
          float lgt = fmaf(A1, H, fmaf(A2, lc, fmaf(A2h, a, K0)));
          float e = __expf(lgt);
          rep[r * 64 + wn + j * 16 + lm] = (bf16_t)e;
        }
      }
    }
  } else if constexpr (ACTF == 0) {
    #pragma unroll
    for (int i = 0; i < 4; i++) {
      #pragma unroll
      for (int q = 0; q < 4; q++) {
        int r = wm + i * 16 + lh * 4 + q;
        #pragma unroll
        for (int j = 0; j < 2; j++)
          rep[r * 64 + wn + j * 16 + lm] = (bf16_t)gelu_fast(acc[i][j][q]);
      }
    }
  } else {
    #pragma unroll
    for (int i = 0; i < 4; i++) {
      #pragma unroll
      for (int q = 0; q < 4; q++) {
        int r = wm + i * 16 + lh * 4 + q;
        #pragma unroll
        for (int j = 0; j < 2; j++)
          rep[r * 64 + wn + j * 16 + lm] = (bf16_t)acc[i][j][q];
      }
    }
  }
  __syncthreads();

  // 4 rounds: coalesced 16B LDS read -> coalesced 16B global store (+ rowsum for score)
  bf16_t* C = Cg + (long)z * sC;
  #pragma unroll
  for (int rd = 0; rd < 4; rd++) {
    int off = rd * 4096 + t * 16;       // byte offset in rep
    int lr = off >> 7;                  // local row (128 B/row)
    int lc = (off & 127) >> 1;          // local col
    bf16x8 vv = *(const bf16x8*)(smem + off);
    *(bf16x8*)(C + (long)(bm + lr) * ldc + bn + lc) = vv;
    if constexpr (ACTF == 1) {
      float s = 0.f;
      #pragma unroll
      for (int e = 0; e < 8; e++) s += (float)vv[e];
      s += __shfl_xor(s, 1, 64);
      s += __shfl_xor(s, 2, 64);
      s += __shfl_xor(s, 4, 64);
      if ((t & 7) == 0)
        aux[((long)z * 16 + blockIdx.y) * 1024 + bm + lr] = s;
    }
  }
}

// ---------------- generic MFMA GEMM (fp32 out / PV-normalize) ----------------
// ACT: 0 fp32 write | 4 normalize-by-16-partials (PV)
template<int BM, int BN, int WM, int WN, int ACT>
DEV void gemm_body(
    const bf16_t* __restrict__ Ag, int lda, long sA,
    const bf16_t* __restrict__ Bg, int ldb, long sB,
    float* __restrict__ Cg, int ldc, long sC,
    int K, const float* __restrict__ aux)
{
  constexpr int MI = WM / 16, NJ = WN / 16;
  constexpr int NWN = BN / WN;
  __shared__ bf16_t As[BM][32];
  __shared__ bf16_t Bs[BN][32];
  __shared__ float sh_inv[BM];
  const int t = threadIdx.x;
  const int wid = t >> 6, lane = t & 63;
  const int lm = lane & 15, lh = lane >> 4;
  const int z = blockIdx.z;
  const bf16_t* A = Ag + (long)z * sA;
  const bf16_t* B = Bg + (long)z * sB;
  const int bm = blockIdx.x * BM;
  const int bn = blockIdx.y * BN;
  const int wm = (wid / NWN) * WM;
  const int wn = (wid % NWN) * WN;
  f32x4 acc[MI][NJ] = {};

  for (int kk = 0; kk < K; kk += 32) {
    __syncthreads();
    #pragma unroll
    for (int r = 0; r < BM / 64; r++) {
      int chunk = r * 4 + wid;
      const char* src = (const char*)(A + (long)(bm + chunk * 16 + (lane >> 2)) * lda + kk)
                        + (lane & 3) * 16;
      gl_lds16(src, (char*)&As[0][0] + chunk * 1024);
    }
    #pragma unroll
    for (int r = 0; r < BN / 64; r++) {
      int chunk = r * 4 + wid;
      const char* src = (const char*)(B + (long)(bn + chunk * 16 + (lane >> 2)) * ldb + kk)
                        + (lane & 3) * 16;
      gl_lds16(src, (char*)&Bs[0][0] + chunk * 1024);
    }
    __syncthreads();
    bf16x8 af[MI], bfr[NJ];
    #pragma unroll
    for (int i = 0; i < MI; i++) af[i] = *(const bf16x8*)&As[wm + i * 16 + lm][lh * 8];
    #pragma unroll
    for (int j = 0; j < NJ; j++) bfr[j] = *(const bf16x8*)&Bs[wn + j * 16 + lm][lh * 8];
    #pragma unroll
    for (int i = 0; i < MI; i++)
      #pragma unroll
      for (int j = 0; j < NJ; j++)
        acc[i][j] = __builtin_amdgcn_mfma_f32_16x16x32_bf16(af[i], bfr[j], acc[i][j], 0, 0, 0);
  }

  float* C = Cg + (long)z * sC;
  if constexpr (ACT == 4) {
    if (t < BM) {
      float su = 0.f;
      #pragma unroll
      for (int p = 0; p < 16; p++)
        su += aux[((long)z * 16 + p) * 1024 + bm + t];
      sh_inv[t] = frcp(su * (1.f + 1e-8f));
    }
    __syncthreads();
    #pragma unroll
    for (int i = 0; i < MI; i++) {
      #pragma unroll
      for (int q = 0; q < 4; q++) {
        int r = wm + i * 16 + lh * 4 + q;
        float sc = sh_inv[r];
        #pragma unroll
        for (int j = 0; j < NJ; j++)
          C[(long)(bm + r) * ldc + bn + wn + j * 16 + lm] = acc[i][j][q] * sc;
      }
    }
  } else {
    #pragma unroll
    for (int i = 0; i < MI; i++) {
      #pragma unroll
      for (int q = 0; q < 4; q++) {
        long row = bm + wm + i * 16 + lh * 4 + q;
        #pragma unroll
        for (int j = 0; j < NJ; j++)
          C[row * ldc + bn + wn + j * 16 + lm] = acc[i][j][q];
      }
    }
  }
}

// ---- named wrappers ----
#define GEMMR_ARGS const bf16_t* A, int lda, long sA, const bf16_t* B, int ldb, long sB, \
                   bf16_t* C, int ldc, long sC, int K, float* aux, \
                   const float* qt, const float* Bi, const float* kt, \
                   const float* lam, const float* tau, const float* temp
#define GEMMR_PASS A,lda,sA,B,ldb,sB,C,ldc,sC,K,aux,qt,Bi,kt,lam,tau,temp
#define GEMMF_ARGS const bf16_t* A, int lda, long sA, const bf16_t* B, int ldb, long sB, \
                   float* C, int ldc, long sC, int K, const float* aux
#define GEMMF_PASS A,lda,sA,B,ldb,sB,C,ldc,sC,K,aux

__global__ __launch_bounds__(256) void gemm_qk (GEMMR_ARGS){ gemm_rep_body<1>(GEMMR_PASS); }
__global__ __launch_bounds__(256) void gemm_f1 (GEMMR_ARGS){ gemm_rep_body<0>(GEMMR_PASS); }
__global__ __launch_bounds__(256) void gemm_qkv(GEMMR_ARGS){ gemm_rep_body<2>(GEMMR_PASS); }
__global__ __launch_bounds__(256) void gemm_pv (GEMMF_ARGS){ gemm_body< 64, 64,32,32,4>(GEMMF_PASS); }
__global__ __launch_bounds__(256) void gemm_wo (GEMMF_ARGS){ gemm_body< 64, 64,32,32,0>(GEMMF_PASS); }
__global__ __launch_bounds__(256) void gemm_f2 (GEMMF_ARGS){ gemm_body< 64, 64,32,32,0>(GEMMF_PASS); }

extern "C" void kernel_launch(void* const* d_in, const int* in_sizes, int n_in,
                              void* d_out, int out_size, void* d_ws, size_t ws_size,
                              hipStream_t stream) {
  const float* x    = (const float*)d_in[0];
  const float* Wq   = (const float*)d_in[1];
  const float* Wk   = (const float*)d_in[2];
  const float* Wv   = (const float*)d_in[3];
  const float* Wo   = (const float*)d_in[4];
  const float* W1   = (const float*)d_in[5];
  const float* W2   = (const float*)d_in[6];
  const float* g1   = (const float*)d_in[7];
  const float* b1   = (const float*)d_in[8];
  const float* g2   = (const float*)d_in[9];
  const float* b2   = (const float*)d_in[10];
  const float* temp = (const float*)d_in[11];
  const float* beta = (const float*)d_in[12];
  const float* tau  = (const float*)d_in[13];
  const float* lam  = (const float*)d_in[14];

  char* W = (char*)d_ws;
  bf16_t* Wqkvb = (bf16_t*)(W + 0);          // [1536][544]
  bf16_t* Wob   = (bf16_t*)(W + 1671168);    // [512][544]
  bf16_t* W1b   = (bf16_t*)(W + 2228224);    // [2048][544]
  bf16_t* W2b   = (bf16_t*)(W + 4456448);    // [512][2080]
  bf16_t* y1b   = (bf16_t*)(W + 6586368);    // [2048][544]
  bf16_t* qkvsb = (bf16_t*)(W + 8814592);    // [2048][1536] bf16 (6.29 MB)
  float*  mt    = (float*) (W + 8814592);    // [16][1024][64] fp32 (alias after qkv_post)
  float*  tmp   = (float*) (W + 15106048);   // [2048][512] fp32
  float*  outs  = (float*) (W + 19300352);   // [2048][512] fp32
  bf16_t* Qab   = (bf16_t*)(W + 23494656);   // [16][1024][64]
  bf16_t* Kab   = (bf16_t*)(W + 25591808);   // [16][1024][64]
  bf16_t* VTt   = (bf16_t*)(W + 27688960);   // [16][64][1024]
  float*  qt    = (float*) (W + 29786112);
  float*  kt    = (float*) (W + 29851648);
  float*  Bi    = (float*) (W + 29917184);
  bf16_t* Pb    = (bf16_t*)(W + 29982720);   // [16][1024][1024] bf16
  float*  part  = (float*) (W + 63537152);   // [16][16][1024] fp32
  bf16_t* VT    = (bf16_t*)(W + 64585728);   // [16][1024][64]
  bf16_t* y2b   = (bf16_t*)(W + 66682880);   // [2048][544]
  bf16_t* hb    = (bf16_t*)(W + 68911104);   // [2048][2080]  (end 77.4 MB)
  bf16_t* attnb = y1b;                       // alias (y1b dead after QKV GEMM)

  // 0. weight conversions
  conv_all<<<12864, 256, 0, stream>>>(Wq, Wk, Wv, Wo, W1, W2, Wqkvb, Wob, W1b, W2b);

  // 1. LN1 -> bf16
  ln_fwd<<<2048, 256, 0, stream>>>(x, g1, b1, y1b);

  // 2. fused QKV projection -> bf16 (repack, coalesced)
  gemm_qkv<<<dim3(16,24,1),256,0,stream>>>(
      y1b,544,0, Wqkvb,544,0, qkvsb,1536,0, 544, nullptr,
      nullptr,nullptr,nullptr,nullptr,nullptr,nullptr);

  // 3. heads + add_time + v_tan + per-row constants
  qkv_post<<<2048, 512, 0, stream>>>(qkvsb, Qab, Kab, VT, qt, kt, Bi, beta);

  // 4. VT -> VTt transpose
  vt_tr<<<dim3(32,2,16),256,0,stream>>>(VT, VTt);

  // 5. batched QK^T (K=64, time folded) + score + exp -> bf16 P + partials
  gemm_qk<<<dim3(8,16,16),256,0,stream>>>(
      Qab,64,(long)1024*64, Kab,64,(long)1024*64, Pb,1024,(long)1024*1024, 64, part,
      qt,Bi,kt, lam,tau,temp);

  // 6. batched PV with normalization epilogue
  gemm_pv<<<dim3(16,1,16),256,0,stream>>>(
      Pb,1024,(long)1024*1024, VTt,1024,(long)64*1024, mt,64,(long)1024*64, 1024, part);

  // 7. expmap0 + merge heads -> attnb
  merge_heads<<<2048, 512, 0, stream>>>(mt, attnb);

  // 8. Wo projection -> fp32 tmp
  gemm_wo<<<dim3(32,8,1),256,0,stream>>>(
      attnb,544,0, Wob,544,0, tmp,512,0, 544, nullptr);

  // 9. residual + LN2
  res_ln<<<2048, 256, 0, stream>>>(tmp, x, g2, b2, outs, y2b);

  // 10. FFN up + GELU -> bf16 hb cols 0..2047
  gemm_f1<<<dim3(16,32,1),256,0,stream>>>(
      y2b,544,0, W1b,544,0, hb,2080,0, 544, nullptr,
      nullptr,nullptr,nullptr,nullptr,nullptr,nullptr);

  // 11. time coordinate for h (col 2048)
  addtime_row<<<2048, 256, 0, stream>>>(hb);

  // 12. FFN down -> fp32 tmp
  gemm_f2<<<dim3(32,8,1),256,0,stream>>>(
      hb,2080,0, W2b,2080,0, tmp,512,0, 2080, nullptr);

  // 13. final residual + add_time -> d_out
  final_k<<<2048, 256, 0, stream>>>(tmp, outs, (float*)d_out);
}

// Round 7
// 147.503 us; speedup vs baseline: 21.1031x; 1.0742x over previous
//
#include <hip/hip_runtime.h>
#include <math.h>

#define DEV static __device__ __forceinline__

typedef __bf16 bf16_t;
typedef __bf16 bf16x8 __attribute__((ext_vector_type(8)));
typedef float f32x4 __attribute__((ext_vector_type(4)));

#define MFMA16(a,b,c) __builtin_amdgcn_mfma_f32_16x16x32_bf16(a,b,c,0,0,0)

// ---------- fast transcendentals ----------
DEV float frcp(float x){ return __builtin_amdgcn_rcpf(x); }
DEV float softplus_fast(float x){
  return fmaxf(x, 0.f) + __logf(1.f + __expf(-fabsf(x)));
}
DEV float tanh_fast(float z){
  float e2 = __expf(2.f * z);
  return (e2 - 1.f) * frcp(e2 + 1.f);
}
DEV float gelu_fast(float v){
  float u = 0.7978845608028654f * fmaf(0.044715f * v, v * v, v);
  u = fminf(fmaxf(u, -15.f), 15.f);
  return 0.5f * v * (1.f + tanh_fast(u));
}

DEV void gl_lds16(const void* g, void* l) {
  __builtin_amdgcn_global_load_lds((const __attribute__((address_space(1))) void*)g,
                                   (__attribute__((address_space(3))) void*)l, 16, 0, 0);
}

DEV float waveReduceSum(float v){
  #pragma unroll
  for (int o = 32; o > 0; o >>= 1) v += __shfl_xor(v, o, 64);
  return v;
}
DEV float blockReduceSum(float v, float* sh){
  v = waveReduceSum(v);
  int w = threadIdx.x >> 6;
  int nw = blockDim.x >> 6;
  __syncthreads();
  if ((threadIdx.x & 63) == 0) sh[w] = v;
  __syncthreads();
  float r = sh[0];
  for (int i = 1; i < nw; i++) r += sh[i];
  return r;
}

// ---------------- weight conversions (time moved to LAST k-slot) ----------------
__global__ __launch_bounds__(256) void conv_all(
    const float* __restrict__ Wq, const float* __restrict__ Wk,
    const float* __restrict__ Wv, const float* __restrict__ Wo,
    const float* __restrict__ W1, const float* __restrict__ W2,
    bf16_t* __restrict__ Wqkvb, bf16_t* __restrict__ Wob,
    bf16_t* __restrict__ W1b, bf16_t* __restrict__ W2b)
{
  long i = (long)blockIdx.x * 256 + threadIdx.x;
  if (i < 1114112) {                       // Wq|Wk|Wv|Wo : [512][513] -> [512][544]
    int w = (int)(i / (512 * 544));
    long rem = i - (long)w * (512 * 544);
    long r = rem / 544;
    int c = (int)(rem - r * 544);
    const float* src = (w == 0) ? Wq : (w == 1) ? Wk : (w == 2) ? Wv : Wo;
    float v = (c < 512) ? src[r * 513 + c + 1] : (c == 512 ? src[r * 513] : 0.f);
    if (w < 3) Wqkvb[(long)w * 512 * 544 + rem] = (bf16_t)v;
    else       Wob[rem] = (bf16_t)v;
  } else if (i < 2228224) {                // W1 : [2048][513] -> [2048][544]
    long j = i - 1114112;
    long r = j / 544;
    int c = (int)(j - r * 544);
    W1b[j] = (c < 512) ? (bf16_t)W1[r * 513 + c + 1]
           : (c == 512 ? (bf16_t)W1[r * 513] : (bf16_t)0.f);
  } else if (i < 3293184) {                // W2 : [512][2049] -> [512][2080]
    long j = i - 2228224;
    long r = j / 2080;
    int c = (int)(j - r * 2080);
    W2b[j] = (c < 2048) ? (bf16_t)W2[r * 2049 + c + 1]
           : (c == 2048 ? (bf16_t)W2[r * 2049] : (bf16_t)0.f);
  }
}

// ---------------- LN1 ----------------
__global__ __launch_bounds__(256) void ln_fwd(
    const float* __restrict__ xin,
    const float* __restrict__ g, const float* __restrict__ b,
    bf16_t* __restrict__ y)
{
  __shared__ float sh[8];
  int row = blockIdx.x;
  const float* xr = xin + (long)row * 513 + 1;
  int t = threadIdx.x;
  float a0 = xr[t], a1 = xr[t + 256];
  float s  = blockReduceSum(a0 + a1, sh);
  float s2 = blockReduceSum(a0 * a0 + a1 * a1, sh);
  float mu = s * (1.f / 512.f);
  float var = s2 * (1.f / 512.f) - mu * mu;
  float inv = rsqrtf(var + 1e-5f);
  float y0 = (a0 - mu) * inv * g[t] + b[t];
  float y1v = (a1 - mu) * inv * g[t + 256] + b[t + 256];
  float q = blockReduceSum(y0 * y0 + y1v * y1v, sh);
  bf16_t* yr = y + (long)row * 544;
  yr[t] = (bf16_t)y0;
  yr[t + 256] = (bf16_t)y1v;
  if (t == 0) yr[512] = (bf16_t)sqrtf(q + 1.f);
  if (t < 31) yr[513 + t] = (bf16_t)0.f;
}

// ---------------- residual + LN2 ----------------
__global__ __launch_bounds__(256) void res_ln(
    const float* __restrict__ wo,
    const float* __restrict__ xin,
    const float* __restrict__ g, const float* __restrict__ b,
    float* __restrict__ outs,
    bf16_t* __restrict__ y)
{
  __shared__ float sh[8];
  int row = blockIdx.x;
  int t = threadIdx.x;
  float a0 = wo[(long)row * 512 + t]       + xin[(long)row * 513 + 1 + t];
  float a1 = wo[(long)row * 512 + t + 256] + xin[(long)row * 513 + 1 + t + 256];
  outs[(long)row * 512 + t] = a0;
  outs[(long)row * 512 + t + 256] = a1;
  float s  = blockReduceSum(a0 + a1, sh);
  float s2 = blockReduceSum(a0 * a0 + a1 * a1, sh);
  float mu = s * (1.f / 512.f);
  float var = s2 * (1.f / 512.f) - mu * mu;
  float inv = rsqrtf(var + 1e-5f);
  float y0 = (a0 - mu) * inv * g[t] + b[t];
  float y1v = (a1 - mu) * inv * g[t + 256] + b[t + 256];
  float q = blockReduceSum(y0 * y0 + y1v * y1v, sh);
  bf16_t* yr = y + (long)row * 544;
  yr[t] = (bf16_t)y0;
  yr[t + 256] = (bf16_t)y1v;
  if (t == 0) yr[512] = (bf16_t)sqrtf(q + 1.f);
  if (t < 31) yr[513 + t] = (bf16_t)0.f;
}

// ---------------- add_time over bf16 h [2048][2080] ----------------
__global__ __launch_bounds__(256) void addtime_row(bf16_t* __restrict__ h)
{
  __shared__ float sh[8];
  int row = blockIdx.x;
  bf16_t* hr = h + (long)row * 2080;
  int t = threadIdx.x;
  float s2 = 0.f;
  bf16x8 v = *(const bf16x8*)&hr[t * 8];
  #pragma unroll
  for (int j = 0; j < 8; j++) {
    float f = (float)v[j];
    s2 = fmaf(f, f, s2);
  }
  s2 = blockReduceSum(s2, sh);
  if (t == 0) hr[2048] = (bf16_t)sqrtf(s2 + 1.f);
  if (t < 31) hr[2049 + t] = (bf16_t)0.f;
}

// ---------------- final residual + add_time -> d_out [t, s] ----------------
__global__ __launch_bounds__(256) void final_k(
    const float* __restrict__ h2, const float* __restrict__ outs,
    float* __restrict__ out)
{
  __shared__ float sh[8];
  int row = blockIdx.x;
  int t = threadIdx.x;
  float o0 = h2[(long)row * 512 + t]       + outs[(long)row * 512 + t];
  float o1 = h2[(long)row * 512 + t + 256] + outs[(long)row * 512 + t + 256];
  float q = blockReduceSum(o0 * o0 + o1 * o1, sh);
  float* yr = out + (long)row * 513;
  yr[1 + t] = o0;
  yr[1 + t + 256] = o1;
  if (t == 0) yr[0] = sqrtf(q + 1.f);
}

// ---------------- per-row q/k stats (time coords + B term) ----------------
__global__ __launch_bounds__(512) void qk_stats(
    const bf16_t* __restrict__ S,     // [2048][1536] bf16
    float* __restrict__ qt, float* __restrict__ kt, float* __restrict__ Bi,
    const float* __restrict__ beta_p)
{
  int row = blockIdx.x;
  int b = row >> 10, n = row & 1023;
  int h = threadIdx.x >> 6, d = threadIdx.x & 63;
  long base = (long)row * 1536;
  float qv = (float)S[base + h * 64 + d];
  float kv = (float)S[base + 512 + h * 64 + d];
  float q2 = waveReduceSum(qv * qv);
  float k2 = waveReduceSum(kv * kv);
  if (d == 0) {
    int z = b * 8 + h;
    int ob = z * 1024 + n;
    float qT = sqrtf(1.f + q2);
    qt[ob] = qT;
    kt[ob] = sqrtf(1.f + k2);
    float beta = softplus_fast(beta_p[0]);
    float xq = fmaxf(qT, 1.001f);
    float sh_ = sqrtf(fmaxf(xq * xq - 1.f, 0.f));
    float rr = beta * frcp(sh_);
    Bi[ob] = sqrtf(fmaxf(1.f - rr * rr, 0.f) + 1e-8f);
  }
}

// ---------------- v_tan + transpose: qkvsb v-section -> VTt [z][d][1024] ----------------
__global__ __launch_bounds__(256) void vtan_tr(
    const bf16_t* __restrict__ qkvsb, bf16_t* __restrict__ VTt)
{
  __shared__ bf16_t tile[64 * 72];    // [d][n'local], pad 72 (16B-aligned rows)
  int z = blockIdx.y, b = z >> 3, h = z & 7;
  int n0 = blockIdx.x * 64;
  int t = threadIdx.x;
  int r = t >> 2;                     // n' local 0..63
  int c4 = t & 3;                     // 16-col chunk
  const bf16_t* vb = qkvsb + ((long)(b * 1024 + n0 + r) * 1536 + 1024 + h * 64 + c4 * 16);
  bf16x8 v0 = *(const bf16x8*)vb;
  bf16x8 v1 = *(const bf16x8*)(vb + 8);
  float ss = 0.f;
  #pragma unroll
  for (int e = 0; e < 8; e++) {
    float f0 = (float)v0[e], f1 = (float)v1[e];
    ss = fmaf(f0, f0, fmaf(f1, f1, ss));
  }
  ss += __shfl_xor(ss, 1, 64);
  ss += __shfl_xor(ss, 2, 64);        // all 4 lanes of the row now hold v2
  float vT = sqrtf(1.f + ss);
  float sn0 = sqrtf(ss);
  float coef = __logf(vT + sn0) * frcp(fmaxf(sn0, 1e-8f));
  #pragma unroll
  for (int e = 0; e < 8; e++) {
    tile[(c4 * 16 + e) * 72 + r]     = (bf16_t)(coef * (float)v0[e]);
    tile[(c4 * 16 + 8 + e) * 72 + r] = (bf16_t)(coef * (float)v1[e]);
  }
  __syncthreads();
  int d = t >> 2, cc = (t & 3) * 16;
  bf16x8 o0 = *(const bf16x8*)&tile[d * 72 + cc];
  bf16x8 o1 = *(const bf16x8*)&tile[d * 72 + cc + 8];
  bf16_t* dst = VTt + (long)z * 64 * 1024 + (long)d * 1024 + n0 + cc;
  *(bf16x8*)dst = o0;
  *(bf16x8*)(dst + 8) = o1;
}

// ---------------- fused attention: QK^T + score + exp + PV + normalize ----------------
// block: 32 q-rows x one (b,h); 256 threads (4 waves); 16 kv-tiles of 64
__global__ __launch_bounds__(256) void attn_fused(
    const bf16_t* __restrict__ qkvsb,   // [2048][1536]
    const bf16_t* __restrict__ VTt,     // [16][64][1024]
    const float* __restrict__ qt, const float* __restrict__ kt,
    const float* __restrict__ Bi,
    float* __restrict__ mt,             // [16][1024][64]
    const float* __restrict__ lam_p, const float* __restrict__ tau_p,
    const float* __restrict__ temp_p)
{
  __shared__ bf16_t Ks[64 * 64];        // 8 KB (also Q staging temp)
  __shared__ bf16_t Vs[64 * 64];        // 8 KB  [d][n']
  __shared__ bf16_t Ps[32 * 72];        // 4.5 KB padded
  __shared__ float ot[32 * 65];         // 8.1 KB output repack
  __shared__ float sh_qt[32], sh_Bc[32], sh_kt[64], rs[32];

  const int t = threadIdx.x;
  const int w = t >> 6;
  const int lane = t & 63;
  const int lm = lane & 15, lh = lane >> 4;
  const int z = blockIdx.y, b = z >> 3, h = z & 7;
  const int n0 = blockIdx.x * 32;

  float lam = softplus_fast(lam_p[0]);
  float tau = softplus_fast(tau_p[0]);
  float invT = frcp(temp_p[0]);
  float A1 = -lam * invT, A2 = -tau * invT;
  float A2h = 0.5f * A2, K0 = A2 * 0.048750465f;

  if (t < 32) {
    sh_qt[t] = qt[z * 1024 + n0 + t];
    sh_Bc[t] = Bi[z * 1024 + n0 + t] - 0.1f;
    rs[t] = 0.f;
  }

  // stage Q (32 x 64) into Ks temp, then preload frags to registers
  const bf16_t* qbase = qkvsb + ((long)(b * 1024 + n0) * 1536 + h * 64);
  gl_lds16((const char*)(qbase + (long)(w * 8 + (lane >> 3)) * 1536) + (lane & 7) * 16,
           (char*)Ks + w * 1024);
  __syncthreads();
  bf16x8 qf[2][2];
  #pragma unroll
  for (int i = 0; i < 2; i++)
    #pragma unroll
    for (int kk = 0; kk < 2; kk++)
      qf[i][kk] = *(const bf16x8*)&Ks[(i * 16 + lm) * 64 + kk * 32 + lh * 8];

  f32x4 oacc[2] = {};
  float racc[2][4] = {};

  const bf16_t* kbase = qkvsb + ((long)b * 1024 * 1536 + 512 + h * 64);
  const bf16_t* vbase = VTt + (long)z * 64 * 1024;

  for (int kv = 0; kv < 16; kv++) {
    __syncthreads();                    // prior-iter LDS reads done (incl. Q frags)
    {
      int r8 = lane >> 3, b16 = (lane & 7) * 16;
      const bf16_t* kb = kbase + (long)(kv * 64) * 1536;
      gl_lds16((const char*)(kb + (long)(w * 16 + r8) * 1536) + b16,     (char*)Ks + (w * 2) * 1024);
      gl_lds16((const char*)(kb + (long)(w * 16 + 8 + r8) * 1536) + b16, (char*)Ks + (w * 2 + 1) * 1024);
      const bf16_t* vb = vbase + kv * 64;
      gl_lds16((const char*)(vb + (long)(w * 16 + r8) * 1024) + b16,     (char*)Vs + (w * 2) * 1024);
      gl_lds16((const char*)(vb + (long)(w * 16 + 8 + r8) * 1024) + b16, (char*)Vs + (w * 2 + 1) * 1024);
    }
    if (t < 64) sh_kt[t] = kt[z * 1024 + kv * 64 + t];
    __syncthreads();

    // score MFMA: rows 32, this wave's cols [w*16, w*16+16)
    f32x4 sacc[2] = {};
    bf16x8 kf0 = *(const bf16x8*)&Ks[(w * 16 + lm) * 64 + lh * 8];
    bf16x8 kf1 = *(const bf16x8*)&Ks[(w * 16 + lm) * 64 + 32 + lh * 8];
    sacc[0] = MFMA16(qf[0][0], kf0, sacc[0]);
    sacc[0] = MFMA16(qf[0][1], kf1, sacc[0]);
    sacc[1] = MFMA16(qf[1][0], kf0, sacc[1]);
    sacc[1] = MFMA16(qf[1][1], kf1, sacc[1]);

    // score epilogue -> Ps + register rowsums
    float ktv = sh_kt[w * 16 + lm];
    #pragma unroll
    for (int i = 0; i < 2; i++) {
      #pragma unroll
      for (int q = 0; q < 4; q++) {
        int r = i * 16 + lh * 4 + q;
        float qtv = sh_qt[r], Bc = sh_Bc[r];
        float nOQ = fmaf(qtv, qtv, -1.f);
        float inner = fmaf(-qtv, ktv, sacc[i][q]);
        float nQK = fmaxf(fmaf(inner, inner, -1.f), 0.f);
        float ri = __builtin_amdgcn_rsqf(fmaf(nQK, nOQ, 2.5e-5f));
        float zr = fmaf(inner, qtv, ktv) * ri;
        float Zc = fminf(fmaxf(-zr, -1.f), 1.f);
        float xx = fmaxf(-inner, 1.001f);
        float u = fmaf(__log2f(xx), 0.01732868f, 0.01732868f);   // acosh/40 ~ ln(2x)/40
        float p = fminf(u * u, 0.09f);
        float H = p * fmaf(p, -6.584f, 3.5556f);
        float a = Zc + Bc;
        float a2 = a * a;
        float lc = a2 * fmaf(a2, fmaf(a2, 0.00034722f, -0.0052083f), 0.125f);
        float lgt = fmaf(A1, H, fmaf(A2, lc, fmaf(A2h, a, K0)));
        float e = __expf(lgt);
        Ps[r * 72 + w * 16 + lm] = (bf16_t)e;
        racc[i][q] += e;
      }
    }
    __syncthreads();                    // Ps complete

    // PV: O^T[d][n] += V^T tile @ P tile  (contraction over n')
    bf16x8 va0 = *(const bf16x8*)&Vs[(w * 16 + lm) * 64 + lh * 8];
    bf16x8 va1 = *(const bf16x8*)&Vs[(w * 16 + lm) * 64 + 32 + lh * 8];
    bf16x8 pb00 = *(const bf16x8*)&Ps[lm * 72 + lh * 8];
    bf16x8 pb01 = *(const bf16x8*)&Ps[lm * 72 + 32 + lh * 8];
    bf16x8 pb10 = *(const bf16x8*)&Ps[(16 + lm) * 72 + lh * 8];
    bf16x8 pb11 = *(const bf16x8*)&Ps[(16 + lm) * 72 + 32 + lh * 8];
    oacc[0] = MFMA16(va0, pb00, oacc[0]);
    oacc[0] = MFMA16(va1, pb01, oacc[0]);
    oacc[1] = MFMA16(va0, pb10, oacc[1]);
    oacc[1] = MFMA16(va1, pb11, oacc[1]);
  }

  // reduce rowsums: over 16 cols in-wave, then across waves via LDS atomics
  #pragma unroll
  for (int i = 0; i < 2; i++)
    #pragma unroll
    for (int q = 0; q < 4; q++) {
      float v = racc[i][q];
      v += __shfl_xor(v, 1, 64);
      v += __shfl_xor(v, 2, 64);
      v += __shfl_xor(v, 4, 64);
      v += __shfl_xor(v, 8, 64);
      if (lm == 0) atomicAdd(&rs[i * 16 + lh * 4 + q], v);
    }

  // write O^T acc -> ot[n][d] (f32, pad 65)
  #pragma unroll
  for (int j = 0; j < 2; j++)
    #pragma unroll
    for (int q = 0; q < 4; q++)
      ot[(j * 16 + lm) * 65 + w * 16 + lh * 4 + q] = oacc[j][q];
  __syncthreads();

  // normalize + coalesced write: mt[z][n0+r][0..63]
  int r = t >> 3, c0 = (t & 7) * 8;
  float inv = frcp(rs[r] * (1.f + 1e-8f));
  float* dst = mt + ((long)z * 1024 + n0 + r) * 64 + c0;
  float4 o0, o1;
  o0.x = ot[r * 65 + c0 + 0] * inv; o0.y = ot[r * 65 + c0 + 1] * inv;
  o0.z = ot[r * 65 + c0 + 2] * inv; o0.w = ot[r * 65 + c0 + 3] * inv;
  o1.x = ot[r * 65 + c0 + 4] * inv; o1.y = ot[r * 65 + c0 + 5] * inv;
  o1.z = ot[r * 65 + c0 + 6] * inv; o1.w = ot[r * 65 + c0 + 7] * inv;
  *(float4*)dst = o0;
  *(float4*)(dst + 4) = o1;
}

// ---------------- merge heads: spatial at 0..511, time at 512 ----------------
__global__ __launch_bounds__(512) void merge_heads(
    const float* __restrict__ mt, bf16_t* __restrict__ attn)
{
  __shared__ float t2s[8];
  int row = blockIdx.x;
  int b = row >> 10, n = row & 1023;
  int h = threadIdx.x >> 6, d = threadIdx.x & 63;
  int z = b * 8 + h;
  float v = mt[((long)z * 1024 + n) * 64 + d];
  float s2 = waveReduceSum(v * v);
  float nn = fmaxf(sqrtf(s2), 1e-8f);
  float e = __expf(nn), ei = frcp(e);
  float coef = 0.5f * (e - ei) * frcp(nn);
  attn[(long)row * 544 + h * 64 + d] = (bf16_t)(coef * v);
  if (d == 0) {
    float th = 0.5f * (e + ei);
    t2s[h] = th * th;
  }
  __syncthreads();
  if (threadIdx.x == 0) {
    float t2 = t2s[0] + t2s[1] + t2s[2] + t2s[3] + t2s[4] + t2s[5] + t2s[6] + t2s[7] - 7.f;
    attn[(long)row * 544 + 512] = (bf16_t)sqrtf(fmaxf(t2, 1e-8f));
  }
  if (threadIdx.x < 31) attn[(long)row * 544 + 513 + threadIdx.x] = (bf16_t)0.f;
}

// ============ bf16-output GEMM with LDS repack (BM=128, BN=64, 4 waves) ============
// ACTF: 0 = GELU | 2 = plain bf16
template<int ACTF>
DEV void gemm_rep_body(
    const bf16_t* __restrict__ Ag, int lda,
    const bf16_t* __restrict__ Bg, int ldb,
    bf16_t* __restrict__ Cg, int ldc,
    int K)
{
  __shared__ char smem[16384];          // k-loop: As 8K | Bs 4K ; epilogue: rep 16K
  bf16_t* As = (bf16_t*)smem;           // [128][32]
  bf16_t* Bs = (bf16_t*)(smem + 8192);  // [64][32]
  const int t = threadIdx.x;
  const int wid = t >> 6, lane = t & 63;
  const int lm = lane & 15, lh = lane >> 4;
  const int bm = blockIdx.x * 128;
  const int bn = blockIdx.y * 64;
  const int wm = (wid >> 1) * 64;
  const int wn = (wid & 1) * 32;
  f32x4 acc[4][2] = {};

  for (int kk = 0; kk < K; kk += 32) {
    __syncthreads();
    #pragma unroll
    for (int r = 0; r < 2; r++) {
      int chunk = r * 4 + wid;
      const char* src = (const char*)(Ag + (long)(bm + chunk * 16 + (lane >> 2)) * lda + kk)
                        + (lane & 3) * 16;
      gl_lds16(src, smem + chunk * 1024);
    }
    {
      const char* src = (const char*)(Bg + (long)(bn + wid * 16 + (lane >> 2)) * ldb + kk)
                        + (lane & 3) * 16;
      gl_lds16(src, smem + 8192 + wid * 1024);
    }
    __syncthreads();
    bf16x8 af[4], bfr[2];
    #pragma unroll
    for (int i = 0; i < 4; i++) af[i] = *(const bf16x8*)&As[(wm + i * 16 + lm) * 32 + lh * 8];
    #pragma unroll
    for (int j = 0; j < 2; j++) bfr[j] = *(const bf16x8*)&Bs[(wn + j * 16 + lm) * 32 + lh * 8];
    #pragma unroll
    for (int i = 0; i < 4; i++)
      #pragma unroll
      for (int j = 0; j < 2; j++)
        acc[i][j] = MFMA16(af[i], bfr[j], acc[i][j]);
  }

  __syncthreads();                       // As/Bs dead; reuse as rep[128][64]
  bf16_t* rep = (bf16_t*)smem;
  #pragma unroll
  for (int i = 0; i < 4; i++) {
    #pragma unroll
    for (int q = 0; q < 4; q++) {
      int r = wm + i * 16 + lh * 4 + q;
      #pragma unroll
      for (int j = 0; j < 2; j++) {
        float v = acc[i][j][q];
        rep[r * 64 + wn + j * 16 + lm] = (bf16_t)(ACTF == 0 ? gelu_fast(v) : v);
      }
    }
  }
  __syncthreads();

  #pragma unroll
  for (int rd = 0; rd < 4; rd++) {
    int off = rd * 4096 + t * 16;
    int lr = off >> 7;
    int lc = (off & 127) >> 1;
    bf16x8 vv = *(const bf16x8*)(smem + off);
    *(bf16x8*)(Cg + (long)(bm + lr) * ldc + bn + lc) = vv;
  }
}

// ---------------- generic MFMA GEMM (fp32 out) ----------------
template<int BM, int BN, int WM, int WN>
DEV void gemm_body(
    const bf16_t* __restrict__ Ag, int lda,
    const bf16_t* __restrict__ Bg, int ldb,
    float* __restrict__ Cg, int ldc,
    int K)
{
  constexpr int MI = WM / 16, NJ = WN / 16;
  constexpr int NWN = BN / WN;
  __shared__ bf16_t As[BM][32];
  __shared__ bf16_t Bs[BN][32];
  const int t = threadIdx.x;
  const int wid = t >> 6, lane = t & 63;
  const int lm = lane & 15, lh = lane >> 4;
  const int bm = blockIdx.x * BM;
  const int bn = blockIdx.y * BN;
  const int wm = (wid / NWN) * WM;
  const int wn = (wid % NWN) * WN;
  f32x4 acc[MI][NJ] = {};

  for (int kk = 0; kk < K; kk += 32) {
    __syncthreads();
    #pragma unroll
    for (int r = 0; r < BM / 64; r++) {
      int chunk = r * 4 + wid;
      const char* src = (const char*)(Ag + (long)(bm + chunk * 16 + (lane >> 2)) * lda + kk)
                        + (lane & 3) * 16;
      gl_lds16(src, (char*)&As[0][0] + chunk * 1024);
    }
    #pragma unroll
    for (int r = 0; r < BN / 64; r++) {
      int chunk = r * 4 + wid;
      const char* src = (const char*)(Bg + (long)(bn + chunk * 16 + (lane >> 2)) * ldb + kk)
                        + (lane & 3) * 16;
      gl_lds16(src, (char*)&Bs[0][0] + chunk * 1024);
    }
    __syncthreads();
    bf16x8 af[MI], bfr[NJ];
    #pragma unroll
    for (int i = 0; i < MI; i++) af[i] = *(const bf16x8*)&As[wm + i * 16 + lm][lh * 8];
    #pragma unroll
    for (int j = 0; j < NJ; j++) bfr[j] = *(const bf16x8*)&Bs[wn + j * 16 + lm][lh * 8];
    #pragma unroll
    for (int i = 0; i < MI; i++)
      #pragma unroll
      for (int j = 0; j < NJ; j++)
        acc[i][j] = MFMA16(af[i], bfr[j], acc[i][j]);
  }

  #pragma unroll
  for (int i = 0; i < MI; i++) {
    #pragma unroll
    for (int q = 0; q < 4; q++) {
      long row = bm + wm + i * 16 + lh * 4 + q;
      #pragma unroll
      for (int j = 0; j < NJ; j++)
        Cg[row * ldc + bn + wn + j * 16 + lm] = acc[i][j][q];
    }
  }
}

// ---- named wrappers ----
__global__ __launch_bounds__(256) void gemm_qkv(const bf16_t* A, int lda, const bf16_t* B, int ldb,
                                                bf16_t* C, int ldc, int K){
  gemm_rep_body<2>(A, lda, B, ldb, C, ldc, K);
}
__global__ __launch_bounds__(256) void gemm_f1(const bf16_t* A, int lda, const bf16_t* B, int ldb,
                                               bf16_t* C, int ldc, int K){
  gemm_rep_body<0>(A, lda, B, ldb, C, ldc, K);
}
__global__ __launch_bounds__(256) void gemm_wo(const bf16_t* A, int lda, const bf16_t* B, int ldb,
                                               float* C, int ldc, int K){
  gemm_body<64, 64, 32, 32>(A, lda, B, ldb, C, ldc, K);
}
__global__ __launch_bounds__(256) void gemm_f2(const bf16_t* A, int lda, const bf16_t* B, int ldb,
                                               float* C, int ldc, int K){
  gemm_body<64, 64, 32, 32>(A, lda, B, ldb, C, ldc, K);
}

extern "C" void kernel_launch(void* const* d_in, const int* in_sizes, int n_in,
                              void* d_out, int out_size, void* d_ws, size_t ws_size,
                              hipStream_t stream) {
  const float* x    = (const float*)d_in[0];
  const float* Wq   = (const float*)d_in[1];
  const float* Wk   = (const float*)d_in[2];
  const float* Wv   = (const float*)d_in[3];
  const float* Wo   = (const float*)d_in[4];
  const float* W1   = (const float*)d_in[5];
  const float* W2   = (const float*)d_in[6];
  const float* g1   = (const float*)d_in[7];
  const float* b1   = (const float*)d_in[8];
  const float* g2   = (const float*)d_in[9];
  const float* b2   = (const float*)d_in[10];
  const float* temp = (const float*)d_in[11];
  const float* beta = (const float*)d_in[12];
  const float* tau  = (const float*)d_in[13];
  const float* lam  = (const float*)d_in[14];

  char* W = (char*)d_ws;
  bf16_t* Wqkvb = (bf16_t*)(W + 0);          // [1536][544]
  bf16_t* Wob   = (bf16_t*)(W + 1671168);    // [512][544]
  bf16_t* W1b   = (bf16_t*)(W + 2228224);    // [2048][544]
  bf16_t* W2b   = (bf16_t*)(W + 4456448);    // [512][2080]
  bf16_t* y1b   = (bf16_t*)(W + 6586368);    // [2048][544]
  bf16_t* qkvsb = (bf16_t*)(W + 8814592);    // [2048][1536] bf16
  float*  mt    = (float*) (W + 15106048);   // [16][1024][64] fp32
  float*  tmp   = (float*) (W + 19300352);   // [2048][512] fp32
  float*  outs  = (float*) (W + 23494656);   // [2048][512] fp32
  bf16_t* VTt   = (bf16_t*)(W + 27688960);   // [16][64][1024]
  float*  qt    = (float*) (W + 29786112);
  float*  kt    = (float*) (W + 29851648);
  float*  Bi    = (float*) (W + 29917184);
  bf16_t* y2b   = (bf16_t*)(W + 29982720);   // [2048][544]
  bf16_t* hb    = (bf16_t*)(W + 32210944);   // [2048][2080]  (end 40.7 MB)
  bf16_t* attnb = y1b;                       // alias (y1b dead after QKV GEMM)

  // 0. weight conversions
  conv_all<<<12864, 256, 0, stream>>>(Wq, Wk, Wv, Wo, W1, W2, Wqkvb, Wob, W1b, W2b);

  // 1. LN1 -> bf16
  ln_fwd<<<2048, 256, 0, stream>>>(x, g1, b1, y1b);

  // 2. fused QKV projection -> bf16
  gemm_qkv<<<dim3(16,24,1),256,0,stream>>>(y1b, 544, Wqkvb, 544, qkvsb, 1536, 544);

  // 3. per-row stats (qt, kt, Bi)
  qk_stats<<<2048, 512, 0, stream>>>(qkvsb, qt, kt, Bi, beta);

  // 4. v_tan + transpose -> VTt
  vtan_tr<<<dim3(16,16,1),256,0,stream>>>(qkvsb, VTt);

  // 5. fused attention -> mt
  attn_fused<<<dim3(32,16,1),256,0,stream>>>(qkvsb, VTt, qt, kt, Bi, mt, lam, tau, temp);

  // 6. expmap0 + merge heads -> attnb
  merge_heads<<<2048, 512, 0, stream>>>(mt, attnb);

  // 7. Wo projection -> fp32 tmp
  gemm_wo<<<dim3(32,8,1),256,0,stream>>>(attnb, 544, Wob, 544, tmp, 512, 544);

  // 8. residual + LN2
  res_ln<<<2048, 256, 0, stream>>>(tmp, x, g2, b2, outs, y2b);

  // 9. FFN up + GELU -> bf16 hb cols 0..2047
  gemm_f1<<<dim3(16,32,1),256,0,stream>>>(y2b, 544, W1b, 544, hb, 2080, 544);

  // 10. time coordinate for h (col 2048)
  addtime_row<<<2048, 256, 0, stream>>>(hb);

  // 11. FFN down -> fp32 tmp
  gemm_f2<<<dim3(32,8,1),256,0,stream>>>(hb, 2080, W2b, 2080, tmp, 512, 2080);

  // 12. final residual + add_time -> d_out
  final_k<<<2048, 256, 0, stream>>>(tmp, outs, (float*)d_out);
}

// Round 8
// 124.495 us; speedup vs baseline: 25.0032x; 1.1848x over previous
//
#include <hip/hip_runtime.h>
#include <math.h>

#define DEV static __device__ __forceinline__

typedef __bf16 bf16_t;
typedef __bf16 bf16x8 __attribute__((ext_vector_type(8)));
typedef float f32x4 __attribute__((ext_vector_type(4)));

#define MFMA16(a,b,c) __builtin_amdgcn_mfma_f32_16x16x32_bf16(a,b,c,0,0,0)

// ---------- fast transcendentals ----------
DEV float frcp(float x){ return __builtin_amdgcn_rcpf(x); }
DEV float softplus_fast(float x){
  return fmaxf(x, 0.f) + __logf(1.f + __expf(-fabsf(x)));
}
DEV float tanh_fast(float z){
  float e2 = __expf(2.f * z);
  return (e2 - 1.f) * frcp(e2 + 1.f);
}
DEV float gelu_fast(float v){
  float u = 0.7978845608028654f * fmaf(0.044715f * v, v * v, v);
  u = fminf(fmaxf(u, -15.f), 15.f);
  return 0.5f * v * (1.f + tanh_fast(u));
}

DEV void gl_lds16(const void* g, void* l) {
  __builtin_amdgcn_global_load_lds((const __attribute__((address_space(1))) void*)g,
                                   (__attribute__((address_space(3))) void*)l, 16, 0, 0);
}

DEV float waveReduceSum(float v){
  #pragma unroll
  for (int o = 32; o > 0; o >>= 1) v += __shfl_xor(v, o, 64);
  return v;
}
DEV float blockReduceSum(float v, float* sh){
  v = waveReduceSum(v);
  int w = threadIdx.x >> 6;
  int nw = blockDim.x >> 6;
  __syncthreads();
  if ((threadIdx.x & 63) == 0) sh[w] = v;
  __syncthreads();
  float r = sh[0];
  for (int i = 1; i < nw; i++) r += sh[i];
  return r;
}

// ---------------- weight conversions (time moved to LAST k-slot) ----------------
__global__ __launch_bounds__(256) void conv_all(
    const float* __restrict__ Wq, const float* __restrict__ Wk,
    const float* __restrict__ Wv, const float* __restrict__ Wo,
    const float* __restrict__ W1, const float* __restrict__ W2,
    bf16_t* __restrict__ Wqkvb, bf16_t* __restrict__ Wob,
    bf16_t* __restrict__ W1b, bf16_t* __restrict__ W2b)
{
  long i = (long)blockIdx.x * 256 + threadIdx.x;
  if (i < 1114112) {                       // Wq|Wk|Wv|Wo : [512][513] -> [512][544]
    int w = (int)(i / (512 * 544));
    long rem = i - (long)w * (512 * 544);
    long r = rem / 544;
    int c = (int)(rem - r * 544);
    const float* src = (w == 0) ? Wq : (w == 1) ? Wk : (w == 2) ? Wv : Wo;
    float v = (c < 512) ? src[r * 513 + c + 1] : (c == 512 ? src[r * 513] : 0.f);
    if (w < 3) Wqkvb[(long)w * 512 * 544 + rem] = (bf16_t)v;
    else       Wob[rem] = (bf16_t)v;
  } else if (i < 2228224) {                // W1 : [2048][513] -> [2048][544]
    long j = i - 1114112;
    long r = j / 544;
    int c = (int)(j - r * 544);
    W1b[j] = (c < 512) ? (bf16_t)W1[r * 513 + c + 1]
           : (c == 512 ? (bf16_t)W1[r * 513] : (bf16_t)0.f);
  } else if (i < 3293184) {                // W2 : [512][2049] -> [512][2080]
    long j = i - 2228224;
    long r = j / 2080;
    int c = (int)(j - r * 2080);
    W2b[j] = (c < 2048) ? (bf16_t)W2[r * 2049 + c + 1]
           : (c == 2048 ? (bf16_t)W2[r * 2049] : (bf16_t)0.f);
  }
}

// ---------------- LN1 ----------------
__global__ __launch_bounds__(256) void ln_fwd(
    const float* __restrict__ xin,
    const float* __restrict__ g, const float* __restrict__ b,
    bf16_t* __restrict__ y)
{
  __shared__ float sh[8];
  int row = blockIdx.x;
  const float* xr = xin + (long)row * 513 + 1;
  int t = threadIdx.x;
  float a0 = xr[t], a1 = xr[t + 256];
  float s  = blockReduceSum(a0 + a1, sh);
  float s2 = blockReduceSum(a0 * a0 + a1 * a1, sh);
  float mu = s * (1.f / 512.f);
  float var = s2 * (1.f / 512.f) - mu * mu;
  float inv = rsqrtf(var + 1e-5f);
  float y0 = (a0 - mu) * inv * g[t] + b[t];
  float y1v = (a1 - mu) * inv * g[t + 256] + b[t + 256];
  float q = blockReduceSum(y0 * y0 + y1v * y1v, sh);
  bf16_t* yr = y + (long)row * 544;
  yr[t] = (bf16_t)y0;
  yr[t + 256] = (bf16_t)y1v;
  if (t == 0) yr[512] = (bf16_t)sqrtf(q + 1.f);
  if (t < 31) yr[513 + t] = (bf16_t)0.f;
}

// ---------------- residual (2 K-split partials) + LN2 ----------------
__global__ __launch_bounds__(256) void res_ln(
    const float* __restrict__ woA, const float* __restrict__ woB,
    const float* __restrict__ xin,
    const float* __restrict__ g, const float* __restrict__ b,
    float* __restrict__ outs,
    bf16_t* __restrict__ y)
{
  __shared__ float sh[8];
  int row = blockIdx.x;
  int t = threadIdx.x;
  long i0 = (long)row * 512 + t, i1 = i0 + 256;
  float a0 = woA[i0] + woB[i0] + xin[(long)row * 513 + 1 + t];
  float a1 = woA[i1] + woB[i1] + xin[(long)row * 513 + 1 + t + 256];
  outs[i0] = a0;
  outs[i1] = a1;
  float s  = blockReduceSum(a0 + a1, sh);
  float s2 = blockReduceSum(a0 * a0 + a1 * a1, sh);
  float mu = s * (1.f / 512.f);
  float var = s2 * (1.f / 512.f) - mu * mu;
  float inv = rsqrtf(var + 1e-5f);
  float y0 = (a0 - mu) * inv * g[t] + b[t];
  float y1v = (a1 - mu) * inv * g[t + 256] + b[t + 256];
  float q = blockReduceSum(y0 * y0 + y1v * y1v, sh);
  bf16_t* yr = y + (long)row * 544;
  yr[t] = (bf16_t)y0;
  yr[t + 256] = (bf16_t)y1v;
  if (t == 0) yr[512] = (bf16_t)sqrtf(q + 1.f);
  if (t < 31) yr[513 + t] = (bf16_t)0.f;
}

// ---------------- add_time over bf16 h [2048][2080] ----------------
__global__ __launch_bounds__(256) void addtime_row(bf16_t* __restrict__ h)
{
  __shared__ float sh[8];
  int row = blockIdx.x;
  bf16_t* hr = h + (long)row * 2080;
  int t = threadIdx.x;
  float s2 = 0.f;
  bf16x8 v = *(const bf16x8*)&hr[t * 8];
  #pragma unroll
  for (int j = 0; j < 8; j++) {
    float f = (float)v[j];
    s2 = fmaf(f, f, s2);
  }
  s2 = blockReduceSum(s2, sh);
  if (t == 0) hr[2048] = (bf16_t)sqrtf(s2 + 1.f);
  if (t < 31) hr[2049 + t] = (bf16_t)0.f;
}

// ---------------- final residual (2 partials) + add_time -> d_out [t, s] ----------------
__global__ __launch_bounds__(256) void final_k(
    const float* __restrict__ h2A, const float* __restrict__ h2B,
    const float* __restrict__ outs,
    float* __restrict__ out)
{
  __shared__ float sh[8];
  int row = blockIdx.x;
  int t = threadIdx.x;
  long i0 = (long)row * 512 + t, i1 = i0 + 256;
  float o0 = h2A[i0] + h2B[i0] + outs[i0];
  float o1 = h2A[i1] + h2B[i1] + outs[i1];
  float q = blockReduceSum(o0 * o0 + o1 * o1, sh);
  float* yr = out + (long)row * 513;
  yr[1 + t] = o0;
  yr[1 + t + 256] = o1;
  if (t == 0) yr[0] = sqrtf(q + 1.f);
}

// ---------------- qkv_prep: per-row stats + v_tan + transpose (fused) ----------------
// grid (16 n-tiles of 64, 16 z); 256 threads: r=t>>2 row, c4=t&3 16-elem chunk
__global__ __launch_bounds__(256) void qkv_prep(
    const bf16_t* __restrict__ qkvsb,   // [2048][1536]
    float* __restrict__ qt, float* __restrict__ kt, float* __restrict__ Bi,
    bf16_t* __restrict__ VTt,           // [16][64][1024]
    const float* __restrict__ beta_p)
{
  __shared__ bf16_t tile[64 * 72];
  int z = blockIdx.y, b = z >> 3, h = z & 7;
  int n0 = blockIdx.x * 64;
  int t = threadIdx.x;
  int r = t >> 2, c4 = t & 3;
  long rowbase = (long)(b * 1024 + n0 + r) * 1536 + h * 64 + c4 * 16;
  bf16x8 q0 = *(const bf16x8*)(qkvsb + rowbase);
  bf16x8 q1 = *(const bf16x8*)(qkvsb + rowbase + 8);
  bf16x8 k0 = *(const bf16x8*)(qkvsb + rowbase + 512);
  bf16x8 k1 = *(const bf16x8*)(qkvsb + rowbase + 520);
  bf16x8 v0 = *(const bf16x8*)(qkvsb + rowbase + 1024);
  bf16x8 v1 = *(const bf16x8*)(qkvsb + rowbase + 1032);
  float q2 = 0.f, k2 = 0.f, vv2 = 0.f;
  #pragma unroll
  for (int e = 0; e < 8; e++) {
    float a0 = (float)q0[e], a1 = (float)q1[e];
    float b0 = (float)k0[e], b1 = (float)k1[e];
    float c0 = (float)v0[e], c1 = (float)v1[e];
    q2 = fmaf(a0, a0, fmaf(a1, a1, q2));
    k2 = fmaf(b0, b0, fmaf(b1, b1, k2));
    vv2 = fmaf(c0, c0, fmaf(c1, c1, vv2));
  }
  q2 += __shfl_xor(q2, 1, 64); q2 += __shfl_xor(q2, 2, 64);
  k2 += __shfl_xor(k2, 1, 64); k2 += __shfl_xor(k2, 2, 64);
  vv2 += __shfl_xor(vv2, 1, 64); vv2 += __shfl_xor(vv2, 2, 64);
  float vT = sqrtf(1.f + vv2);
  float sn0 = sqrtf(vv2);
  float coef = __logf(vT + sn0) * frcp(fmaxf(sn0, 1e-8f));
  if (c4 == 0) {
    int ob = z * 1024 + n0 + r;
    float qT = sqrtf(1.f + q2);
    qt[ob] = qT;
    kt[ob] = sqrtf(1.f + k2);
    float beta = softplus_fast(beta_p[0]);
    float xq = fmaxf(qT, 1.001f);
    float sh_ = sqrtf(fmaxf(xq * xq - 1.f, 0.f));
    float rr = beta * frcp(sh_);
    Bi[ob] = sqrtf(fmaxf(1.f - rr * rr, 0.f) + 1e-8f);
  }
  #pragma unroll
  for (int e = 0; e < 8; e++) {
    tile[(c4 * 16 + e) * 72 + r]     = (bf16_t)(coef * (float)v0[e]);
    tile[(c4 * 16 + 8 + e) * 72 + r] = (bf16_t)(coef * (float)v1[e]);
  }
  __syncthreads();
  int d = t >> 2, cc = (t & 3) * 16;
  bf16x8 o0 = *(const bf16x8*)&tile[d * 72 + cc];
  bf16x8 o1 = *(const bf16x8*)&tile[d * 72 + cc + 8];
  bf16_t* dst = VTt + (long)z * 64 * 1024 + (long)d * 1024 + n0 + cc;
  *(bf16x8*)dst = o0;
  *(bf16x8*)(dst + 8) = o1;
}

// ---------------- fused attention + expmap merge ----------------
// block: 32 q-rows x one (b,h); 256 threads (4 waves); 16 kv-tiles of 64
__global__ __launch_bounds__(256) void attn_fused(
    const bf16_t* __restrict__ qkvsb,   // [2048][1536]
    const bf16_t* __restrict__ VTt,     // [16][64][1024]
    const float* __restrict__ qt, const float* __restrict__ kt,
    const float* __restrict__ Bi,
    bf16_t* __restrict__ attnb,         // [2048][544] (spatial slice for this head)
    float* __restrict__ ch2,            // [2048][8] cosh^2 per head
    const float* __restrict__ lam_p, const float* __restrict__ tau_p,
    const float* __restrict__ temp_p)
{
  __shared__ bf16_t Ks[64 * 64];        // 8 KB (also Q staging temp)
  __shared__ bf16_t Vs[64 * 64];        // 8 KB  [d][n']
  __shared__ bf16_t Ps[32 * 72];        // 4.5 KB padded
  __shared__ float ot[32 * 65];         // 8.1 KB output repack
  __shared__ float sh_qt[32], sh_Bc[32], sh_kt[64], rs[32];

  const int t = threadIdx.x;
  const int w = t >> 6;
  const int lane = t & 63;
  const int lm = lane & 15, lh = lane >> 4;
  const int z = blockIdx.y, b = z >> 3, h = z & 7;
  const int n0 = blockIdx.x * 32;

  float lam = softplus_fast(lam_p[0]);
  float tau = softplus_fast(tau_p[0]);
  float invT = frcp(temp_p[0]);
  float A1 = -lam * invT, A2 = -tau * invT;
  float A2h = 0.5f * A2, K0 = A2 * 0.048750465f;

  if (t < 32) {
    sh_qt[t] = qt[z * 1024 + n0 + t];
    sh_Bc[t] = Bi[z * 1024 + n0 + t] - 0.1f;
    rs[t] = 0.f;
  }

  // stage Q (32 x 64) into Ks temp, then preload frags to registers
  const bf16_t* qbase = qkvsb + ((long)(b * 1024 + n0) * 1536 + h * 64);
  gl_lds16((const char*)(qbase + (long)(w * 8 + (lane >> 3)) * 1536) + (lane & 7) * 16,
           (char*)Ks + w * 1024);
  __syncthreads();
  bf16x8 qf[2][2];
  #pragma unroll
  for (int i = 0; i < 2; i++)
    #pragma unroll
    for (int kk = 0; kk < 2; kk++)
      qf[i][kk] = *(const bf16x8*)&Ks[(i * 16 + lm) * 64 + kk * 32 + lh * 8];

  f32x4 oacc[2] = {};
  float racc[2][4] = {};

  const bf16_t* kbase = qkvsb + ((long)b * 1024 * 1536 + 512 + h * 64);
  const bf16_t* vbase = VTt + (long)z * 64 * 1024;

  for (int kv = 0; kv < 16; kv++) {
    __syncthreads();                    // prior-iter LDS reads done (incl. Q frags)
    {
      int r8 = lane >> 3, b16 = (lane & 7) * 16;
      const bf16_t* kb = kbase + (long)(kv * 64) * 1536;
      gl_lds16((const char*)(kb + (long)(w * 16 + r8) * 1536) + b16,     (char*)Ks + (w * 2) * 1024);
      gl_lds16((const char*)(kb + (long)(w * 16 + 8 + r8) * 1536) + b16, (char*)Ks + (w * 2 + 1) * 1024);
      const bf16_t* vb = vbase + kv * 64;
      gl_lds16((const char*)(vb + (long)(w * 16 + r8) * 1024) + b16,     (char*)Vs + (w * 2) * 1024);
      gl_lds16((const char*)(vb + (long)(w * 16 + 8 + r8) * 1024) + b16, (char*)Vs + (w * 2 + 1) * 1024);
    }
    if (t < 64) sh_kt[t] = kt[z * 1024 + kv * 64 + t];
    __syncthreads();

    // score MFMA: rows 32, this wave's cols [w*16, w*16+16)
    f32x4 sacc[2] = {};
    bf16x8 kf0 = *(const bf16x8*)&Ks[(w * 16 + lm) * 64 + lh * 8];
    bf16x8 kf1 = *(const bf16x8*)&Ks[(w * 16 + lm) * 64 + 32 + lh * 8];
    sacc[0] = MFMA16(qf[0][0], kf0, sacc[0]);
    sacc[0] = MFMA16(qf[0][1], kf1, sacc[0]);
    sacc[1] = MFMA16(qf[1][0], kf0, sacc[1]);
    sacc[1] = MFMA16(qf[1][1], kf1, sacc[1]);

    // score epilogue -> Ps + register rowsums
    float ktv = sh_kt[w * 16 + lm];
    #pragma unroll
    for (int i = 0; i < 2; i++) {
      #pragma unroll
      for (int q = 0; q < 4; q++) {
        int r = i * 16 + lh * 4 + q;
        float qtv = sh_qt[r], Bc = sh_Bc[r];
        float nOQ = fmaf(qtv, qtv, -1.f);
        float inner = fmaf(-qtv, ktv, sacc[i][q]);
        float nQK = fmaxf(fmaf(inner, inner, -1.f), 0.f);
        float ri = __builtin_amdgcn_rsqf(fmaf(nQK, nOQ, 2.5e-5f));
        float zr = fmaf(inner, qtv, ktv) * ri;
        float Zc = fminf(fmaxf(-zr, -1.f), 1.f);
        float xx = fmaxf(-inner, 1.001f);
        float u = fmaf(__log2f(xx), 0.01732868f, 0.01732868f);   // acosh/40 ~ ln(2x)/40
        float p = fminf(u * u, 0.09f);
        float H = p * fmaf(p, -6.584f, 3.5556f);
        float a = Zc + Bc;
        float a2 = a * a;
        float lc = a2 * fmaf(a2, fmaf(a2, 0.00034722f, -0.0052083f), 0.125f);
        float lgt = fmaf(A1, H, fmaf(A2, lc, fmaf(A2h, a, K0)));
        float e = __expf(lgt);
        Ps[r * 72 + w * 16 + lm] = (bf16_t)e;
        racc[i][q] += e;
      }
    }
    __syncthreads();                    // Ps complete

    // PV: O^T[d][n] += V^T tile @ P tile  (contraction over n')
    bf16x8 va0 = *(const bf16x8*)&Vs[(w * 16 + lm) * 64 + lh * 8];
    bf16x8 va1 = *(const bf16x8*)&Vs[(w * 16 + lm) * 64 + 32 + lh * 8];
    bf16x8 pb00 = *(const bf16x8*)&Ps[lm * 72 + lh * 8];
    bf16x8 pb01 = *(const bf16x8*)&Ps[lm * 72 + 32 + lh * 8];
    bf16x8 pb10 = *(const bf16x8*)&Ps[(16 + lm) * 72 + lh * 8];
    bf16x8 pb11 = *(const bf16x8*)&Ps[(16 + lm) * 72 + 32 + lh * 8];
    oacc[0] = MFMA16(va0, pb00, oacc[0]);
    oacc[0] = MFMA16(va1, pb01, oacc[0]);
    oacc[1] = MFMA16(va0, pb10, oacc[1]);
    oacc[1] = MFMA16(va1, pb11, oacc[1]);
  }

  // reduce rowsums: over 16 cols in-wave, then across waves via LDS atomics
  #pragma unroll
  for (int i = 0; i < 2; i++)
    #pragma unroll
    for (int q = 0; q < 4; q++) {
      float v = racc[i][q];
      v += __shfl_xor(v, 1, 64);
      v += __shfl_xor(v, 2, 64);
      v += __shfl_xor(v, 4, 64);
      v += __shfl_xor(v, 8, 64);
      if (lm == 0) atomicAdd(&rs[i * 16 + lh * 4 + q], v);
    }

  // write O^T acc -> ot[n][d] (f32, pad 65)
  #pragma unroll
  for (int j = 0; j < 2; j++)
    #pragma unroll
    for (int q = 0; q < 4; q++)
      ot[(j * 16 + lm) * 65 + w * 16 + lh * 4 + q] = oacc[j][q];
  __syncthreads();

  // normalize + expmap0 + write bf16 spatial slice + cosh^2
  int r = t >> 3, c0 = (t & 7) * 8;
  float inv = frcp(rs[r] * (1.f + 1e-8f));
  float v[8];
  float ss = 0.f;
  #pragma unroll
  for (int e = 0; e < 8; e++) {
    v[e] = ot[r * 65 + c0 + e] * inv;
    ss = fmaf(v[e], v[e], ss);
  }
  ss += __shfl_xor(ss, 1, 64);
  ss += __shfl_xor(ss, 2, 64);
  ss += __shfl_xor(ss, 4, 64);
  float nn = fmaxf(sqrtf(ss), 1e-8f);
  float e_ = __expf(nn), ei = frcp(e_);
  float coef = 0.5f * (e_ - ei) * frcp(nn);     // sinh(nn)/nn
  bf16x8 ov;
  #pragma unroll
  for (int e = 0; e < 8; e++) ov[e] = (bf16_t)(coef * v[e]);
  *(bf16x8*)(attnb + (long)(b * 1024 + n0 + r) * 544 + h * 64 + c0) = ov;
  if (c0 == 0) {
    float ch = 0.5f * (e_ + ei);                // cosh(nn)
    ch2[(long)(b * 1024 + n0 + r) * 8 + h] = ch * ch;
  }
}

// ---------------- merge time: attnb[row][512] = sqrt(sum cosh^2 - 7); zero pad ----------------
__global__ __launch_bounds__(256) void merge_time(
    const float* __restrict__ ch2, bf16_t* __restrict__ attn)
{
  int row = blockIdx.x * 256 + threadIdx.x;
  const float* c = ch2 + (long)row * 8;
  float s = ((c[0] + c[1]) + (c[2] + c[3])) + ((c[4] + c[5]) + (c[6] + c[7]));
  bf16_t* ar = attn + (long)row * 544;
  ar[512] = (bf16_t)sqrtf(fmaxf(s - 7.f, 1e-8f));
  #pragma unroll
  for (int i = 0; i < 31; i++) ar[513 + i] = (bf16_t)0.f;
}

// ============ bf16-output GEMM with LDS repack (BM=128, BN=64, 4 waves) ============
// ACTF: 0 = GELU | 2 = plain bf16
template<int ACTF>
DEV void gemm_rep_body(
    const bf16_t* __restrict__ Ag, int lda,
    const bf16_t* __restrict__ Bg, int ldb,
    bf16_t* __restrict__ Cg, int ldc,
    int K)
{
  __shared__ char smem[16384];          // k-loop: As 8K | Bs 4K ; epilogue: rep 16K
  bf16_t* As = (bf16_t*)smem;           // [128][32]
  bf16_t* Bs = (bf16_t*)(smem + 8192);  // [64][32]
  const int t = threadIdx.x;
  const int wid = t >> 6, lane = t & 63;
  const int lm = lane & 15, lh = lane >> 4;
  const int bm = blockIdx.x * 128;
  const int bn = blockIdx.y * 64;
  const int wm = (wid >> 1) * 64;
  const int wn = (wid & 1) * 32;
  f32x4 acc[4][2] = {};

  for (int kk = 0; kk < K; kk += 32) {
    __syncthreads();
    #pragma unroll
    for (int r = 0; r < 2; r++) {
      int chunk = r * 4 + wid;
      const char* src = (const char*)(Ag + (long)(bm + chunk * 16 + (lane >> 2)) * lda + kk)
                        + (lane & 3) * 16;
      gl_lds16(src, smem + chunk * 1024);
    }
    {
      const char* src = (const char*)(Bg + (long)(bn + wid * 16 + (lane >> 2)) * ldb + kk)
                        + (lane & 3) * 16;
      gl_lds16(src, smem + 8192 + wid * 1024);
    }
    __syncthreads();
    bf16x8 af[4], bfr[2];
    #pragma unroll
    for (int i = 0; i < 4; i++) af[i] = *(const bf16x8*)&As[(wm + i * 16 + lm) * 32 + lh * 8];
    #pragma unroll
    for (int j = 0; j < 2; j++) bfr[j] = *(const bf16x8*)&Bs[(wn + j * 16 + lm) * 32 + lh * 8];
    #pragma unroll
    for (int i = 0; i < 4; i++)
      #pragma unroll
      for (int j = 0; j < 2; j++)
        acc[i][j] = MFMA16(af[i], bfr[j], acc[i][j]);
  }

  __syncthreads();                       // As/Bs dead; reuse as rep[128][64]
  bf16_t* rep = (bf16_t*)smem;
  #pragma unroll
  for (int i = 0; i < 4; i++) {
    #pragma unroll
    for (int q = 0; q < 4; q++) {
      int r = wm + i * 16 + lh * 4 + q;
      #pragma unroll
      for (int j = 0; j < 2; j++) {
        float v = acc[i][j][q];
        rep[r * 64 + wn + j * 16 + lm] = (bf16_t)(ACTF == 0 ? gelu_fast(v) : v);
      }
    }
  }
  __syncthreads();

  #pragma unroll
  for (int rd = 0; rd < 4; rd++) {
    int off = rd * 4096 + t * 16;
    int lr = off >> 7;
    int lc = (off & 127) >> 1;
    bf16x8 vv = *(const bf16x8*)(smem + off);
    *(bf16x8*)(Cg + (long)(bm + lr) * ldc + bn + lc) = vv;
  }
}

// ---------------- generic MFMA GEMM (fp32 out, K-range) ----------------
template<int BM, int BN, int WM, int WN>
DEV void gemm_body(
    const bf16_t* __restrict__ Ag, int lda,
    const bf16_t* __restrict__ Bg, int ldb,
    float* __restrict__ Cg, int ldc,
    int k0, int k1)
{
  constexpr int MI = WM / 16, NJ = WN / 16;
  constexpr int NWN = BN / WN;
  __shared__ bf16_t As[BM][32];
  __shared__ bf16_t Bs[BN][32];
  const int t = threadIdx.x;
  const int wid = t >> 6, lane = t & 63;
  const int lm = lane & 15, lh = lane >> 4;
  const int bm = blockIdx.x * BM;
  const int bn = blockIdx.y * BN;
  const int wm = (wid / NWN) * WM;
  const int wn = (wid % NWN) * WN;
  f32x4 acc[MI][NJ] = {};

  for (int kk = k0; kk < k1; kk += 32) {
    __syncthreads();
    #pragma unroll
    for (int r = 0; r < BM / 64; r++) {
      int chunk = r * 4 + wid;
      const char* src = (const char*)(Ag + (long)(bm + chunk * 16 + (lane >> 2)) * lda + kk)
                        + (lane & 3) * 16;
      gl_lds16(src, (char*)&As[0][0] + chunk * 1024);
    }
    #pragma unroll
    for (int r = 0; r < BN / 64; r++) {
      int chunk = r * 4 + wid;
      const char* src = (const char*)(Bg + (long)(bn + chunk * 16 + (lane >> 2)) * ldb + kk)
                        + (lane & 3) * 16;
      gl_lds16(src, (char*)&Bs[0][0] + chunk * 1024);
    }
    __syncthreads();
    bf16x8 af[MI], bfr[NJ];
    #pragma unroll
    for (int i = 0; i < MI; i++) af[i] = *(const bf16x8*)&As[wm + i * 16 + lm][lh * 8];
    #pragma unroll
    for (int j = 0; j < NJ; j++) bfr[j] = *(const bf16x8*)&Bs[wn + j * 16 + lm][lh * 8];
    #pragma unroll
    for (int i = 0; i < MI; i++)
      #pragma unroll
      for (int j = 0; j < NJ; j++)
        acc[i][j] = MFMA16(af[i], bfr[j], acc[i][j]);
  }

  #pragma unroll
  for (int i = 0; i < MI; i++) {
    #pragma unroll
    for (int q = 0; q < 4; q++) {
      long row = bm + wm + i * 16 + lh * 4 + q;
      #pragma unroll
      for (int j = 0; j < NJ; j++)
        Cg[row * ldc + bn + wn + j * 16 + lm] = acc[i][j][q];
    }
  }
}

// ---- named wrappers ----
__global__ __launch_bounds__(256) void gemm_qkv(const bf16_t* A, int lda, const bf16_t* B, int ldb,
                                                bf16_t* C, int ldc, int K){
  gemm_rep_body<2>(A, lda, B, ldb, C, ldc, K);
}
__global__ __launch_bounds__(256) void gemm_f1(const bf16_t* A, int lda, const bf16_t* B, int ldb,
                                               bf16_t* C, int ldc, int K){
  gemm_rep_body<0>(A, lda, B, ldb, C, ldc, K);
}
// K-split variants: blockIdx.z selects K-chunk; partial C goes to C + z*2048*ldc
__global__ __launch_bounds__(256) void gemm_wo(const bf16_t* A, int lda, const bf16_t* B, int ldb,
                                               float* C, int ldc, int K, int kcut){
  int k0 = blockIdx.z ? kcut : 0;
  int k1 = blockIdx.z ? K : kcut;
  gemm_body<64, 64, 32, 32>(A, lda, B, ldb, C + (long)blockIdx.z * 2048 * ldc, ldc, k0, k1);
}
__global__ __launch_bounds__(256) void gemm_f2(const bf16_t* A, int lda, const bf16_t* B, int ldb,
                                               float* C, int ldc, int K, int kcut){
  int k0 = blockIdx.z ? kcut : 0;
  int k1 = blockIdx.z ? K : kcut;
  gemm_body<64, 64, 32, 32>(A, lda, B, ldb, C + (long)blockIdx.z * 2048 * ldc, ldc, k0, k1);
}

extern "C" void kernel_launch(void* const* d_in, const int* in_sizes, int n_in,
                              void* d_out, int out_size, void* d_ws, size_t ws_size,
                              hipStream_t stream) {
  const float* x    = (const float*)d_in[0];
  const float* Wq   = (const float*)d_in[1];
  const float* Wk   = (const float*)d_in[2];
  const float* Wv   = (const float*)d_in[3];
  const float* Wo   = (const float*)d_in[4];
  const float* W1   = (const float*)d_in[5];
  const float* W2   = (const float*)d_in[6];
  const float* g1   = (const float*)d_in[7];
  const float* b1   = (const float*)d_in[8];
  const float* g2   = (const float*)d_in[9];
  const float* b2   = (const float*)d_in[10];
  const float* temp = (const float*)d_in[11];
  const float* beta = (const float*)d_in[12];
  const float* tau  = (const float*)d_in[13];
  const float* lam  = (const float*)d_in[14];

  char* W = (char*)d_ws;
  bf16_t* Wqkvb = (bf16_t*)(W + 0);          // [1536][544]
  bf16_t* Wob   = (bf16_t*)(W + 1671168);    // [512][544]
  bf16_t* W1b   = (bf16_t*)(W + 2228224);    // [2048][544]
  bf16_t* W2b   = (bf16_t*)(W + 4456448);    // [512][2080]
  bf16_t* y1b   = (bf16_t*)(W + 6586368);    // [2048][544]
  bf16_t* qkvsb = (bf16_t*)(W + 8814592);    // [2048][1536] bf16
  float*  tmpA  = (float*) (W + 15106048);   // [2048][512] fp32 (K-split partial 0)
  float*  tmpB  = (float*) (W + 19300352);   // [2048][512] fp32 (K-split partial 1)
  float*  outs  = (float*) (W + 23494656);   // [2048][512] fp32
  bf16_t* VTt   = (bf16_t*)(W + 27688960);   // [16][64][1024]
  float*  qt    = (float*) (W + 29786112);
  float*  kt    = (float*) (W + 29851648);
  float*  Bi    = (float*) (W + 29917184);
  float*  ch2   = (float*) (W + 29982720);   // [2048][8] fp32
  bf16_t* y2b   = (bf16_t*)(W + 30048256);   // [2048][544]
  bf16_t* hb    = (bf16_t*)(W + 32276480);   // [2048][2080]  (end 40.8 MB)
  bf16_t* attnb = y1b;                       // alias (y1b dead after QKV GEMM)

  // 0. weight conversions
  conv_all<<<12864, 256, 0, stream>>>(Wq, Wk, Wv, Wo, W1, W2, Wqkvb, Wob, W1b, W2b);

  // 1. LN1 -> bf16
  ln_fwd<<<2048, 256, 0, stream>>>(x, g1, b1, y1b);

  // 2. fused QKV projection -> bf16
  gemm_qkv<<<dim3(16,24,1),256,0,stream>>>(y1b, 544, Wqkvb, 544, qkvsb, 1536, 544);

  // 3. per-row stats + v_tan + transpose (fused)
  qkv_prep<<<dim3(16,16,1),256,0,stream>>>(qkvsb, qt, kt, Bi, VTt, beta);

  // 4. fused attention + expmap merge -> attnb spatial + ch2
  attn_fused<<<dim3(32,16,1),256,0,stream>>>(qkvsb, VTt, qt, kt, Bi, attnb, ch2, lam, tau, temp);

  // 5. time column + pad for attnb
  merge_time<<<8, 256, 0, stream>>>(ch2, attnb);

  // 6. Wo projection (K-split x2) -> fp32 tmpA/tmpB
  gemm_wo<<<dim3(32,8,2),256,0,stream>>>(attnb, 544, Wob, 544, tmpA, 512, 544, 288);

  // 7. residual + LN2
  res_ln<<<2048, 256, 0, stream>>>(tmpA, tmpB, x, g2, b2, outs, y2b);

  // 8. FFN up + GELU -> bf16 hb cols 0..2047
  gemm_f1<<<dim3(16,32,1),256,0,stream>>>(y2b, 544, W1b, 544, hb, 2080, 544);

  // 9. time coordinate for h (col 2048)
  addtime_row<<<2048, 256, 0, stream>>>(hb);

  // 10. FFN down (K-split x2) -> fp32 tmpA/tmpB
  gemm_f2<<<dim3(32,8,2),256,0,stream>>>(hb, 2080, W2b, 2080, tmpA, 512, 2080, 1056);

  // 11. final residual + add_time -> d_out
  final_k<<<2048, 256, 0, stream>>>(tmpA, tmpB, outs, (float*)d_out);
}

// Round 9
// 101.955 us; speedup vs baseline: 30.5308x; 1.2211x over previous
//
#include <hip/hip_runtime.h>
#include <math.h>

#define DEV static __device__ __forceinline__

typedef __bf16 bf16_t;
typedef __bf16 bf16x8 __attribute__((ext_vector_type(8)));
typedef float f32x4 __attribute__((ext_vector_type(4)));

#define MFMA16(a,b,c) __builtin_amdgcn_mfma_f32_16x16x32_bf16(a,b,c,0,0,0)

// ---------- fast transcendentals ----------
DEV float frcp(float x){ return __builtin_amdgcn_rcpf(x); }
DEV float softplus_fast(float x){
  return fmaxf(x, 0.f) + __logf(1.f + __expf(-fabsf(x)));
}
DEV float tanh_fast(float z){
  float e2 = __expf(2.f * z);
  return (e2 - 1.f) * frcp(e2 + 1.f);
}
DEV float gelu_fast(float v){
  float u = 0.7978845608028654f * fmaf(0.044715f * v, v * v, v);
  u = fminf(fmaxf(u, -15.f), 15.f);
  return 0.5f * v * (1.f + tanh_fast(u));
}

DEV void gl_lds16(const void* g, void* l) {
  __builtin_amdgcn_global_load_lds((const __attribute__((address_space(1))) void*)g,
                                   (__attribute__((address_space(3))) void*)l, 16, 0, 0);
}

DEV float waveReduceSum(float v){
  #pragma unroll
  for (int o = 32; o > 0; o >>= 1) v += __shfl_xor(v, o, 64);
  return v;
}
DEV float blockReduceSum(float v, float* sh){
  v = waveReduceSum(v);
  int w = threadIdx.x >> 6;
  int nw = blockDim.x >> 6;
  __syncthreads();
  if ((threadIdx.x & 63) == 0) sh[w] = v;
  __syncthreads();
  float r = sh[0];
  for (int i = 1; i < nw; i++) r += sh[i];
  return r;
}

// ---------------- weight conversions: spatial [N][512|2048] bf16 + col0 fp32 ----------------
__global__ __launch_bounds__(256) void conv_all(
    const float* __restrict__ Wq, const float* __restrict__ Wk,
    const float* __restrict__ Wv, const float* __restrict__ Wo,
    const float* __restrict__ W1, const float* __restrict__ W2,
    bf16_t* __restrict__ Wqkvb, bf16_t* __restrict__ Wob,
    bf16_t* __restrict__ W1b, bf16_t* __restrict__ W2b,
    float* __restrict__ wqkv0, float* __restrict__ wo0,
    float* __restrict__ w10, float* __restrict__ w20)
{
  long i = (long)blockIdx.x * 256 + threadIdx.x;
  if (i < 786432) {                       // Wqkv spatial [1536][512]
    long r = i >> 9; int c = (int)(i & 511);
    const float* src = (r < 512) ? Wq + r * 513 : (r < 1024) ? Wk + (r - 512) * 513 : Wv + (r - 1024) * 513;
    Wqkvb[i] = (bf16_t)src[c + 1];
  } else if (i < 1048576) {               // Wo spatial [512][512]
    long j = i - 786432;
    long r = j >> 9; int c = (int)(j & 511);
    Wob[j] = (bf16_t)Wo[r * 513 + c + 1];
  } else if (i < 2097152) {               // W1 spatial [2048][512]
    long j = i - 1048576;
    long r = j >> 9; int c = (int)(j & 511);
    W1b[j] = (bf16_t)W1[r * 513 + c + 1];
  } else if (i < 3145728) {               // W2 spatial [512][2048]
    long j = i - 2097152;
    long r = j >> 11; int c = (int)(j & 2047);
    W2b[j] = (bf16_t)W2[r * 2049 + c + 1];
  } else if (i < 3150336) {               // time columns (fp32)
    int j = (int)(i - 3145728);
    if (j < 1536) {
      wqkv0[j] = (j < 512) ? Wq[(long)j * 513] : (j < 1024) ? Wk[(long)(j - 512) * 513] : Wv[(long)(j - 1024) * 513];
    } else if (j < 2048) wo0[j - 1536] = Wo[(long)(j - 1536) * 513];
    else if (j < 4096)  w10[j - 2048] = W1[(long)(j - 2048) * 513];
    else                w20[j - 4096] = W2[(long)(j - 4096) * 2049];
  }
}

// ---------------- LN1: y1b [2048][512] + ty1 ----------------
__global__ __launch_bounds__(256) void ln_fwd(
    const float* __restrict__ xin,
    const float* __restrict__ g, const float* __restrict__ b,
    bf16_t* __restrict__ y, float* __restrict__ ty)
{
  __shared__ float sh[8];
  int row = blockIdx.x;
  const float* xr = xin + (long)row * 513 + 1;
  int t = threadIdx.x;
  float a0 = xr[t], a1 = xr[t + 256];
  float s  = blockReduceSum(a0 + a1, sh);
  float s2 = blockReduceSum(a0 * a0 + a1 * a1, sh);
  float mu = s * (1.f / 512.f);
  float var = s2 * (1.f / 512.f) - mu * mu;
  float inv = rsqrtf(var + 1e-5f);
  float y0 = (a0 - mu) * inv * g[t] + b[t];
  float y1v = (a1 - mu) * inv * g[t + 256] + b[t + 256];
  float q = blockReduceSum(y0 * y0 + y1v * y1v, sh);
  bf16_t* yr = y + (long)row * 512;
  yr[t] = (bf16_t)y0;
  yr[t + 256] = (bf16_t)y1v;
  if (t == 0) ty[row] = sqrtf(q + 1.f);
}

// ---------------- residual + rank-1(Wo time) + LN2 -> outs, y2b, ty2 ----------------
__global__ __launch_bounds__(256) void res_ln(
    const float* __restrict__ woA, const float* __restrict__ woB,
    const float* __restrict__ ch2, const float* __restrict__ wo0,
    const float* __restrict__ xin,
    const float* __restrict__ g, const float* __restrict__ b,
    float* __restrict__ outs,
    bf16_t* __restrict__ y, float* __restrict__ ty)
{
  __shared__ float sh[8];
  int row = blockIdx.x;
  int t = threadIdx.x;
  const float* c = ch2 + (long)row * 8;
  float cs = ((c[0] + c[1]) + (c[2] + c[3])) + ((c[4] + c[5]) + (c[6] + c[7]));
  float tattn = sqrtf(fmaxf(cs - 7.f, 1e-8f));
  long i0 = (long)row * 512 + t, i1 = i0 + 256;
  float a0 = woA[i0] + woB[i0] + tattn * wo0[t]       + xin[(long)row * 513 + 1 + t];
  float a1 = woA[i1] + woB[i1] + tattn * wo0[t + 256] + xin[(long)row * 513 + 1 + t + 256];
  outs[i0] = a0;
  outs[i1] = a1;
  float s  = blockReduceSum(a0 + a1, sh);
  float s2 = blockReduceSum(a0 * a0 + a1 * a1, sh);
  float mu = s * (1.f / 512.f);
  float var = s2 * (1.f / 512.f) - mu * mu;
  float inv = rsqrtf(var + 1e-5f);
  float y0 = (a0 - mu) * inv * g[t] + b[t];
  float y1v = (a1 - mu) * inv * g[t + 256] + b[t + 256];
  float q = blockReduceSum(y0 * y0 + y1v * y1v, sh);
  bf16_t* yr = y + (long)row * 512;
  yr[t] = (bf16_t)y0;
  yr[t + 256] = (bf16_t)y1v;
  if (t == 0) ty[row] = sqrtf(q + 1.f);
}

// ---------------- final: h-norm + residual + rank-1(W2 time) + add_time -> d_out ----------------
__global__ __launch_bounds__(256) void final_k(
    const float* __restrict__ h2A, const float* __restrict__ h2B,
    const bf16_t* __restrict__ hb, const float* __restrict__ w20,
    const float* __restrict__ outs,
    float* __restrict__ out)
{
  __shared__ float sh[8];
  int row = blockIdx.x;
  int t = threadIdx.x;
  // th = sqrt(1 + ||h_row||^2)
  bf16x8 hv = *(const bf16x8*)&hb[(long)row * 2048 + t * 8];
  float ss = 0.f;
  #pragma unroll
  for (int j = 0; j < 8; j++) { float f = (float)hv[j]; ss = fmaf(f, f, ss); }
  float th = sqrtf(blockReduceSum(ss, sh) + 1.f);
  long i0 = (long)row * 512 + t, i1 = i0 + 256;
  float o0 = h2A[i0] + h2B[i0] + th * w20[t]       + outs[i0];
  float o1 = h2A[i1] + h2B[i1] + th * w20[t + 256] + outs[i1];
  float q = blockReduceSum(o0 * o0 + o1 * o1, sh);
  float* yr = out + (long)row * 513;
  yr[1 + t] = o0;
  yr[1 + t + 256] = o1;
  if (t == 0) yr[0] = sqrtf(q + 1.f);
}

// ---------------- qkv_prep: per-row stats + v_tan + transpose ----------------
__global__ __launch_bounds__(256) void qkv_prep(
    const bf16_t* __restrict__ qkvsb,   // [2048][1536]
    float* __restrict__ qt, float* __restrict__ kt, float* __restrict__ Bi,
    bf16_t* __restrict__ VTt,           // [16][64][1024]
    const float* __restrict__ beta_p)
{
  __shared__ bf16_t tile[64 * 72];
  int z = blockIdx.y, b = z >> 3, h = z & 7;
  int n0 = blockIdx.x * 64;
  int t = threadIdx.x;
  int r = t >> 2, c4 = t & 3;
  long rowbase = (long)(b * 1024 + n0 + r) * 1536 + h * 64 + c4 * 16;
  bf16x8 q0 = *(const bf16x8*)(qkvsb + rowbase);
  bf16x8 q1 = *(const bf16x8*)(qkvsb + rowbase + 8);
  bf16x8 k0 = *(const bf16x8*)(qkvsb + rowbase + 512);
  bf16x8 k1 = *(const bf16x8*)(qkvsb + rowbase + 520);
  bf16x8 v0 = *(const bf16x8*)(qkvsb + rowbase + 1024);
  bf16x8 v1 = *(const bf16x8*)(qkvsb + rowbase + 1032);
  float q2 = 0.f, k2 = 0.f, vv2 = 0.f;
  #pragma unroll
  for (int e = 0; e < 8; e++) {
    float a0 = (float)q0[e], a1 = (float)q1[e];
    float b0 = (float)k0[e], b1 = (float)k1[e];
    float c0 = (float)v0[e], c1 = (float)v1[e];
    q2 = fmaf(a0, a0, fmaf(a1, a1, q2));
    k2 = fmaf(b0, b0, fmaf(b1, b1, k2));
    vv2 = fmaf(c0, c0, fmaf(c1, c1, vv2));
  }
  q2 += __shfl_xor(q2, 1, 64); q2 += __shfl_xor(q2, 2, 64);
  k2 += __shfl_xor(k2, 1, 64); k2 += __shfl_xor(k2, 2, 64);
  vv2 += __shfl_xor(vv2, 1, 64); vv2 += __shfl_xor(vv2, 2, 64);
  float vT = sqrtf(1.f + vv2);
  float sn0 = sqrtf(vv2);
  float coef = __logf(vT + sn0) * frcp(fmaxf(sn0, 1e-8f));
  if (c4 == 0) {
    int ob = z * 1024 + n0 + r;
    float qT = sqrtf(1.f + q2);
    qt[ob] = qT;
    kt[ob] = sqrtf(1.f + k2);
    float beta = softplus_fast(beta_p[0]);
    float xq = fmaxf(qT, 1.001f);
    float sh_ = sqrtf(fmaxf(xq * xq - 1.f, 0.f));
    float rr = beta * frcp(sh_);
    Bi[ob] = sqrtf(fmaxf(1.f - rr * rr, 0.f) + 1e-8f);
  }
  #pragma unroll
  for (int e = 0; e < 8; e++) {
    tile[(c4 * 16 + e) * 72 + r]     = (bf16_t)(coef * (float)v0[e]);
    tile[(c4 * 16 + 8 + e) * 72 + r] = (bf16_t)(coef * (float)v1[e]);
  }
  __syncthreads();
  int d = t >> 2, cc = (t & 3) * 16;
  bf16x8 o0 = *(const bf16x8*)&tile[d * 72 + cc];
  bf16x8 o1 = *(const bf16x8*)&tile[d * 72 + cc + 8];
  bf16_t* dst = VTt + (long)z * 64 * 1024 + (long)d * 1024 + n0 + cc;
  *(bf16x8*)dst = o0;
  *(bf16x8*)(dst + 8) = o1;
}

// ---------------- fused attention + expmap merge (XOR-swizzled LDS) ----------------
__global__ __launch_bounds__(256) void attn_fused(
    const bf16_t* __restrict__ qkvsb,   // [2048][1536]
    const bf16_t* __restrict__ VTt,     // [16][64][1024]
    const float* __restrict__ qt, const float* __restrict__ kt,
    const float* __restrict__ Bi,
    bf16_t* __restrict__ attnb,         // [2048][512]
    float* __restrict__ ch2,            // [2048][8]
    const float* __restrict__ lam_p, const float* __restrict__ tau_p,
    const float* __restrict__ temp_p)
{
  __shared__ bf16_t Ks[64 * 64];
  __shared__ bf16_t Vs[64 * 64];
  __shared__ bf16_t Ps[32 * 72];
  __shared__ float ot[32 * 65];
  __shared__ float sh_qt[32], sh_Bc[32], sh_kt[64], rs[32];

  const int t = threadIdx.x;
  const int w = t >> 6;
  const int lane = t & 63;
  const int lm = lane & 15, lh = lane >> 4;
  const int z = blockIdx.y, b = z >> 3, h = z & 7;
  const int n0 = blockIdx.x * 32;
  const int sb = (((lane & 7) ^ (lane >> 3)) << 4);  // swizzled source byte offset
  const int r8 = lane >> 3;

  float lam = softplus_fast(lam_p[0]);
  float tau = softplus_fast(tau_p[0]);
  float invT = frcp(temp_p[0]);
  float A1 = -lam * invT, A2 = -tau * invT;
  float A2h = 0.5f * A2, K0 = A2 * 0.048750465f;

  if (t < 32) {
    sh_qt[t] = qt[z * 1024 + n0 + t];
    sh_Bc[t] = Bi[z * 1024 + n0 + t] - 0.1f;
    rs[t] = 0.f;
  }

  // stage Q (32x64, swizzled) then preload frags
  const bf16_t* qbase = qkvsb + ((long)(b * 1024 + n0) * 1536 + h * 64);
  gl_lds16((const char*)(qbase + (long)(w * 8 + r8) * 1536) + sb, (char*)Ks + w * 1024);
  __syncthreads();
  bf16x8 qf[2][2];
  #pragma unroll
  for (int i = 0; i < 2; i++)
    #pragma unroll
    for (int kk = 0; kk < 2; kk++)
      qf[i][kk] = *(const bf16x8*)&Ks[(i * 16 + lm) * 64 + (((kk * 4 + lh) ^ (lm & 7)) << 3)];

  f32x4 oacc[2] = {};
  float racc[2][4] = {};

  const bf16_t* kbase = qkvsb + ((long)b * 1024 * 1536 + 512 + h * 64);
  const bf16_t* vbase = VTt + (long)z * 64 * 1024;
  const int sl0 = ((lh) ^ (lm & 7)) << 3;        // k-slice 0 swizzled elem offset
  const int sl1 = ((4 + lh) ^ (lm & 7)) << 3;    // k-slice 1

  for (int kv = 0; kv < 16; kv++) {
    __syncthreads();
    {
      const bf16_t* kb = kbase + (long)(kv * 64) * 1536;
      gl_lds16((const char*)(kb + (long)(w * 16 + r8) * 1536) + sb,     (char*)Ks + (w * 2) * 1024);
      gl_lds16((const char*)(kb + (long)(w * 16 + 8 + r8) * 1536) + sb, (char*)Ks + (w * 2 + 1) * 1024);
      const bf16_t* vb = vbase + kv * 64;
      gl_lds16((const char*)(vb + (long)(w * 16 + r8) * 1024) + sb,     (char*)Vs + (w * 2) * 1024);
      gl_lds16((const char*)(vb + (long)(w * 16 + 8 + r8) * 1024) + sb, (char*)Vs + (w * 2 + 1) * 1024);
    }
    if (t < 64) sh_kt[t] = kt[z * 1024 + kv * 64 + t];
    __syncthreads();

    f32x4 sacc[2] = {};
    bf16x8 kf0 = *(const bf16x8*)&Ks[(w * 16 + lm) * 64 + sl0];
    bf16x8 kf1 = *(const bf16x8*)&Ks[(w * 16 + lm) * 64 + sl1];
    sacc[0] = MFMA16(qf[0][0], kf0, sacc[0]);
    sacc[0] = MFMA16(qf[0][1], kf1, sacc[0]);
    sacc[1] = MFMA16(qf[1][0], kf0, sacc[1]);
    sacc[1] = MFMA16(qf[1][1], kf1, sacc[1]);

    float ktv = sh_kt[w * 16 + lm];
    #pragma unroll
    for (int i = 0; i < 2; i++) {
      #pragma unroll
      for (int q = 0; q < 4; q++) {
        int r = i * 16 + lh * 4 + q;
        float qtv = sh_qt[r], Bc = sh_Bc[r];
        float nOQ = fmaf(qtv, qtv, -1.f);
        float inner = fmaf(-qtv, ktv, sacc[i][q]);
        float nQK = fmaxf(fmaf(inner, inner, -1.f), 0.f);
        float ri = __builtin_amdgcn_rsqf(fmaf(nQK, nOQ, 2.5e-5f));
        float zr = fmaf(inner, qtv, ktv) * ri;
        float Zc = fminf(fmaxf(-zr, -1.f), 1.f);
        float xx = fmaxf(-inner, 1.001f);
        float u = fmaf(__log2f(xx), 0.01732868f, 0.01732868f);
        float p = fminf(u * u, 0.09f);
        float H = p * fmaf(p, -6.584f, 3.5556f);
        float a = Zc + Bc;
        float a2 = a * a;
        float lc = a2 * fmaf(a2, fmaf(a2, 0.00034722f, -0.0052083f), 0.125f);
        float lgt = fmaf(A1, H, fmaf(A2, lc, fmaf(A2h, a, K0)));
        float e = __expf(lgt);
        Ps[r * 72 + w * 16 + lm] = (bf16_t)e;
        racc[i][q] += e;
      }
    }
    __syncthreads();

    bf16x8 va0 = *(const bf16x8*)&Vs[(w * 16 + lm) * 64 + sl0];
    bf16x8 va1 = *(const bf16x8*)&Vs[(w * 16 + lm) * 64 + sl1];
    bf16x8 pb00 = *(const bf16x8*)&Ps[lm * 72 + lh * 8];
    bf16x8 pb01 = *(const bf16x8*)&Ps[lm * 72 + 32 + lh * 8];
    bf16x8 pb10 = *(const bf16x8*)&Ps[(16 + lm) * 72 + lh * 8];
    bf16x8 pb11 = *(const bf16x8*)&Ps[(16 + lm) * 72 + 32 + lh * 8];
    oacc[0] = MFMA16(va0, pb00, oacc[0]);
    oacc[0] = MFMA16(va1, pb01, oacc[0]);
    oacc[1] = MFMA16(va0, pb10, oacc[1]);
    oacc[1] = MFMA16(va1, pb11, oacc[1]);
  }

  #pragma unroll
  for (int i = 0; i < 2; i++)
    #pragma unroll
    for (int q = 0; q < 4; q++) {
      float v = racc[i][q];
      v += __shfl_xor(v, 1, 64);
      v += __shfl_xor(v, 2, 64);
      v += __shfl_xor(v, 4, 64);
      v += __shfl_xor(v, 8, 64);
      if (lm == 0) atomicAdd(&rs[i * 16 + lh * 4 + q], v);
    }

  #pragma unroll
  for (int j = 0; j < 2; j++)
    #pragma unroll
    for (int q = 0; q < 4; q++)
      ot[(j * 16 + lm) * 65 + w * 16 + lh * 4 + q] = oacc[j][q];
  __syncthreads();

  int r = t >> 3, c0 = (t & 7) * 8;
  float inv = frcp(rs[r] * (1.f + 1e-8f));
  float v[8];
  float ss = 0.f;
  #pragma unroll
  for (int e = 0; e < 8; e++) {
    v[e] = ot[r * 65 + c0 + e] * inv;
    ss = fmaf(v[e], v[e], ss);
  }
  ss += __shfl_xor(ss, 1, 64);
  ss += __shfl_xor(ss, 2, 64);
  ss += __shfl_xor(ss, 4, 64);
  float nn = fmaxf(sqrtf(ss), 1e-8f);
  float e_ = __expf(nn), ei = frcp(e_);
  float coef = 0.5f * (e_ - ei) * frcp(nn);
  bf16x8 ov;
  #pragma unroll
  for (int e = 0; e < 8; e++) ov[e] = (bf16_t)(coef * v[e]);
  *(bf16x8*)(attnb + (long)(b * 1024 + n0 + r) * 512 + h * 64 + c0) = ov;
  if (c0 == 0) {
    float ch = 0.5f * (e_ + ei);
    ch2[(long)(b * 1024 + n0 + r) * 8 + h] = ch * ch;
  }
}

// ============ bf16-out GEMM, BK=64, swizzled, rank-1 epilogue (128x64, 4 waves) ============
// ACTF: 0 = GELU | 2 = plain
template<int ACTF>
DEV void gemm_rep_body(
    const bf16_t* __restrict__ Ag, int lda,
    const bf16_t* __restrict__ Bg, int ldb,
    bf16_t* __restrict__ Cg, int ldc, int K,
    const float* __restrict__ trow, const float* __restrict__ w0)
{
  __shared__ char smem[24576];          // As [128][64] 16K | Bs [64][64] 8K ; repack reuses 16K
  __shared__ float sh_t[128];
  bf16_t* As = (bf16_t*)smem;
  bf16_t* Bs = (bf16_t*)(smem + 16384);
  const int t = threadIdx.x;
  const int wid = t >> 6, lane = t & 63;
  const int lm = lane & 15, lh = lane >> 4;
  const int bm = blockIdx.x * 128;
  const int bn = blockIdx.y * 64;
  const int wm = (wid >> 1) * 64;
  const int wn = (wid & 1) * 32;
  const int sb = (((lane & 7) ^ (lane >> 3)) << 4);
  const int r8 = lane >> 3;
  f32x4 acc[4][2] = {};

  if (t < 128) sh_t[t] = trow[bm + t];
  float w0c[2] = { w0[bn + wn + lm], w0[bn + wn + 16 + lm] };

  for (int kk = 0; kk < K; kk += 64) {
    __syncthreads();
    #pragma unroll
    for (int r = 0; r < 4; r++) {
      int chunk = wid * 4 + r;
      gl_lds16((const char*)(Ag + (long)(bm + chunk * 8 + r8) * lda + kk) + sb,
               smem + chunk * 1024);
    }
    #pragma unroll
    for (int r = 0; r < 2; r++) {
      int chunk = wid * 2 + r;
      gl_lds16((const char*)(Bg + (long)(bn + chunk * 8 + r8) * ldb + kk) + sb,
               smem + 16384 + chunk * 1024);
    }
    __syncthreads();
    #pragma unroll
    for (int k2 = 0; k2 < 2; k2++) {
      const int sl = (((k2 * 4 + lh) ^ (lm & 7)) << 3);
      bf16x8 af[4], bfr[2];
      #pragma unroll
      for (int i = 0; i < 4; i++) af[i] = *(const bf16x8*)&As[(wm + i * 16 + lm) * 64 + sl];
      #pragma unroll
      for (int j = 0; j < 2; j++) bfr[j] = *(const bf16x8*)&Bs[(wn + j * 16 + lm) * 64 + sl];
      #pragma unroll
      for (int i = 0; i < 4; i++)
        #pragma unroll
        for (int j = 0; j < 2; j++)
          acc[i][j] = MFMA16(af[i], bfr[j], acc[i][j]);
    }
  }

  __syncthreads();
  bf16_t* rep = (bf16_t*)smem;
  #pragma unroll
  for (int i = 0; i < 4; i++) {
    #pragma unroll
    for (int q = 0; q < 4; q++) {
      int r = wm + i * 16 + lh * 4 + q;
      #pragma unroll
      for (int j = 0; j < 2; j++) {
        float v = acc[i][j][q] + sh_t[r] * w0c[j];
        rep[r * 64 + wn + j * 16 + lm] = (bf16_t)(ACTF == 0 ? gelu_fast(v) : v);
      }
    }
  }
  __syncthreads();

  #pragma unroll
  for (int rd = 0; rd < 4; rd++) {
    int off = rd * 4096 + t * 16;
    int lr = off >> 7;
    int lc = (off & 127) >> 1;
    bf16x8 vv = *(const bf16x8*)(smem + off);
    *(bf16x8*)(Cg + (long)(bm + lr) * ldc + bn + lc) = vv;
  }
}

// ---------------- fp32-out GEMM, BK=64, swizzled (64x64, 4 waves, K-range) ----------------
DEV void gemm_f32_body(
    const bf16_t* __restrict__ Ag, int lda,
    const bf16_t* __restrict__ Bg, int ldb,
    float* __restrict__ Cg, int ldc,
    int k0, int k1)
{
  __shared__ bf16_t As[64 * 64];
  __shared__ bf16_t Bs[64 * 64];
  const int t = threadIdx.x;
  const int wid = t >> 6, lane = t & 63;
  const int lm = lane & 15, lh = lane >> 4;
  const int bm = blockIdx.x * 64;
  const int bn = blockIdx.y * 64;
  const int wm = (wid >> 1) * 32;
  const int wn = (wid & 1) * 32;
  const int sb = (((lane & 7) ^ (lane >> 3)) << 4);
  const int r8 = lane >> 3;
  f32x4 acc[2][2] = {};

  for (int kk = k0; kk < k1; kk += 64) {
    __syncthreads();
    #pragma unroll
    for (int r = 0; r < 2; r++) {
      int chunk = wid * 2 + r;
      gl_lds16((const char*)(Ag + (long)(bm + chunk * 8 + r8) * lda + kk) + sb,
               (char*)As + chunk * 1024);
      gl_lds16((const char*)(Bg + (long)(bn + chunk * 8 + r8) * ldb + kk) + sb,
               (char*)Bs + chunk * 1024);
    }
    __syncthreads();
    #pragma unroll
    for (int k2 = 0; k2 < 2; k2++) {
      const int sl = (((k2 * 4 + lh) ^ (lm & 7)) << 3);
      bf16x8 af[2], bfr[2];
      #pragma unroll
      for (int i = 0; i < 2; i++) af[i] = *(const bf16x8*)&As[(wm + i * 16 + lm) * 64 + sl];
      #pragma unroll
      for (int j = 0; j < 2; j++) bfr[j] = *(const bf16x8*)&Bs[(wn + j * 16 + lm) * 64 + sl];
      #pragma unroll
      for (int i = 0; i < 2; i++)
        #pragma unroll
        for (int j = 0; j < 2; j++)
          acc[i][j] = MFMA16(af[i], bfr[j], acc[i][j]);
    }
  }

  #pragma unroll
  for (int i = 0; i < 2; i++) {
    #pragma unroll
    for (int q = 0; q < 4; q++) {
      long row = bm + wm + i * 16 + lh * 4 + q;
      #pragma unroll
      for (int j = 0; j < 2; j++)
        Cg[row * ldc + bn + wn + j * 16 + lm] = acc[i][j][q];
    }
  }
}

// ---- named wrappers ----
__global__ __launch_bounds__(256) void gemm_qkv(const bf16_t* A, int lda, const bf16_t* B, int ldb,
                                                bf16_t* C, int ldc, int K,
                                                const float* trow, const float* w0){
  gemm_rep_body<2>(A, lda, B, ldb, C, ldc, K, trow, w0);
}
__global__ __launch_bounds__(256) void gemm_f1(const bf16_t* A, int lda, const bf16_t* B, int ldb,
                                               bf16_t* C, int ldc, int K,
                                               const float* trow, const float* w0){
  gemm_rep_body<0>(A, lda, B, ldb, C, ldc, K, trow, w0);
}
__global__ __launch_bounds__(256) void gemm_wo(const bf16_t* A, int lda, const bf16_t* B, int ldb,
                                               float* C, int ldc, int K, int kcut){
  int k0 = blockIdx.z ? kcut : 0;
  int k1 = blockIdx.z ? K : kcut;
  gemm_f32_body(A, lda, B, ldb, C + (long)blockIdx.z * 2048 * ldc, ldc, k0, k1);
}
__global__ __launch_bounds__(256) void gemm_f2(const bf16_t* A, int lda, const bf16_t* B, int ldb,
                                               float* C, int ldc, int K, int kcut){
  int k0 = blockIdx.z ? kcut : 0;
  int k1 = blockIdx.z ? K : kcut;
  gemm_f32_body(A, lda, B, ldb, C + (long)blockIdx.z * 2048 * ldc, ldc, k0, k1);
}

extern "C" void kernel_launch(void* const* d_in, const int* in_sizes, int n_in,
                              void* d_out, int out_size, void* d_ws, size_t ws_size,
                              hipStream_t stream) {
  const float* x    = (const float*)d_in[0];
  const float* Wq   = (const float*)d_in[1];
  const float* Wk   = (const float*)d_in[2];
  const float* Wv   = (const float*)d_in[3];
  const float* Wo   = (const float*)d_in[4];
  const float* W1   = (const float*)d_in[5];
  const float* W2   = (const float*)d_in[6];
  const float* g1   = (const float*)d_in[7];
  const float* b1   = (const float*)d_in[8];
  const float* g2   = (const float*)d_in[9];
  const float* b2   = (const float*)d_in[10];
  const float* temp = (const float*)d_in[11];
  const float* beta = (const float*)d_in[12];
  const float* tau  = (const float*)d_in[13];
  const float* lam  = (const float*)d_in[14];

  char* W = (char*)d_ws;
  bf16_t* Wqkvb = (bf16_t*)(W + 0);          // [1536][512]
  bf16_t* Wob   = (bf16_t*)(W + 1572864);    // [512][512]
  bf16_t* W1b   = (bf16_t*)(W + 2097152);    // [2048][512]
  bf16_t* W2b   = (bf16_t*)(W + 4194304);    // [512][2048]
  float*  wqkv0 = (float*) (W + 6291456);    // [1536]
  float*  wo0   = (float*) (W + 6297600);    // [512]
  float*  w10   = (float*) (W + 6299648);    // [2048]
  float*  w20   = (float*) (W + 6307840);    // [512]
  bf16_t* y1b   = (bf16_t*)(W + 6309888);    // [2048][512]
  float*  ty1   = (float*) (W + 8407040);    // [2048]
  bf16_t* qkvsb = (bf16_t*)(W + 8415232);    // [2048][1536]
  float*  qt    = (float*) (W + 14706688);   // [16384]
  float*  kt    = (float*) (W + 14772224);
  float*  Bi    = (float*) (W + 14837760);
  bf16_t* VTt   = (bf16_t*)(W + 14903296);   // [16][64][1024]
  float*  ch2   = (float*) (W + 17000448);   // [2048][8]
  bf16_t* attnb = (bf16_t*)(W + 17065984);   // [2048][512]
  float*  tmpA  = (float*) (W + 19163136);   // [2048][512]
  float*  tmpB  = (float*) (W + 23357440);   // [2048][512]
  float*  outs  = (float*) (W + 27551744);   // [2048][512]
  bf16_t* y2b   = (bf16_t*)(W + 31746048);   // [2048][512]
  float*  ty2   = (float*) (W + 33843200);   // [2048]
  bf16_t* hb    = (bf16_t*)(W + 33851392);   // [2048][2048]  (end ~42.2 MB)

  // 0. weight conversions (spatial bf16 + time cols fp32)
  conv_all<<<12306, 256, 0, stream>>>(Wq, Wk, Wv, Wo, W1, W2,
                                      Wqkvb, Wob, W1b, W2b, wqkv0, wo0, w10, w20);

  // 1. LN1 -> y1b + ty1
  ln_fwd<<<2048, 256, 0, stream>>>(x, g1, b1, y1b, ty1);

  // 2. QKV projection (K=512) + rank-1 time -> qkvsb
  gemm_qkv<<<dim3(16,24,1),256,0,stream>>>(y1b, 512, Wqkvb, 512, qkvsb, 1536, 512, ty1, wqkv0);

  // 3. per-row stats + v_tan + transpose
  qkv_prep<<<dim3(16,16,1),256,0,stream>>>(qkvsb, qt, kt, Bi, VTt, beta);

  // 4. fused attention + expmap merge -> attnb + ch2
  attn_fused<<<dim3(32,16,1),256,0,stream>>>(qkvsb, VTt, qt, kt, Bi, attnb, ch2, lam, tau, temp);

  // 5. Wo projection (K=512, split 2) -> tmpA/tmpB
  gemm_wo<<<dim3(32,8,2),256,0,stream>>>(attnb, 512, Wob, 512, tmpA, 512, 512, 256);

  // 6. residual + rank-1(Wo time via ch2) + LN2 -> outs, y2b, ty2
  res_ln<<<2048, 256, 0, stream>>>(tmpA, tmpB, ch2, wo0, x, g2, b2, outs, y2b, ty2);

  // 7. FFN up (K=512) + rank-1 + GELU -> hb
  gemm_f1<<<dim3(16,32,1),256,0,stream>>>(y2b, 512, W1b, 512, hb, 2048, 512, ty2, w10);

  // 8. FFN down (K=2048, split 2) -> tmpA/tmpB
  gemm_f2<<<dim3(32,8,2),256,0,stream>>>(hb, 2048, W2b, 2048, tmpA, 512, 2048, 1024);

  // 9. final: h-norm + residual + rank-1(W2 time) + add_time -> d_out
  final_k<<<2048, 256, 0, stream>>>(tmpA, tmpB, hb, w20, outs, (float*)d_out);
}

// Round 10
// 101.689 us; speedup vs baseline: 30.6107x; 1.0026x over previous
//
#include <hip/hip_runtime.h>
#include <math.h>

#define DEV static __device__ __forceinline__

typedef __bf16 bf16_t;
typedef __bf16 bf16x8 __attribute__((ext_vector_type(8)));
typedef float f32x4 __attribute__((ext_vector_type(4)));

#define MFMA16(a,b,c) __builtin_amdgcn_mfma_f32_16x16x32_bf16(a,b,c,0,0,0)

// ---------- fast transcendentals ----------
DEV float frcp(float x){ return __builtin_amdgcn_rcpf(x); }
DEV float softplus_fast(float x){
  return fmaxf(x, 0.f) + __logf(1.f + __expf(-fabsf(x)));
}
DEV float tanh_fast(float z){
  float e2 = __expf(2.f * z);
  return (e2 - 1.f) * frcp(e2 + 1.f);
}
DEV float gelu_fast(float v){
  float u = 0.7978845608028654f * fmaf(0.044715f * v, v * v, v);
  u = fminf(fmaxf(u, -15.f), 15.f);
  return 0.5f * v * (1.f + tanh_fast(u));
}

DEV void gl_lds16(const void* g, void* l) {
  __builtin_amdgcn_global_load_lds((const __attribute__((address_space(1))) void*)g,
                                   (__attribute__((address_space(3))) void*)l, 16, 0, 0);
}

DEV float waveReduceSum(float v){
  #pragma unroll
  for (int o = 32; o > 0; o >>= 1) v += __shfl_xor(v, o, 64);
  return v;
}
DEV float blockReduceSum(float v, float* sh){
  v = waveReduceSum(v);
  int w = threadIdx.x >> 6;
  int nw = blockDim.x >> 6;
  __syncthreads();
  if ((threadIdx.x & 63) == 0) sh[w] = v;
  __syncthreads();
  float r = sh[0];
  for (int i = 1; i < nw; i++) r += sh[i];
  return r;
}

// bijective XCD swizzle for grids with (gx*gy)%8==0
DEV int2 xcd_swz(int gx, int gy){
  int id = blockIdx.y * gx + blockIdx.x;
  int q = (gx * gy) >> 3;
  int s = (id & 7) * q + (id >> 3);
  int2 r; r.x = s % gx; r.y = s / gx;
  return r;
}

// ---------------- prep: LN1 (blocks 0..2047) + weight conversions (rest) ----------------
__global__ __launch_bounds__(256) void prep(
    const float* __restrict__ xin,
    const float* __restrict__ g, const float* __restrict__ b,
    const float* __restrict__ Wq, const float* __restrict__ Wk,
    const float* __restrict__ Wv, const float* __restrict__ Wo,
    const float* __restrict__ W1, const float* __restrict__ W2,
    bf16_t* __restrict__ y, float* __restrict__ ty,
    bf16_t* __restrict__ Wqkvb, bf16_t* __restrict__ Wob,
    bf16_t* __restrict__ W1b, bf16_t* __restrict__ W2b,
    float* __restrict__ wqkv0, float* __restrict__ wo0,
    float* __restrict__ w10, float* __restrict__ w20)
{
  int t = threadIdx.x;
  if (blockIdx.x < 2048) {
    __shared__ float sh[8];
    int row = blockIdx.x;
    const float* xr = xin + (long)row * 513 + 1;
    float a0 = xr[t], a1 = xr[t + 256];
    float s  = blockReduceSum(a0 + a1, sh);
    float s2 = blockReduceSum(a0 * a0 + a1 * a1, sh);
    float mu = s * (1.f / 512.f);
    float var = s2 * (1.f / 512.f) - mu * mu;
    float inv = rsqrtf(var + 1e-5f);
    float y0 = (a0 - mu) * inv * g[t] + b[t];
    float y1v = (a1 - mu) * inv * g[t + 256] + b[t + 256];
    float q = blockReduceSum(y0 * y0 + y1v * y1v, sh);
    bf16_t* yr = y + (long)row * 512;
    yr[t] = (bf16_t)y0;
    yr[t + 256] = (bf16_t)y1v;
    if (t == 0) ty[row] = sqrtf(q + 1.f);
    return;
  }
  long i = (long)(blockIdx.x - 2048) * 256 + t;
  if (i < 786432) {                       // Wqkv spatial [1536][512]
    long r = i >> 9; int c = (int)(i & 511);
    const float* src = (r < 512) ? Wq + r * 513 : (r < 1024) ? Wk + (r - 512) * 513 : Wv + (r - 1024) * 513;
    Wqkvb[i] = (bf16_t)src[c + 1];
  } else if (i < 1048576) {               // Wo spatial [512][512]
    long j = i - 786432;
    long r = j >> 9; int c = (int)(j & 511);
    Wob[j] = (bf16_t)Wo[r * 513 + c + 1];
  } else if (i < 2097152) {               // W1 spatial [2048][512]
    long j = i - 1048576;
    long r = j >> 9; int c = (int)(j & 511);
    W1b[j] = (bf16_t)W1[r * 513 + c + 1];
  } else if (i < 3145728) {               // W2 spatial [512][2048]
    long j = i - 2097152;
    long r = j >> 11; int c = (int)(j & 2047);
    W2b[j] = (bf16_t)W2[r * 2049 + c + 1];
  } else if (i < 3150336) {               // time columns (fp32)
    int j = (int)(i - 3145728);
    if (j < 1536) {
      wqkv0[j] = (j < 512) ? Wq[(long)j * 513] : (j < 1024) ? Wk[(long)(j - 512) * 513] : Wv[(long)(j - 1024) * 513];
    } else if (j < 2048) wo0[j - 1536] = Wo[(long)(j - 1536) * 513];
    else if (j < 4096)  w10[j - 2048] = W1[(long)(j - 2048) * 513];
    else                w20[j - 4096] = W2[(long)(j - 4096) * 2049];
  }
}

// ---------------- residual + rank-1(Wo time) + LN2 -> outs, y2b, ty2 ----------------
__global__ __launch_bounds__(256) void res_ln(
    const float* __restrict__ woA, const float* __restrict__ woB,
    const float* __restrict__ ch2, const float* __restrict__ wo0,
    const float* __restrict__ xin,
    const float* __restrict__ g, const float* __restrict__ b,
    float* __restrict__ outs,
    bf16_t* __restrict__ y, float* __restrict__ ty)
{
  __shared__ float sh[8];
  int row = blockIdx.x;
  int t = threadIdx.x;
  const float* c = ch2 + (long)row * 8;
  float cs = ((c[0] + c[1]) + (c[2] + c[3])) + ((c[4] + c[5]) + (c[6] + c[7]));
  float tattn = sqrtf(fmaxf(cs - 7.f, 1e-8f));
  long i0 = (long)row * 512 + t, i1 = i0 + 256;
  float a0 = woA[i0] + woB[i0] + tattn * wo0[t]       + xin[(long)row * 513 + 1 + t];
  float a1 = woA[i1] + woB[i1] + tattn * wo0[t + 256] + xin[(long)row * 513 + 1 + t + 256];
  outs[i0] = a0;
  outs[i1] = a1;
  float s  = blockReduceSum(a0 + a1, sh);
  float s2 = blockReduceSum(a0 * a0 + a1 * a1, sh);
  float mu = s * (1.f / 512.f);
  float var = s2 * (1.f / 512.f) - mu * mu;
  float inv = rsqrtf(var + 1e-5f);
  float y0 = (a0 - mu) * inv * g[t] + b[t];
  float y1v = (a1 - mu) * inv * g[t + 256] + b[t + 256];
  float q = blockReduceSum(y0 * y0 + y1v * y1v, sh);
  bf16_t* yr = y + (long)row * 512;
  yr[t] = (bf16_t)y0;
  yr[t + 256] = (bf16_t)y1v;
  if (t == 0) ty[row] = sqrtf(q + 1.f);
}

// ---------------- final: th2p-sum + residual(4 partials) + rank-1 + add_time ----------------
__global__ __launch_bounds__(256) void final_k(
    const float* __restrict__ hA, const float* __restrict__ hB,
    const float* __restrict__ hC, const float* __restrict__ hD,
    const float* __restrict__ th2p, const float* __restrict__ w20,
    const float* __restrict__ outs,
    float* __restrict__ out)
{
  __shared__ float sh[8];
  int row = blockIdx.x;
  int t = threadIdx.x;
  float p = (t < 32) ? th2p[(long)t * 2048 + row] : 0.f;
  float hn = blockReduceSum(p, sh);
  float th = sqrtf(hn + 1.f);
  long i0 = (long)row * 512 + t, i1 = i0 + 256;
  float o0 = (hA[i0] + hB[i0]) + (hC[i0] + hD[i0]) + th * w20[t]       + outs[i0];
  float o1 = (hA[i1] + hB[i1]) + (hC[i1] + hD[i1]) + th * w20[t + 256] + outs[i1];
  float q = blockReduceSum(o0 * o0 + o1 * o1, sh);
  float* yr = out + (long)row * 513;
  yr[1 + t] = o0;
  yr[1 + t + 256] = o1;
  if (t == 0) yr[0] = sqrtf(q + 1.f);
}

// ---------------- vtan_tr: v_tan + transpose (V third of qkvsb only) ----------------
__global__ __launch_bounds__(256) void vtan_tr(
    const bf16_t* __restrict__ qkvsb, bf16_t* __restrict__ VTt)
{
  __shared__ bf16_t tile[64 * 72];
  int z = blockIdx.y, b = z >> 3, h = z & 7;
  int n0 = blockIdx.x * 64;
  int t = threadIdx.x;
  int r = t >> 2, c4 = t & 3;
  const bf16_t* vb = qkvsb + ((long)(b * 1024 + n0 + r) * 1536 + 1024 + h * 64 + c4 * 16);
  bf16x8 v0 = *(const bf16x8*)vb;
  bf16x8 v1 = *(const bf16x8*)(vb + 8);
  float ss = 0.f;
  #pragma unroll
  for (int e = 0; e < 8; e++) {
    float f0 = (float)v0[e], f1 = (float)v1[e];
    ss = fmaf(f0, f0, fmaf(f1, f1, ss));
  }
  ss += __shfl_xor(ss, 1, 64);
  ss += __shfl_xor(ss, 2, 64);
  float vT = sqrtf(1.f + ss);
  float sn0 = sqrtf(ss);
  float coef = __logf(vT + sn0) * frcp(fmaxf(sn0, 1e-8f));
  #pragma unroll
  for (int e = 0; e < 8; e++) {
    tile[(c4 * 16 + e) * 72 + r]     = (bf16_t)(coef * (float)v0[e]);
    tile[(c4 * 16 + 8 + e) * 72 + r] = (bf16_t)(coef * (float)v1[e]);
  }
  __syncthreads();
  int d = t >> 2, cc = (t & 3) * 16;
  bf16x8 o0 = *(const bf16x8*)&tile[d * 72 + cc];
  bf16x8 o1 = *(const bf16x8*)&tile[d * 72 + cc + 8];
  bf16_t* dst = VTt + (long)z * 64 * 1024 + (long)d * 1024 + n0 + cc;
  *(bf16x8*)dst = o0;
  *(bf16x8*)(dst + 8) = o1;
}

// ---------------- fused attention + expmap merge (XOR-swizzled LDS) ----------------
__global__ __launch_bounds__(256) void attn_fused(
    const bf16_t* __restrict__ qkvsb,   // [2048][1536]
    const bf16_t* __restrict__ VTt,     // [16][64][1024]
    const float* __restrict__ qt, const float* __restrict__ kt,
    const float* __restrict__ Bi,
    bf16_t* __restrict__ attnb,         // [2048][512]
    float* __restrict__ ch2,            // [2048][8]
    const float* __restrict__ lam_p, const float* __restrict__ tau_p,
    const float* __restrict__ temp_p)
{
  __shared__ bf16_t Ks[64 * 64];
  __shared__ bf16_t Vs[64 * 64];
  __shared__ bf16_t Ps[32 * 72];
  __shared__ float ot[32 * 65];
  __shared__ float sh_qt[32], sh_Bc[32], sh_kt[64], rs[32];

  const int t = threadIdx.x;
  const int w = t >> 6;
  const int lane = t & 63;
  const int lm = lane & 15, lh = lane >> 4;
  int2 sw = xcd_swz(32, 16);
  const int z = sw.y, b = z >> 3, h = z & 7;
  const int n0 = sw.x * 32;
  const int sb = (((lane & 7) ^ (lane >> 3)) << 4);
  const int r8 = lane >> 3;

  float lam = softplus_fast(lam_p[0]);
  float tau = softplus_fast(tau_p[0]);
  float invT = frcp(temp_p[0]);
  float A1 = -lam * invT, A2 = -tau * invT;
  float A2h = 0.5f * A2, K0 = A2 * 0.048750465f;

  if (t < 32) {
    sh_qt[t] = qt[z * 1024 + n0 + t];
    sh_Bc[t] = Bi[z * 1024 + n0 + t] - 0.1f;
    rs[t] = 0.f;
  }

  // stage Q (32x64, swizzled) then preload frags
  const bf16_t* qbase = qkvsb + ((long)(b * 1024 + n0) * 1536 + h * 64);
  gl_lds16((const char*)(qbase + (long)(w * 8 + r8) * 1536) + sb, (char*)Ks + w * 1024);
  __syncthreads();
  bf16x8 qf[2][2];
  #pragma unroll
  for (int i = 0; i < 2; i++)
    #pragma unroll
    for (int kk = 0; kk < 2; kk++)
      qf[i][kk] = *(const bf16x8*)&Ks[(i * 16 + lm) * 64 + (((kk * 4 + lh) ^ (lm & 7)) << 3)];

  f32x4 oacc[2] = {};
  float racc[2][4] = {};

  const bf16_t* kbase = qkvsb + ((long)b * 1024 * 1536 + 512 + h * 64);
  const bf16_t* vbase = VTt + (long)z * 64 * 1024;
  const int sl0 = ((lh) ^ (lm & 7)) << 3;
  const int sl1 = ((4 + lh) ^ (lm & 7)) << 3;

  for (int kv = 0; kv < 16; kv++) {
    __syncthreads();
    {
      const bf16_t* kb = kbase + (long)(kv * 64) * 1536;
      gl_lds16((const char*)(kb + (long)(w * 16 + r8) * 1536) + sb,     (char*)Ks + (w * 2) * 1024);
      gl_lds16((const char*)(kb + (long)(w * 16 + 8 + r8) * 1536) + sb, (char*)Ks + (w * 2 + 1) * 1024);
      const bf16_t* vb = vbase + kv * 64;
      gl_lds16((const char*)(vb + (long)(w * 16 + r8) * 1024) + sb,     (char*)Vs + (w * 2) * 1024);
      gl_lds16((const char*)(vb + (long)(w * 16 + 8 + r8) * 1024) + sb, (char*)Vs + (w * 2 + 1) * 1024);
    }
    if (t < 64) sh_kt[t] = kt[z * 1024 + kv * 64 + t];
    __syncthreads();

    f32x4 sacc[2] = {};
    bf16x8 kf0 = *(const bf16x8*)&Ks[(w * 16 + lm) * 64 + sl0];
    bf16x8 kf1 = *(const bf16x8*)&Ks[(w * 16 + lm) * 64 + sl1];
    sacc[0] = MFMA16(qf[0][0], kf0, sacc[0]);
    sacc[0] = MFMA16(qf[0][1], kf1, sacc[0]);
    sacc[1] = MFMA16(qf[1][0], kf0, sacc[1]);
    sacc[1] = MFMA16(qf[1][1], kf1, sacc[1]);

    float ktv = sh_kt[w * 16 + lm];
    #pragma unroll
    for (int i = 0; i < 2; i++) {
      #pragma unroll
      for (int q = 0; q < 4; q++) {
        int r = i * 16 + lh * 4 + q;
        float qtv = sh_qt[r], Bc = sh_Bc[r];
        float nOQ = fmaf(qtv, qtv, -1.f);
        float inner = fmaf(-qtv, ktv, sacc[i][q]);
        float nQK = fmaxf(fmaf(inner, inner, -1.f), 0.f);
        float ri = __builtin_amdgcn_rsqf(fmaf(nQK, nOQ, 2.5e-5f));
        float zr = fmaf(inner, qtv, ktv) * ri;
        float Zc = fminf(fmaxf(-zr, -1.f), 1.f);
        float xx = fmaxf(-inner, 1.001f);
        float u = fmaf(__log2f(xx), 0.01732868f, 0.01732868f);
        float p = fminf(u * u, 0.09f);
        float H = p * fmaf(p, -6.584f, 3.5556f);
        float a = Zc + Bc;
        float a2 = a * a;
        float lc = a2 * fmaf(a2, fmaf(a2, 0.00034722f, -0.0052083f), 0.125f);
        float lgt = fmaf(A1, H, fmaf(A2, lc, fmaf(A2h, a, K0)));
        float e = __expf(lgt);
        Ps[r * 72 + w * 16 + lm] = (bf16_t)e;
        racc[i][q] += e;
      }
    }
    __syncthreads();

    bf16x8 va0 = *(const bf16x8*)&Vs[(w * 16 + lm) * 64 + sl0];
    bf16x8 va1 = *(const bf16x8*)&Vs[(w * 16 + lm) * 64 + sl1];
    bf16x8 pb00 = *(const bf16x8*)&Ps[lm * 72 + lh * 8];
    bf16x8 pb01 = *(const bf16x8*)&Ps[lm * 72 + 32 + lh * 8];
    bf16x8 pb10 = *(const bf16x8*)&Ps[(16 + lm) * 72 + lh * 8];
    bf16x8 pb11 = *(const bf16x8*)&Ps[(16 + lm) * 72 + 32 + lh * 8];
    oacc[0] = MFMA16(va0, pb00, oacc[0]);
    oacc[0] = MFMA16(va1, pb01, oacc[0]);
    oacc[1] = MFMA16(va0, pb10, oacc[1]);
    oacc[1] = MFMA16(va1, pb11, oacc[1]);
  }

  #pragma unroll
  for (int i = 0; i < 2; i++)
    #pragma unroll
    for (int q = 0; q < 4; q++) {
      float v = racc[i][q];
      v += __shfl_xor(v, 1, 64);
      v += __shfl_xor(v, 2, 64);
      v += __shfl_xor(v, 4, 64);
      v += __shfl_xor(v, 8, 64);
      if (lm == 0) atomicAdd(&rs[i * 16 + lh * 4 + q], v);
    }

  #pragma unroll
  for (int j = 0; j < 2; j++)
    #pragma unroll
    for (int q = 0; q < 4; q++)
      ot[(j * 16 + lm) * 65 + w * 16 + lh * 4 + q] = oacc[j][q];
  __syncthreads();

  int r = t >> 3, c0 = (t & 7) * 8;
  float inv = frcp(rs[r] * (1.f + 1e-8f));
  float v[8];
  float ss = 0.f;
  #pragma unroll
  for (int e = 0; e < 8; e++) {
    v[e] = ot[r * 65 + c0 + e] * inv;
    ss = fmaf(v[e], v[e], ss);
  }
  ss += __shfl_xor(ss, 1, 64);
  ss += __shfl_xor(ss, 2, 64);
  ss += __shfl_xor(ss, 4, 64);
  float nn = fmaxf(sqrtf(ss), 1e-8f);
  float e_ = __expf(nn), ei = frcp(e_);
  float coef = 0.5f * (e_ - ei) * frcp(nn);
  bf16x8 ov;
  #pragma unroll
  for (int e = 0; e < 8; e++) ov[e] = (bf16_t)(coef * v[e]);
  *(bf16x8*)(attnb + (long)(b * 1024 + n0 + r) * 512 + h * 64 + c0) = ov;
  if (c0 == 0) {
    float ch = 0.5f * (e_ + ei);
    ch2[(long)(b * 1024 + n0 + r) * 8 + h] = ch * ch;
  }
}

// ============ bf16-out GEMM, BK=64, swizzled, rank-1 epilogue + stats ============
// ACTF: 0 = GELU | 2 = plain.  STATS: 0 none | 1 qt/kt/Bi (QKV) | 2 row ||.||^2 partials (F1)
template<int ACTF, int STATS>
DEV void gemm_rep_body(
    const bf16_t* __restrict__ Ag, int lda,
    const bf16_t* __restrict__ Bg, int ldb,
    bf16_t* __restrict__ Cg, int ldc, int K,
    const float* __restrict__ trow, const float* __restrict__ w0,
    float* __restrict__ s0, float* __restrict__ s1, float* __restrict__ s2,
    const float* __restrict__ beta_p,
    int bx, int by)
{
  __shared__ char smem[24576];
  __shared__ float sh_t[128];
  bf16_t* As = (bf16_t*)smem;
  bf16_t* Bs = (bf16_t*)(smem + 16384);
  const int t = threadIdx.x;
  const int wid = t >> 6, lane = t & 63;
  const int lm = lane & 15, lh = lane >> 4;
  const int bm = bx * 128;
  const int bn = by * 64;
  const int wm = (wid >> 1) * 64;
  const int wn = (wid & 1) * 32;
  const int sb = (((lane & 7) ^ (lane >> 3)) << 4);
  const int r8 = lane >> 3;
  f32x4 acc[4][2] = {};

  if (t < 128) sh_t[t] = trow[bm + t];
  float w0c[2] = { w0[bn + wn + lm], w0[bn + wn + 16 + lm] };

  for (int kk = 0; kk < K; kk += 64) {
    __syncthreads();
    #pragma unroll
    for (int r = 0; r < 4; r++) {
      int chunk = wid * 4 + r;
      gl_lds16((const char*)(Ag + (long)(bm + chunk * 8 + r8) * lda + kk) + sb,
               smem + chunk * 1024);
    }
    #pragma unroll
    for (int r = 0; r < 2; r++) {
      int chunk = wid * 2 + r;
      gl_lds16((const char*)(Bg + (long)(bn + chunk * 8 + r8) * ldb + kk) + sb,
               smem + 16384 + chunk * 1024);
    }
    __syncthreads();
    #pragma unroll
    for (int k2 = 0; k2 < 2; k2++) {
      const int sl = (((k2 * 4 + lh) ^ (lm & 7)) << 3);
      bf16x8 af[4], bfr[2];
      #pragma unroll
      for (int i = 0; i < 4; i++) af[i] = *(const bf16x8*)&As[(wm + i * 16 + lm) * 64 + sl];
      #pragma unroll
      for (int j = 0; j < 2; j++) bfr[j] = *(const bf16x8*)&Bs[(wn + j * 16 + lm) * 64 + sl];
      #pragma unroll
      for (int i = 0; i < 4; i++)
        #pragma unroll
        for (int j = 0; j < 2; j++)
          acc[i][j] = MFMA16(af[i], bfr[j], acc[i][j]);
    }
  }

  __syncthreads();
  bf16_t* rep = (bf16_t*)smem;
  #pragma unroll
  for (int i = 0; i < 4; i++) {
    #pragma unroll
    for (int q = 0; q < 4; q++) {
      int r = wm + i * 16 + lh * 4 + q;
      #pragma unroll
      for (int j = 0; j < 2; j++) {
        float v = acc[i][j][q] + sh_t[r] * w0c[j];
        rep[r * 64 + wn + j * 16 + lm] = (bf16_t)(ACTF == 0 ? gelu_fast(v) : v);
      }
    }
  }
  __syncthreads();

  #pragma unroll
  for (int rd = 0; rd < 4; rd++) {
    int off = rd * 4096 + t * 16;
    int lr = off >> 7;
    int lc = (off & 127) >> 1;
    bf16x8 vv = *(const bf16x8*)(smem + off);
    *(bf16x8*)(Cg + (long)(bm + lr) * ldc + bn + lc) = vv;
  }

  if constexpr (STATS != 0) {
    int rr = t >> 1, half = t & 1;
    const bf16_t* rp = rep + rr * 64 + half * 32;
    float s = 0.f;
    #pragma unroll
    for (int c = 0; c < 4; c++) {
      bf16x8 vv = *(const bf16x8*)(rp + c * 8);
      #pragma unroll
      for (int e = 0; e < 8; e++) { float f = (float)vv[e]; s = fmaf(f, f, s); }
    }
    s += __shfl_xor(s, 1, 64);
    if (half == 0) {
      if constexpr (STATS == 2) {
        s0[(long)(bn >> 6) * 2048 + bm + rr] = s;          // ||h_row||^2 partial
      } else {
        int bnh = bn >> 6;                                  // 0..23: q heads, k heads, v heads
        if (bnh < 16) {
          int grow = bm + rr, bloc = grow >> 10, n = grow & 1023;
          if (bnh < 8) {
            int zz = bloc * 8 + bnh;
            float qT = sqrtf(1.f + s);
            s0[zz * 1024 + n] = qT;
            float beta = softplus_fast(beta_p[0]);
            float xq = fmaxf(qT, 1.001f);
            float sh_ = sqrtf(fmaxf(xq * xq - 1.f, 0.f));
            float rr0 = beta * frcp(sh_);
            s2[zz * 1024 + n] = sqrtf(fmaxf(1.f - rr0 * rr0, 0.f) + 1e-8f);
          } else {
            int zz = bloc * 8 + (bnh - 8);
            s1[zz * 1024 + n] = sqrtf(1.f + s);
          }
        }
      }
    }
  }
}

// ---------------- fp32-out GEMM, BK=64, swizzled (64x64, 4 waves, K-range) ----------------
DEV void gemm_f32_body(
    const bf16_t* __restrict__ Ag, int lda,
    const bf16_t* __restrict__ Bg, int ldb,
    float* __restrict__ Cg, int ldc,
    int k0, int k1, int bx, int by)
{
  __shared__ bf16_t As[64 * 64];
  __shared__ bf16_t Bs[64 * 64];
  const int t = threadIdx.x;
  const int wid = t >> 6, lane = t & 63;
  const int lm = lane & 15, lh = lane >> 4;
  const int bm = bx * 64;
  const int bn = by * 64;
  const int wm = (wid >> 1) * 32;
  const int wn = (wid & 1) * 32;
  const int sb = (((lane & 7) ^ (lane >> 3)) << 4);
  const int r8 = lane >> 3;
  f32x4 acc[2][2] = {};

  for (int kk = k0; kk < k1; kk += 64) {
    __syncthreads();
    #pragma unroll
    for (int r = 0; r < 2; r++) {
      int chunk = wid * 2 + r;
      gl_lds16((const char*)(Ag + (long)(bm + chunk * 8 + r8) * lda + kk) + sb,
               (char*)As + chunk * 1024);
      gl_lds16((const char*)(Bg + (long)(bn + chunk * 8 + r8) * ldb + kk) + sb,
               (char*)Bs + chunk * 1024);
    }
    __syncthreads();
    #pragma unroll
    for (int k2 = 0; k2 < 2; k2++) {
      const int sl = (((k2 * 4 + lh) ^ (lm & 7)) << 3);
      bf16x8 af[2], bfr[2];
      #pragma unroll
      for (int i = 0; i < 2; i++) af[i] = *(const bf16x8*)&As[(wm + i * 16 + lm) * 64 + sl];
      #pragma unroll
      for (int j = 0; j < 2; j++) bfr[j] = *(const bf16x8*)&Bs[(wn + j * 16 + lm) * 64 + sl];
      #pragma unroll
      for (int i = 0; i < 2; i++)
        #pragma unroll
        for (int j = 0; j < 2; j++)
          acc[i][j] = MFMA16(af[i], bfr[j], acc[i][j]);
    }
  }

  #pragma unroll
  for (int i = 0; i < 2; i++) {
    #pragma unroll
    for (int q = 0; q < 4; q++) {
      long row = bm + wm + i * 16 + lh * 4 + q;
      #pragma unroll
      for (int j = 0; j < 2; j++)
        Cg[row * ldc + bn + wn + j * 16 + lm] = acc[i][j][q];
    }
  }
}

// ---- named wrappers ----
__global__ __launch_bounds__(256) void gemm_qkv(const bf16_t* A, int lda, const bf16_t* B, int ldb,
                                                bf16_t* C, int ldc, int K,
                                                const float* trow, const float* w0,
                                                float* qt, float* kt, float* Bi, const float* beta){
  int2 sw = xcd_swz(16, 24);
  gemm_rep_body<2, 1>(A, lda, B, ldb, C, ldc, K, trow, w0, qt, kt, Bi, beta, sw.x, sw.y);
}
__global__ __launch_bounds__(256) void gemm_f1(const bf16_t* A, int lda, const bf16_t* B, int ldb,
                                               bf16_t* C, int ldc, int K,
                                               const float* trow, const float* w0,
                                               float* th2p){
  int2 sw = xcd_swz(16, 32);
  gemm_rep_body<0, 2>(A, lda, B, ldb, C, ldc, K, trow, w0, th2p, nullptr, nullptr, nullptr, sw.x, sw.y);
}
__global__ __launch_bounds__(256) void gemm_wo(const bf16_t* A, int lda, const bf16_t* B, int ldb,
                                               float* C, int ldc, int K){
  int2 sw = xcd_swz(32, 8);
  int k0 = blockIdx.z * (K >> 1);
  gemm_f32_body(A, lda, B, ldb, C + (long)blockIdx.z * 2048 * ldc, ldc,
                k0, k0 + (K >> 1), sw.x, sw.y);
}
__global__ __launch_bounds__(256) void gemm_f2(const bf16_t* A, int lda, const bf16_t* B, int ldb,
                                               float* C, int ldc, int K){
  int2 sw = xcd_swz(32, 8);
  int k0 = blockIdx.z * (K >> 2);
  gemm_f32_body(A, lda, B, ldb, C + (long)blockIdx.z * 2048 * ldc, ldc,
                k0, k0 + (K >> 2), sw.x, sw.y);
}

extern "C" void kernel_launch(void* const* d_in, const int* in_sizes, int n_in,
                              void* d_out, int out_size, void* d_ws, size_t ws_size,
                              hipStream_t stream) {
  const float* x    = (const float*)d_in[0];
  const float* Wq   = (const float*)d_in[1];
  const float* Wk   = (const float*)d_in[2];
  const float* Wv   = (const float*)d_in[3];
  const float* Wo   = (const float*)d_in[4];
  const float* W1   = (const float*)d_in[5];
  const float* W2   = (const float*)d_in[6];
  const float* g1   = (const float*)d_in[7];
  const float* b1   = (const float*)d_in[8];
  const float* g2   = (const float*)d_in[9];
  const float* b2   = (const float*)d_in[10];
  const float* temp = (const float*)d_in[11];
  const float* beta = (const float*)d_in[12];
  const float* tau  = (const float*)d_in[13];
  const float* lam  = (const float*)d_in[14];

  char* W = (char*)d_ws;
  bf16_t* Wqkvb = (bf16_t*)(W + 0);          // [1536][512]
  bf16_t* Wob   = (bf16_t*)(W + 1572864);    // [512][512]
  bf16_t* W1b   = (bf16_t*)(W + 2097152);    // [2048][512]
  bf16_t* W2b   = (bf16_t*)(W + 4194304);    // [512][2048]
  float*  wqkv0 = (float*) (W + 6291456);    // [1536]
  float*  wo0   = (float*) (W + 6297600);    // [512]
  float*  w10   = (float*) (W + 6299648);    // [2048]
  float*  w20   = (float*) (W + 6307840);    // [512]
  bf16_t* y1b   = (bf16_t*)(W + 6309888);    // [2048][512]
  float*  ty1   = (float*) (W + 8407040);    // [2048]
  bf16_t* qkvsb = (bf16_t*)(W + 8415232);    // [2048][1536]
  float*  qt    = (float*) (W + 14706688);   // [16384]
  float*  kt    = (float*) (W + 14772224);
  float*  Bi    = (float*) (W + 14837760);
  bf16_t* VTt   = (bf16_t*)(W + 14903296);   // [16][64][1024]
  float*  ch2   = (float*) (W + 17000448);   // [2048][8]
  bf16_t* attnb = (bf16_t*)(W + 17065984);   // [2048][512]
  float*  tmpA  = (float*) (W + 19163136);   // [2048][512] x4 partials (contiguous)
  float*  outs  = (float*) (W + 35940352);   // [2048][512]
  bf16_t* y2b   = (bf16_t*)(W + 40134656);   // [2048][512]
  float*  ty2   = (float*) (W + 42231808);   // [2048]
  bf16_t* hb    = (bf16_t*)(W + 42240000);   // [2048][2048]
  float*  th2p  = (float*) (W + 50628608);   // [32][2048]  (end ~50.9 MB)
  float*  tmpB  = tmpA + 1048576;
  float*  tmpC  = tmpA + 2097152;
  float*  tmpD  = tmpA + 3145728;

  // 0. LN1 + weight conversions (fused)
  prep<<<14354, 256, 0, stream>>>(x, g1, b1, Wq, Wk, Wv, Wo, W1, W2,
                                  y1b, ty1, Wqkvb, Wob, W1b, W2b, wqkv0, wo0, w10, w20);

  // 1. QKV projection (K=512) + rank-1 time + q/k stats epilogue -> qkvsb, qt, kt, Bi
  gemm_qkv<<<dim3(16,24,1),256,0,stream>>>(y1b, 512, Wqkvb, 512, qkvsb, 1536, 512,
                                           ty1, wqkv0, qt, kt, Bi, beta);

  // 2. v_tan + transpose -> VTt
  vtan_tr<<<dim3(16,16,1),256,0,stream>>>(qkvsb, VTt);

  // 3. fused attention + expmap merge -> attnb + ch2
  attn_fused<<<dim3(32,16,1),256,0,stream>>>(qkvsb, VTt, qt, kt, Bi, attnb, ch2, lam, tau, temp);

  // 4. Wo projection (K=512, split 2) -> tmpA/tmpB
  gemm_wo<<<dim3(32,8,2),256,0,stream>>>(attnb, 512, Wob, 512, tmpA, 512, 512);

  // 5. residual + rank-1(Wo time via ch2) + LN2 -> outs, y2b, ty2
  res_ln<<<2048, 256, 0, stream>>>(tmpA, tmpB, ch2, wo0, x, g2, b2, outs, y2b, ty2);

  // 6. FFN up (K=512) + rank-1 + GELU + ||h||^2 partials -> hb, th2p
  gemm_f1<<<dim3(16,32,1),256,0,stream>>>(y2b, 512, W1b, 512, hb, 2048, 512, ty2, w10, th2p);

  // 7. FFN down (K=2048, split 4) -> tmpA..D
  gemm_f2<<<dim3(32,8,4),256,0,stream>>>(hb, 2048, W2b, 2048, tmpA, 512, 2048);

  // 8. final: th from th2p + residual + rank-1(W2 time) + add_time -> d_out
  final_k<<<2048, 256, 0, stream>>>(tmpA, tmpB, tmpC, tmpD, th2p, w20, outs, (float*)d_out);
}